// Round 8
// baseline (1848.037 us; speedup 1.0000x reference)
//
#include <hip/hip_runtime.h>

typedef __bf16 bf16_t;
using bf16x8 = __bf16 __attribute__((ext_vector_type(8)));
using f32x4  = float __attribute__((ext_vector_type(4)));

// B=2048, N=64, D=256, H=256, T=16
static constexpr long MTOT = 131072;   // B*N

__device__ __forceinline__ f32x4 mfma16(bf16x8 a, bf16x8 b, f32x4 c) {
  return __builtin_amdgcn_mfma_f32_16x16x32_bf16(a, b, c, 0, 0, 0);
}

// Swizzled LDS tiles: element (row,k) at byte row*rowBytes + ((k*2 + colOff) ^ ((row&7)<<4)).
__device__ __forceinline__ bf16x8 lds_frag(const bf16_t* base, int row, int k, int rowBytes) {
  int byte = row * rowBytes + ((k << 1) ^ ((row & 7) << 4));
  return *reinterpret_cast<const bf16x8*>(reinterpret_cast<const char*>(base) + byte);
}
__device__ __forceinline__ void lds_put(bf16_t* base, int row, int col, int rowBytes, float v) {
  int byte = row * rowBytes + ((col << 1) ^ ((row & 7) << 4));
  *reinterpret_cast<bf16_t*>(reinterpret_cast<char*>(base) + byte) = (bf16_t)v;
}
__device__ __forceinline__ void lds_put2(bf16_t* hi, bf16_t* lo, int row, int col,
                                         int rowBytes, float v) {
  int byte = row * rowBytes + ((col << 1) ^ ((row & 7) << 4));
  bf16_t h = (bf16_t)v;
  bf16_t l = (bf16_t)(v - (float)h);
  *reinterpret_cast<bf16_t*>(reinterpret_cast<char*>(hi) + byte) = h;
  *reinterpret_cast<bf16_t*>(reinterpret_cast<char*>(lo) + byte) = l;
}

// Stage a [64 x 256] f32 tile (lda=256) -> split hi/lo bf16 swizzled LDS tiles.
__device__ __forceinline__ void stage_split(bf16_t* hi, bf16_t* lo, const float* src,
                                            long row0, int rowBytesLds, int colOffBytes,
                                            int tid, int nthr) {
  for (int e = tid * 4; e < 64 * 256; e += nthr * 4) {
    int r = e >> 8, c = e & 255;
    float4 v = *reinterpret_cast<const float4*>(src + (row0 + r) * 256 + c);
    bf16_t h4[4], l4[4];
    h4[0] = (bf16_t)v.x; l4[0] = (bf16_t)(v.x - (float)h4[0]);
    h4[1] = (bf16_t)v.y; l4[1] = (bf16_t)(v.y - (float)h4[1]);
    h4[2] = (bf16_t)v.z; l4[2] = (bf16_t)(v.z - (float)h4[2]);
    h4[3] = (bf16_t)v.w; l4[3] = (bf16_t)(v.w - (float)h4[3]);
    int db = r * rowBytesLds + (((c << 1) + colOffBytes) ^ ((r & 7) << 4));
    *reinterpret_cast<uint2*>(reinterpret_cast<char*>(hi) + db) = *reinterpret_cast<const uint2*>(h4);
    *reinterpret_cast<uint2*>(reinterpret_cast<char*>(lo) + db) = *reinterpret_cast<const uint2*>(l4);
  }
}

// Stage a [64 x 256] f32 tile -> single bf16 swizzled LDS (rowBytes=512).
__device__ __forceinline__ void stage_f32(bf16_t* lds, const float* src, long row0,
                                          int tid, int nthr) {
  for (int e = tid * 4; e < 64 * 256; e += nthr * 4) {
    int r = e >> 8, c = e & 255;
    float4 v = *reinterpret_cast<const float4*>(src + (row0 + r) * 256 + c);
    bf16_t t4[4] = {(bf16_t)v.x, (bf16_t)v.y, (bf16_t)v.z, (bf16_t)v.w};
    int db = r * 512 + ((c << 1) ^ ((r & 7) << 4));
    *reinterpret_cast<uint2*>(reinterpret_cast<char*>(lds) + db) =
        *reinterpret_cast<const uint2*>(t4);
  }
}

// ---------------------------------------------------------------------------
// Weights f32 -> bf16 in ws. Offsets (elements): fc_gru_w 0, in_proj_w 65536,
// out_proj_w 262144, att_w 327680, gru_wih 458752, gru_whh 655360, fc2_w 851968.
// ---------------------------------------------------------------------------
__global__ __launch_bounds__(256) void cvt_weights(const float* __restrict__ w0,
                                                   const float* __restrict__ w1,
                                                   const float* __restrict__ w2,
                                                   const float* __restrict__ w3,
                                                   const float* __restrict__ w4,
                                                   const float* __restrict__ w5,
                                                   const float* __restrict__ w6,
                                                   bf16_t* __restrict__ dst) {
  long e = ((long)blockIdx.x * 256 + threadIdx.x) * 4;
  const float* src; long off;
  if (e < 65536)       { src = w0; off = 0; }
  else if (e < 262144) { src = w1; off = 65536; }
  else if (e < 327680) { src = w2; off = 262144; }
  else if (e < 458752) { src = w3; off = 327680; }
  else if (e < 655360) { src = w4; off = 458752; }
  else if (e < 851968) { src = w5; off = 655360; }
  else                 { src = w6; off = 851968; }
  float4 v = *reinterpret_cast<const float4*>(src + (e - off));
  bf16_t o[4] = {(bf16_t)v.x, (bf16_t)v.y, (bf16_t)v.z, (bf16_t)v.w};
  *reinterpret_cast<uint2*>(dst + e) = *reinterpret_cast<const uint2*>(o);
}

// ---------------------------------------------------------------------------
// x = relu(inputs @ fc_gru_w^T + b): f32 in (split), f32 out. Tile 64x256.
// ---------------------------------------------------------------------------
__global__ __launch_bounds__(256, 2) void gemm1(const float* __restrict__ X,
                                                const bf16_t* __restrict__ W,
                                                const float* __restrict__ Bi,
                                                float* __restrict__ C) {
  __shared__ bf16_t Ihi[64 * 256], Ilo[64 * 256];
  const int tid = threadIdx.x, lane = tid & 63, wv = tid >> 6;
  const int rl = lane & 15, kof = (lane >> 4) << 3, ro4 = (lane >> 4) << 2;
  const long m0 = (long)blockIdx.x * 64;
  stage_split(Ihi, Ilo, X, m0, 512, 0, tid, 256);
  __syncthreads();
  f32x4 acc[4][4] = {};
  for (int kk = 0; kk < 256; kk += 32) {
    bf16x8 ah[4], al[4], bb[4];
#pragma unroll
    for (int rt = 0; rt < 4; ++rt) {
      ah[rt] = lds_frag(Ihi, rt * 16 + rl, kk + kof, 512);
      al[rt] = lds_frag(Ilo, rt * 16 + rl, kk + kof, 512);
    }
#pragma unroll
    for (int ct = 0; ct < 4; ++ct)
      bb[ct] = *reinterpret_cast<const bf16x8*>(W + (long)(wv * 64 + ct * 16 + rl) * 256 + kk + kof);
#pragma unroll
    for (int rt = 0; rt < 4; ++rt)
#pragma unroll
      for (int ct = 0; ct < 4; ++ct) {
        acc[rt][ct] = mfma16(ah[rt], bb[ct], acc[rt][ct]);
        acc[rt][ct] = mfma16(al[rt], bb[ct], acc[rt][ct]);
      }
  }
#pragma unroll
  for (int ct = 0; ct < 4; ++ct) {
    int c = wv * 64 + ct * 16 + rl;
    float bv = Bi[c];
#pragma unroll
    for (int rt = 0; rt < 4; ++rt)
#pragma unroll
      for (int i = 0; i < 4; ++i)
        C[(m0 + rt * 16 + ro4 + i) * 256 + c] = fmaxf(acc[rt][ct][i] + bv, 0.f);
  }
}

// ---------------------------------------------------------------------------
// Fused per-sample attention, split-precision. Block = 1 sample, 512 thr/8 waves.
// Reads x (f32 [M,256]), writes x_att (f32 [M,256]). Mask is INT32 (bool->int).
// ---------------------------------------------------------------------------
__global__ __launch_bounds__(512, 2) void attn_kernel(const float* __restrict__ Xf,
                                                      float* __restrict__ Xatt,
                                                      const bf16_t* __restrict__ Wqkv,
                                                      const float* __restrict__ Bqkv,
                                                      const bf16_t* __restrict__ Wo,
                                                      const float* __restrict__ Bo,
                                                      const int* __restrict__ drop) {
  __shared__ __align__(16) char buf[147456];
  bf16_t* XHI = reinterpret_cast<bf16_t*>(buf);            // 32K, swz rowBytes 512
  bf16_t* XLO = reinterpret_cast<bf16_t*>(buf + 32768);    // 32K
  bf16_t* QS  = reinterpret_cast<bf16_t*>(buf + 65536);    // 32K, swz 512; later V^T swz 128
  bf16_t* KS  = reinterpret_cast<bf16_t*>(buf + 98304);    // 32K, swz 512; later PHI/PLO swz 128
  bf16_t* PHI = KS;                                        // 8K  [64][64]
  bf16_t* PLO = reinterpret_cast<bf16_t*>(buf + 98304 + 8192);
  float*  SS  = reinterpret_cast<float*>(buf + 131072);    // 16K [64][64]
  const int tid = threadIdx.x, lane = tid & 63, wv = tid >> 6;
  const int rl = lane & 15, kof = (lane >> 4) << 3, ro4 = (lane >> 4) << 2;
  const int b = blockIdx.x;
  const long R0 = (long)b * 64;
  stage_split(XHI, XLO, Xf, R0, 512, 0, tid, 512);
  __syncthreads();
  const int c0 = wv * 32;

  // q and k GEMMs (split x) -> bf16 swizzled LDS
  for (int which = 0; which < 2; ++which) {
    const bf16_t* Wp = Wqkv + (long)which * 65536;
    bf16_t* outp = which ? KS : QS;
    f32x4 acc[4][2] = {};
    for (int kk = 0; kk < 256; kk += 32) {
      bf16x8 ah[4], al[4], bb[2];
#pragma unroll
      for (int rt = 0; rt < 4; ++rt) {
        ah[rt] = lds_frag(XHI, rt * 16 + rl, kk + kof, 512);
        al[rt] = lds_frag(XLO, rt * 16 + rl, kk + kof, 512);
      }
#pragma unroll
      for (int ct = 0; ct < 2; ++ct)
        bb[ct] = *reinterpret_cast<const bf16x8*>(Wp + (long)(c0 + ct * 16 + rl) * 256 + kk + kof);
#pragma unroll
      for (int rt = 0; rt < 4; ++rt)
#pragma unroll
        for (int ct = 0; ct < 2; ++ct) {
          acc[rt][ct] = mfma16(ah[rt], bb[ct], acc[rt][ct]);
          acc[rt][ct] = mfma16(al[rt], bb[ct], acc[rt][ct]);
        }
    }
#pragma unroll
    for (int ct = 0; ct < 2; ++ct) {
      int c = c0 + ct * 16 + rl;
      float bv = Bqkv[which * 256 + c];
#pragma unroll
      for (int rt = 0; rt < 4; ++rt)
#pragma unroll
        for (int i = 0; i < 4; ++i) lds_put(outp, rt * 16 + ro4 + i, c, 512, acc[rt][ct][i] + bv);
    }
  }
  __syncthreads();

  // scores = q k^T * scale, masked (int32 mask) -> SS f32
  {
    const int rt0 = (wv & 3) * 16, sc0 = (wv >> 2) * 32;
    f32x4 acc[2] = {};
    for (int kk = 0; kk < 256; kk += 32) {
      bf16x8 a = lds_frag(QS, rt0 + rl, kk + kof, 512);
#pragma unroll
      for (int ct = 0; ct < 2; ++ct) {
        bf16x8 bb = lds_frag(KS, sc0 + ct * 16 + rl, kk + kof, 512);
        acc[ct] = mfma16(a, bb, acc[ct]);
      }
    }
#pragma unroll
    for (int ct = 0; ct < 2; ++ct)
#pragma unroll
      for (int i = 0; i < 4; ++i) {
        int rr = rt0 + ro4 + i, cc = sc0 + ct * 16 + rl;
        float s = acc[ct][i] * 0.0625f;
        if (drop[(long)b * 4096 + rr * 64 + cc]) s = -1e9f;
        SS[rr * 64 + cc] = s;
      }
  }
  __syncthreads();

  // v GEMM (split x) -> V^T [256][64] bf16 over Q region (q dead)
  {
    const bf16_t* Wp = Wqkv + (long)2 * 65536;
    f32x4 acc[4][2] = {};
    for (int kk = 0; kk < 256; kk += 32) {
      bf16x8 ah[4], al[4], bb[2];
#pragma unroll
      for (int rt = 0; rt < 4; ++rt) {
        ah[rt] = lds_frag(XHI, rt * 16 + rl, kk + kof, 512);
        al[rt] = lds_frag(XLO, rt * 16 + rl, kk + kof, 512);
      }
#pragma unroll
      for (int ct = 0; ct < 2; ++ct)
        bb[ct] = *reinterpret_cast<const bf16x8*>(Wp + (long)(c0 + ct * 16 + rl) * 256 + kk + kof);
#pragma unroll
      for (int rt = 0; rt < 4; ++rt)
#pragma unroll
        for (int ct = 0; ct < 2; ++ct) {
          acc[rt][ct] = mfma16(ah[rt], bb[ct], acc[rt][ct]);
          acc[rt][ct] = mfma16(al[rt], bb[ct], acc[rt][ct]);
        }
    }
#pragma unroll
    for (int ct = 0; ct < 2; ++ct) {
      int c = c0 + ct * 16 + rl;
      float bv = Bqkv[512 + c];
#pragma unroll
      for (int rt = 0; rt < 4; ++rt)
#pragma unroll
        for (int i = 0; i < 4; ++i) {
          int j = rt * 16 + ro4 + i;                    // agent (key) index
          lds_put(QS, c, j, 128, acc[rt][ct][i] + bv);  // V^T[c][j]
        }
    }
  }
  // wave-parallel softmax -> split P over K region (k dead)
  for (int j = 0; j < 8; ++j) {
    int rr = wv * 8 + j;
    float s = SS[rr * 64 + lane];
    float m = s;
#pragma unroll
    for (int off = 32; off >= 1; off >>= 1) m = fmaxf(m, __shfl_xor(m, off));
    float e = __expf(s - m);
    float sum = e;
#pragma unroll
    for (int off = 32; off >= 1; off >>= 1) sum += __shfl_xor(sum, off);
    lds_put2(PHI, PLO, rr, lane, 128, e / sum);
  }
  __syncthreads();

  // ctx = P @ V (split P) -> split ctx over X region (x dead)
  {
    f32x4 acc[4][2] = {};
    for (int kk = 0; kk < 64; kk += 32) {
      bf16x8 ah[4], al[4], bb[2];
#pragma unroll
      for (int rt = 0; rt < 4; ++rt) {
        ah[rt] = lds_frag(PHI, rt * 16 + rl, kk + kof, 128);
        al[rt] = lds_frag(PLO, rt * 16 + rl, kk + kof, 128);
      }
#pragma unroll
      for (int ct = 0; ct < 2; ++ct) bb[ct] = lds_frag(QS, c0 + ct * 16 + rl, kk + kof, 128);
#pragma unroll
      for (int rt = 0; rt < 4; ++rt)
#pragma unroll
        for (int ct = 0; ct < 2; ++ct) {
          acc[rt][ct] = mfma16(ah[rt], bb[ct], acc[rt][ct]);
          acc[rt][ct] = mfma16(al[rt], bb[ct], acc[rt][ct]);
        }
    }
    __syncthreads();
#pragma unroll
    for (int ct = 0; ct < 2; ++ct)
#pragma unroll
      for (int rt = 0; rt < 4; ++rt)
#pragma unroll
        for (int i = 0; i < 4; ++i)
          lds_put2(XHI, XLO, rt * 16 + ro4 + i, c0 + ct * 16 + rl, 512, acc[rt][ct][i]);
  }
  __syncthreads();

  // x_att = ctx @ Wo^T + Bo (split ctx) -> f32 global
  {
    f32x4 acc[4][2] = {};
    for (int kk = 0; kk < 256; kk += 32) {
      bf16x8 ah[4], al[4], bb[2];
#pragma unroll
      for (int rt = 0; rt < 4; ++rt) {
        ah[rt] = lds_frag(XHI, rt * 16 + rl, kk + kof, 512);
        al[rt] = lds_frag(XLO, rt * 16 + rl, kk + kof, 512);
      }
#pragma unroll
      for (int ct = 0; ct < 2; ++ct)
        bb[ct] = *reinterpret_cast<const bf16x8*>(Wo + (long)(c0 + ct * 16 + rl) * 256 + kk + kof);
#pragma unroll
      for (int rt = 0; rt < 4; ++rt)
#pragma unroll
        for (int ct = 0; ct < 2; ++ct) {
          acc[rt][ct] = mfma16(ah[rt], bb[ct], acc[rt][ct]);
          acc[rt][ct] = mfma16(al[rt], bb[ct], acc[rt][ct]);
        }
    }
#pragma unroll
    for (int ct = 0; ct < 2; ++ct) {
      int c = c0 + ct * 16 + rl;
      float bv = Bo[c];
#pragma unroll
      for (int rt = 0; rt < 4; ++rt)
#pragma unroll
        for (int i = 0; i < 4; ++i)
          Xatt[(R0 + rt * 16 + ro4 + i) * 256 + c] = acc[rt][ct][i] + bv;
    }
  }
}

// ---------------------------------------------------------------------------
// x_ = relu([x | x_att] @ att_w^T + b), split operands, f32 in/out.
// ---------------------------------------------------------------------------
__global__ __launch_bounds__(256, 2) void gemm_cat(float* __restrict__ Xa,
                                                   const float* __restrict__ Xb,
                                                   const bf16_t* __restrict__ W,
                                                   const float* __restrict__ Bi) {
  __shared__ bf16_t Chi[64 * 512], Clo[64 * 512];  // 64K + 64K
  const int tid = threadIdx.x, lane = tid & 63, wv = tid >> 6;
  const int rl = lane & 15, kof = (lane >> 4) << 3, ro4 = (lane >> 4) << 2;
  const long m0 = (long)blockIdx.x * 64;
  stage_split(Chi, Clo, Xa, m0, 1024, 0, tid, 256);
  stage_split(Chi, Clo, Xb, m0, 1024, 512, tid, 256);
  __syncthreads();
  f32x4 acc[4][4] = {};
  for (int kk = 0; kk < 512; kk += 32) {
    bf16x8 ah[4], al[4], bb[4];
#pragma unroll
    for (int rt = 0; rt < 4; ++rt) {
      ah[rt] = lds_frag(Chi, rt * 16 + rl, kk + kof, 1024);
      al[rt] = lds_frag(Clo, rt * 16 + rl, kk + kof, 1024);
    }
#pragma unroll
    for (int ct = 0; ct < 4; ++ct)
      bb[ct] = *reinterpret_cast<const bf16x8*>(W + (long)(wv * 64 + ct * 16 + rl) * 512 + kk + kof);
#pragma unroll
    for (int rt = 0; rt < 4; ++rt)
#pragma unroll
      for (int ct = 0; ct < 4; ++ct) {
        acc[rt][ct] = mfma16(ah[rt], bb[ct], acc[rt][ct]);
        acc[rt][ct] = mfma16(al[rt], bb[ct], acc[rt][ct]);
      }
  }
#pragma unroll
  for (int ct = 0; ct < 4; ++ct) {
    int c = wv * 64 + ct * 16 + rl;
    float bv = Bi[c];
#pragma unroll
    for (int rt = 0; rt < 4; ++rt)
#pragma unroll
      for (int i = 0; i < 4; ++i)
        Xa[(m0 + rt * 16 + ro4 + i) * 256 + c] = fmaxf(acc[rt][ct][i] + bv, 0.f);
  }
}

// ---------------------------------------------------------------------------
// Fused GRUCell, register-frugal formulation (fits 128 VGPR, no spill):
//  - r,z gates: single accumulator for x@Wih^T + h@Whh^T (sequential phases)
//  - n gate: separate i_n / h_n (r multiplies h_n)
//  - single-bf16 operands (error << comparator ulp); 64 KB LDS -> 2 blocks/CU
// 2 M-tiles per block for weight L2 reuse.
// ---------------------------------------------------------------------------
__global__ __launch_bounds__(512) void gru_kernel(const float* __restrict__ Xf,
                                                  const float* __restrict__ Hin,
                                                  const bf16_t* __restrict__ Wih,
                                                  const bf16_t* __restrict__ Whh,
                                                  const float* __restrict__ bih,
                                                  const float* __restrict__ bhh,
                                                  float* __restrict__ Hout) {
  __shared__ bf16_t Xs[64 * 256], Hs[64 * 256];
  const int tid = threadIdx.x, lane = tid & 63, wv = tid >> 6;
  const int rl = lane & 15, kof = (lane >> 4) << 3, ro4 = (lane >> 4) << 2;
  for (int t = 0; t < 2; ++t) {
    const long m0 = ((long)blockIdx.x * 2 + t) * 64;
    if (t) __syncthreads();  // all waves done with LDS before re-stage
    stage_f32(Xs, Xf, m0, tid, 512);
    stage_f32(Hs, Hin, m0, tid, 512);
    __syncthreads();
    for (int p = 0; p < 2; ++p) {
      const int c0 = p * 128 + wv * 16;
      f32x4 aRZ[2][4] = {}, aIN[4] = {}, aHN[4] = {};
      // x-phase: accumulate x@Wih^T into r,z (merged) and i_n
      for (int kk = 0; kk < 256; kk += 32) {
        bf16x8 ax[4], bI[3];
#pragma unroll
        for (int rt = 0; rt < 4; ++rt) ax[rt] = lds_frag(Xs, rt * 16 + rl, kk + kof, 512);
#pragma unroll
        for (int g = 0; g < 3; ++g)
          bI[g] = *reinterpret_cast<const bf16x8*>(Wih + (long)(g * 256 + c0 + rl) * 256 + kk + kof);
#pragma unroll
        for (int rt = 0; rt < 4; ++rt) {
          aRZ[0][rt] = mfma16(ax[rt], bI[0], aRZ[0][rt]);
          aRZ[1][rt] = mfma16(ax[rt], bI[1], aRZ[1][rt]);
          aIN[rt]    = mfma16(ax[rt], bI[2], aIN[rt]);
        }
      }
      // h-phase: accumulate h@Whh^T into r,z (same accs) and h_n (separate)
      for (int kk = 0; kk < 256; kk += 32) {
        bf16x8 ah_[4], bH[3];
#pragma unroll
        for (int rt = 0; rt < 4; ++rt) ah_[rt] = lds_frag(Hs, rt * 16 + rl, kk + kof, 512);
#pragma unroll
        for (int g = 0; g < 3; ++g)
          bH[g] = *reinterpret_cast<const bf16x8*>(Whh + (long)(g * 256 + c0 + rl) * 256 + kk + kof);
#pragma unroll
        for (int rt = 0; rt < 4; ++rt) {
          aRZ[0][rt] = mfma16(ah_[rt], bH[0], aRZ[0][rt]);
          aRZ[1][rt] = mfma16(ah_[rt], bH[1], aRZ[1][rt]);
          aHN[rt]    = mfma16(ah_[rt], bH[2], aHN[rt]);
        }
      }
      const int c = c0 + rl;
      float br  = bih[c] + bhh[c];
      float bz  = bih[256 + c] + bhh[256 + c];
      float bin_ = bih[512 + c], bhn = bhh[512 + c];
#pragma unroll
      for (int rt = 0; rt < 4; ++rt)
#pragma unroll
        for (int i = 0; i < 4; ++i) {
          int rloc = rt * 16 + ro4 + i;
          float rg = 1.f / (1.f + __expf(-(aRZ[0][rt][i] + br)));
          float zg = 1.f / (1.f + __expf(-(aRZ[1][rt][i] + bz)));
          float nx = aIN[rt][i] + bin_ + rg * (aHN[rt][i] + bhn);
          float ng = 1.f - 2.f / (__expf(2.f * nx) + 1.f);  // tanh, saturation-safe
          float hv = Hin[(m0 + rloc) * 256 + c];
          Hout[(m0 + rloc) * 256 + c] = (1.f - zg) * ng + zg * hv;
        }
    }
  }
}

// tactic_q = h @ fc2_w^T + b, split h. 256 thr / 4 waves, 16 rows per wave.
__global__ __launch_bounds__(256, 2) void fc2_kernel(const float* __restrict__ h,
                                                     const bf16_t* __restrict__ Wt,
                                                     const float* __restrict__ bt,
                                                     float* __restrict__ out) {
  __shared__ bf16_t Hhi[64 * 256], Hlo[64 * 256];
  const int tid = threadIdx.x, lane = tid & 63, wv = tid >> 6;
  const int rl = lane & 15, kof = (lane >> 4) << 3, ro4 = (lane >> 4) << 2;
  const long m0 = (long)blockIdx.x * 64;
  stage_split(Hhi, Hlo, h, m0, 512, 0, tid, 256);
  __syncthreads();
  f32x4 acc = {};
  for (int kk = 0; kk < 256; kk += 32) {
    bf16x8 ah = lds_frag(Hhi, wv * 16 + rl, kk + kof, 512);
    bf16x8 al = lds_frag(Hlo, wv * 16 + rl, kk + kof, 512);
    bf16x8 bb = *reinterpret_cast<const bf16x8*>(Wt + (long)rl * 256 + kk + kof);
    acc = mfma16(ah, bb, acc);
    acc = mfma16(al, bb, acc);
  }
  float bv = bt[rl];
#pragma unroll
  for (int i = 0; i < 4; ++i) out[(m0 + wv * 16 + ro4 + i) * 16 + rl] = acc[i] + bv;
}

// int32 bool -> f32 {0,1} copy, 4 elems/thread
__global__ __launch_bounds__(256) void drop_copy(const int* __restrict__ d,
                                                 float* __restrict__ o) {
  long i = (long)blockIdx.x * 256 + threadIdx.x;
  int4 v = reinterpret_cast<const int4*>(d)[i];
  float4 r;
  r.x = v.x ? 1.f : 0.f;
  r.y = v.y ? 1.f : 0.f;
  r.z = v.z ? 1.f : 0.f;
  r.w = v.w ? 1.f : 0.f;
  reinterpret_cast<float4*>(o)[i] = r;
}

extern "C" void kernel_launch(void* const* d_in, const int* in_sizes, int n_in,
                              void* d_out, int out_size, void* d_ws, size_t ws_size,
                              hipStream_t stream) {
  (void)in_sizes; (void)n_in; (void)out_size; (void)ws_size;
  const float* inputs      = (const float*)d_in[0];
  const float* hidden      = (const float*)d_in[1];
  const int*   drp         = (const int*)d_in[2];   // bool pushed as int32
  // d_in[3] = t (unused)
  const float* fc_gru_w    = (const float*)d_in[4];
  const float* fc_gru_b    = (const float*)d_in[5];
  const float* in_proj_w   = (const float*)d_in[6];
  const float* in_proj_b   = (const float*)d_in[7];
  const float* out_proj_w  = (const float*)d_in[8];
  const float* out_proj_b  = (const float*)d_in[9];
  const float* att_w       = (const float*)d_in[10];
  const float* att_b       = (const float*)d_in[11];
  const float* gru_wih     = (const float*)d_in[12];
  const float* gru_whh     = (const float*)d_in[13];
  const float* gru_bih     = (const float*)d_in[14];
  const float* gru_bhh     = (const float*)d_in[15];
  const float* fc2_w       = (const float*)d_in[16];
  const float* fc2_b       = (const float*)d_in[17];

  float* out_t = (float*)d_out;          // [M,16]
  float* out_h = out_t + MTOT * 16;      // [M,256] f32: x_att, then h
  float* out_d = out_h + MTOT * 256;     // [B*64*64] f32

  float*  A  = (float*)d_ws;             // [M,256] f32: x, then x_   (128 MB)
  bf16_t* Wb = (bf16_t*)(A + MTOT * 256);  // bf16 weights (1.7 MB)

  // 0) weights f32 -> bf16
  cvt_weights<<<836, 256, 0, stream>>>(fc_gru_w, in_proj_w, out_proj_w, att_w,
                                       gru_wih, gru_whh, fc2_w, Wb);
  // 1) x = relu(inputs @ fc_gru_w^T + b) -> A (f32)
  gemm1<<<2048, 256, 0, stream>>>(inputs, Wb, fc_gru_b, A);
  // 2) fused attention: x -> x_att (f32, parked in out_h)
  attn_kernel<<<2048, 512, 0, stream>>>(A, out_h, Wb + 65536, in_proj_b,
                                        Wb + 262144, out_proj_b, drp);
  // 3) x_ = relu([x | x_att] @ att_w^T + b) -> A (f32, in-place)
  gemm_cat<<<2048, 256, 0, stream>>>(A, out_h, Wb + 327680, att_b);
  // 4) GRU: x_ (A) + hidden -> h -> out_h (f32, overwrites x_att); 2 tiles/block
  gru_kernel<<<1024, 512, 0, stream>>>(A, hidden, Wb + 458752, Wb + 655360,
                                       gru_bih, gru_bhh, out_h);
  // 5) tactic_q = h @ fc2_w^T + b -> out_t
  fc2_kernel<<<2048, 256, 0, stream>>>(out_h, Wb + 851968, fc2_b, out_t);
  // 6) drop mask echo as f32 (8388608 elems / 4 per thread / 256 = 8192 blocks)
  drop_copy<<<8192, 256, 0, stream>>>(drp, out_d);
}

// Round 9
// 1810.731 us; speedup vs baseline: 1.0206x; 1.0206x over previous
//
#include <hip/hip_runtime.h>

typedef __bf16 bf16_t;
using bf16x8 = __bf16 __attribute__((ext_vector_type(8)));
using f32x4  = float __attribute__((ext_vector_type(4)));

// B=2048, N=64, D=256, H=256, T=16
static constexpr long MTOT = 131072;   // B*N

__device__ __forceinline__ f32x4 mfma16(bf16x8 a, bf16x8 b, f32x4 c) {
  return __builtin_amdgcn_mfma_f32_16x16x32_bf16(a, b, c, 0, 0, 0);
}

// Swizzled LDS tiles: element (row,k) at byte row*rowBytes + ((k*2 + colOff) ^ ((row&7)<<4)).
__device__ __forceinline__ bf16x8 lds_frag(const bf16_t* base, int row, int k, int rowBytes) {
  int byte = row * rowBytes + ((k << 1) ^ ((row & 7) << 4));
  return *reinterpret_cast<const bf16x8*>(reinterpret_cast<const char*>(base) + byte);
}
__device__ __forceinline__ float lds_get1(const bf16_t* base, int row, int col, int rowBytes) {
  int byte = row * rowBytes + ((col << 1) ^ ((row & 7) << 4));
  return (float)*reinterpret_cast<const bf16_t*>(reinterpret_cast<const char*>(base) + byte);
}
__device__ __forceinline__ void lds_put(bf16_t* base, int row, int col, int rowBytes, float v) {
  int byte = row * rowBytes + ((col << 1) ^ ((row & 7) << 4));
  *reinterpret_cast<bf16_t*>(reinterpret_cast<char*>(base) + byte) = (bf16_t)v;
}
__device__ __forceinline__ void lds_put2(bf16_t* hi, bf16_t* lo, int row, int col,
                                         int rowBytes, float v) {
  int byte = row * rowBytes + ((col << 1) ^ ((row & 7) << 4));
  bf16_t h = (bf16_t)v;
  bf16_t l = (bf16_t)(v - (float)h);
  *reinterpret_cast<bf16_t*>(reinterpret_cast<char*>(hi) + byte) = h;
  *reinterpret_cast<bf16_t*>(reinterpret_cast<char*>(lo) + byte) = l;
}

// Stage a [64 x 256] f32 tile (lda=256) -> split hi/lo bf16 swizzled LDS tiles.
__device__ __forceinline__ void stage_split(bf16_t* hi, bf16_t* lo, const float* src,
                                            long row0, int rowBytesLds, int colOffBytes,
                                            int tid, int nthr) {
  for (int e = tid * 4; e < 64 * 256; e += nthr * 4) {
    int r = e >> 8, c = e & 255;
    float4 v = *reinterpret_cast<const float4*>(src + (row0 + r) * 256 + c);
    bf16_t h4[4], l4[4];
    h4[0] = (bf16_t)v.x; l4[0] = (bf16_t)(v.x - (float)h4[0]);
    h4[1] = (bf16_t)v.y; l4[1] = (bf16_t)(v.y - (float)h4[1]);
    h4[2] = (bf16_t)v.z; l4[2] = (bf16_t)(v.z - (float)h4[2]);
    h4[3] = (bf16_t)v.w; l4[3] = (bf16_t)(v.w - (float)h4[3]);
    int db = r * rowBytesLds + (((c << 1) + colOffBytes) ^ ((r & 7) << 4));
    *reinterpret_cast<uint2*>(reinterpret_cast<char*>(hi) + db) = *reinterpret_cast<const uint2*>(h4);
    *reinterpret_cast<uint2*>(reinterpret_cast<char*>(lo) + db) = *reinterpret_cast<const uint2*>(l4);
  }
}

// Stage a [64 x 256] f32 tile -> single bf16 swizzled LDS (rowBytes=512).
__device__ __forceinline__ void stage_f32(bf16_t* lds, const float* src, long row0,
                                          int tid, int nthr) {
  for (int e = tid * 4; e < 64 * 256; e += nthr * 4) {
    int r = e >> 8, c = e & 255;
    float4 v = *reinterpret_cast<const float4*>(src + (row0 + r) * 256 + c);
    bf16_t t4[4] = {(bf16_t)v.x, (bf16_t)v.y, (bf16_t)v.z, (bf16_t)v.w};
    int db = r * 512 + ((c << 1) ^ ((r & 7) << 4));
    *reinterpret_cast<uint2*>(reinterpret_cast<char*>(lds) + db) =
        *reinterpret_cast<const uint2*>(t4);
  }
}

// ---------------------------------------------------------------------------
// Weights f32 -> bf16 in ws. Offsets (elements): fc_gru_w 0, in_proj_w 65536,
// out_proj_w 262144, att_w 327680, gru_wih 458752, gru_whh 655360, fc2_w 851968.
// ---------------------------------------------------------------------------
__global__ __launch_bounds__(256) void cvt_weights(const float* __restrict__ w0,
                                                   const float* __restrict__ w1,
                                                   const float* __restrict__ w2,
                                                   const float* __restrict__ w3,
                                                   const float* __restrict__ w4,
                                                   const float* __restrict__ w5,
                                                   const float* __restrict__ w6,
                                                   bf16_t* __restrict__ dst) {
  long e = ((long)blockIdx.x * 256 + threadIdx.x) * 4;
  const float* src; long off;
  if (e < 65536)       { src = w0; off = 0; }
  else if (e < 262144) { src = w1; off = 65536; }
  else if (e < 327680) { src = w2; off = 262144; }
  else if (e < 458752) { src = w3; off = 327680; }
  else if (e < 655360) { src = w4; off = 458752; }
  else if (e < 851968) { src = w5; off = 655360; }
  else                 { src = w6; off = 851968; }
  float4 v = *reinterpret_cast<const float4*>(src + (e - off));
  bf16_t o[4] = {(bf16_t)v.x, (bf16_t)v.y, (bf16_t)v.z, (bf16_t)v.w};
  *reinterpret_cast<uint2*>(dst + e) = *reinterpret_cast<const uint2*>(o);
}

// ---------------------------------------------------------------------------
// x = relu(inputs @ fc_gru_w^T + b): f32 in (split), f32 out. Tile 64x256.
// ---------------------------------------------------------------------------
__global__ __launch_bounds__(256, 2) void gemm1(const float* __restrict__ X,
                                                const bf16_t* __restrict__ W,
                                                const float* __restrict__ Bi,
                                                float* __restrict__ C) {
  __shared__ bf16_t Ihi[64 * 256], Ilo[64 * 256];
  const int tid = threadIdx.x, lane = tid & 63, wv = tid >> 6;
  const int rl = lane & 15, kof = (lane >> 4) << 3, ro4 = (lane >> 4) << 2;
  const long m0 = (long)blockIdx.x * 64;
  stage_split(Ihi, Ilo, X, m0, 512, 0, tid, 256);
  __syncthreads();
  f32x4 acc[4][4] = {};
  for (int kk = 0; kk < 256; kk += 32) {
    bf16x8 ah[4], al[4], bb[4];
#pragma unroll
    for (int rt = 0; rt < 4; ++rt) {
      ah[rt] = lds_frag(Ihi, rt * 16 + rl, kk + kof, 512);
      al[rt] = lds_frag(Ilo, rt * 16 + rl, kk + kof, 512);
    }
#pragma unroll
    for (int ct = 0; ct < 4; ++ct)
      bb[ct] = *reinterpret_cast<const bf16x8*>(W + (long)(wv * 64 + ct * 16 + rl) * 256 + kk + kof);
#pragma unroll
    for (int rt = 0; rt < 4; ++rt)
#pragma unroll
      for (int ct = 0; ct < 4; ++ct) {
        acc[rt][ct] = mfma16(ah[rt], bb[ct], acc[rt][ct]);
        acc[rt][ct] = mfma16(al[rt], bb[ct], acc[rt][ct]);
      }
  }
#pragma unroll
  for (int ct = 0; ct < 4; ++ct) {
    int c = wv * 64 + ct * 16 + rl;
    float bv = Bi[c];
#pragma unroll
    for (int rt = 0; rt < 4; ++rt)
#pragma unroll
      for (int i = 0; i < 4; ++i)
        C[(m0 + rt * 16 + ro4 + i) * 256 + c] = fmaxf(acc[rt][ct][i] + bv, 0.f);
  }
}

// ---------------------------------------------------------------------------
// Fused per-sample attention, split-precision. Block = 1 sample, 512 thr/8 waves.
// Reads x (f32 [M,256]), writes x_att (f32 [M,256]). Mask is INT32 (bool->int).
// ---------------------------------------------------------------------------
__global__ __launch_bounds__(512, 2) void attn_kernel(const float* __restrict__ Xf,
                                                      float* __restrict__ Xatt,
                                                      const bf16_t* __restrict__ Wqkv,
                                                      const float* __restrict__ Bqkv,
                                                      const bf16_t* __restrict__ Wo,
                                                      const float* __restrict__ Bo,
                                                      const int* __restrict__ drop) {
  __shared__ __align__(16) char buf[147456];
  bf16_t* XHI = reinterpret_cast<bf16_t*>(buf);            // 32K, swz rowBytes 512
  bf16_t* XLO = reinterpret_cast<bf16_t*>(buf + 32768);    // 32K
  bf16_t* QS  = reinterpret_cast<bf16_t*>(buf + 65536);    // 32K, swz 512; later V^T swz 128
  bf16_t* KS  = reinterpret_cast<bf16_t*>(buf + 98304);    // 32K, swz 512; later PHI/PLO swz 128
  bf16_t* PHI = KS;                                        // 8K  [64][64]
  bf16_t* PLO = reinterpret_cast<bf16_t*>(buf + 98304 + 8192);
  float*  SS  = reinterpret_cast<float*>(buf + 131072);    // 16K [64][64]
  const int tid = threadIdx.x, lane = tid & 63, wv = tid >> 6;
  const int rl = lane & 15, kof = (lane >> 4) << 3, ro4 = (lane >> 4) << 2;
  const int b = blockIdx.x;
  const long R0 = (long)b * 64;
  stage_split(XHI, XLO, Xf, R0, 512, 0, tid, 512);
  __syncthreads();
  const int c0 = wv * 32;

  // q and k GEMMs (split x) -> bf16 swizzled LDS
  for (int which = 0; which < 2; ++which) {
    const bf16_t* Wp = Wqkv + (long)which * 65536;
    bf16_t* outp = which ? KS : QS;
    f32x4 acc[4][2] = {};
    for (int kk = 0; kk < 256; kk += 32) {
      bf16x8 ah[4], al[4], bb[2];
#pragma unroll
      for (int rt = 0; rt < 4; ++rt) {
        ah[rt] = lds_frag(XHI, rt * 16 + rl, kk + kof, 512);
        al[rt] = lds_frag(XLO, rt * 16 + rl, kk + kof, 512);
      }
#pragma unroll
      for (int ct = 0; ct < 2; ++ct)
        bb[ct] = *reinterpret_cast<const bf16x8*>(Wp + (long)(c0 + ct * 16 + rl) * 256 + kk + kof);
#pragma unroll
      for (int rt = 0; rt < 4; ++rt)
#pragma unroll
        for (int ct = 0; ct < 2; ++ct) {
          acc[rt][ct] = mfma16(ah[rt], bb[ct], acc[rt][ct]);
          acc[rt][ct] = mfma16(al[rt], bb[ct], acc[rt][ct]);
        }
    }
#pragma unroll
    for (int ct = 0; ct < 2; ++ct) {
      int c = c0 + ct * 16 + rl;
      float bv = Bqkv[which * 256 + c];
#pragma unroll
      for (int rt = 0; rt < 4; ++rt)
#pragma unroll
        for (int i = 0; i < 4; ++i) lds_put(outp, rt * 16 + ro4 + i, c, 512, acc[rt][ct][i] + bv);
    }
  }
  __syncthreads();

  // scores = q k^T * scale, masked (int32 mask) -> SS f32
  {
    const int rt0 = (wv & 3) * 16, sc0 = (wv >> 2) * 32;
    f32x4 acc[2] = {};
    for (int kk = 0; kk < 256; kk += 32) {
      bf16x8 a = lds_frag(QS, rt0 + rl, kk + kof, 512);
#pragma unroll
      for (int ct = 0; ct < 2; ++ct) {
        bf16x8 bb = lds_frag(KS, sc0 + ct * 16 + rl, kk + kof, 512);
        acc[ct] = mfma16(a, bb, acc[ct]);
      }
    }
#pragma unroll
    for (int ct = 0; ct < 2; ++ct)
#pragma unroll
      for (int i = 0; i < 4; ++i) {
        int rr = rt0 + ro4 + i, cc = sc0 + ct * 16 + rl;
        float s = acc[ct][i] * 0.0625f;
        if (drop[(long)b * 4096 + rr * 64 + cc]) s = -1e9f;
        SS[rr * 64 + cc] = s;
      }
  }
  __syncthreads();

  // v GEMM (split x) -> V^T [256][64] bf16 over Q region (q dead)
  {
    const bf16_t* Wp = Wqkv + (long)2 * 65536;
    f32x4 acc[4][2] = {};
    for (int kk = 0; kk < 256; kk += 32) {
      bf16x8 ah[4], al[4], bb[2];
#pragma unroll
      for (int rt = 0; rt < 4; ++rt) {
        ah[rt] = lds_frag(XHI, rt * 16 + rl, kk + kof, 512);
        al[rt] = lds_frag(XLO, rt * 16 + rl, kk + kof, 512);
      }
#pragma unroll
      for (int ct = 0; ct < 2; ++ct)
        bb[ct] = *reinterpret_cast<const bf16x8*>(Wp + (long)(c0 + ct * 16 + rl) * 256 + kk + kof);
#pragma unroll
      for (int rt = 0; rt < 4; ++rt)
#pragma unroll
        for (int ct = 0; ct < 2; ++ct) {
          acc[rt][ct] = mfma16(ah[rt], bb[ct], acc[rt][ct]);
          acc[rt][ct] = mfma16(al[rt], bb[ct], acc[rt][ct]);
        }
    }
#pragma unroll
    for (int ct = 0; ct < 2; ++ct) {
      int c = c0 + ct * 16 + rl;
      float bv = Bqkv[512 + c];
#pragma unroll
      for (int rt = 0; rt < 4; ++rt)
#pragma unroll
        for (int i = 0; i < 4; ++i) {
          int j = rt * 16 + ro4 + i;                    // agent (key) index
          lds_put(QS, c, j, 128, acc[rt][ct][i] + bv);  // V^T[c][j]
        }
    }
  }
  // wave-parallel softmax -> split P over K region (k dead)
  for (int j = 0; j < 8; ++j) {
    int rr = wv * 8 + j;
    float s = SS[rr * 64 + lane];
    float m = s;
#pragma unroll
    for (int off = 32; off >= 1; off >>= 1) m = fmaxf(m, __shfl_xor(m, off));
    float e = __expf(s - m);
    float sum = e;
#pragma unroll
    for (int off = 32; off >= 1; off >>= 1) sum += __shfl_xor(sum, off);
    lds_put2(PHI, PLO, rr, lane, 128, e / sum);
  }
  __syncthreads();

  // ctx = P @ V (split P) -> split ctx over X region (x dead)
  {
    f32x4 acc[4][2] = {};
    for (int kk = 0; kk < 64; kk += 32) {
      bf16x8 ah[4], al[4], bb[2];
#pragma unroll
      for (int rt = 0; rt < 4; ++rt) {
        ah[rt] = lds_frag(PHI, rt * 16 + rl, kk + kof, 128);
        al[rt] = lds_frag(PLO, rt * 16 + rl, kk + kof, 128);
      }
#pragma unroll
      for (int ct = 0; ct < 2; ++ct) bb[ct] = lds_frag(QS, c0 + ct * 16 + rl, kk + kof, 128);
#pragma unroll
      for (int rt = 0; rt < 4; ++rt)
#pragma unroll
        for (int ct = 0; ct < 2; ++ct) {
          acc[rt][ct] = mfma16(ah[rt], bb[ct], acc[rt][ct]);
          acc[rt][ct] = mfma16(al[rt], bb[ct], acc[rt][ct]);
        }
    }
    __syncthreads();
#pragma unroll
    for (int ct = 0; ct < 2; ++ct)
#pragma unroll
      for (int rt = 0; rt < 4; ++rt)
#pragma unroll
        for (int i = 0; i < 4; ++i)
          lds_put2(XHI, XLO, rt * 16 + ro4 + i, c0 + ct * 16 + rl, 512, acc[rt][ct][i]);
  }
  __syncthreads();

  // x_att = ctx @ Wo^T + Bo (split ctx) -> f32 global
  {
    f32x4 acc[4][2] = {};
    for (int kk = 0; kk < 256; kk += 32) {
      bf16x8 ah[4], al[4], bb[2];
#pragma unroll
      for (int rt = 0; rt < 4; ++rt) {
        ah[rt] = lds_frag(XHI, rt * 16 + rl, kk + kof, 512);
        al[rt] = lds_frag(XLO, rt * 16 + rl, kk + kof, 512);
      }
#pragma unroll
      for (int ct = 0; ct < 2; ++ct)
        bb[ct] = *reinterpret_cast<const bf16x8*>(Wo + (long)(c0 + ct * 16 + rl) * 256 + kk + kof);
#pragma unroll
      for (int rt = 0; rt < 4; ++rt)
#pragma unroll
        for (int ct = 0; ct < 2; ++ct) {
          acc[rt][ct] = mfma16(ah[rt], bb[ct], acc[rt][ct]);
          acc[rt][ct] = mfma16(al[rt], bb[ct], acc[rt][ct]);
        }
    }
#pragma unroll
    for (int ct = 0; ct < 2; ++ct) {
      int c = c0 + ct * 16 + rl;
      float bv = Bo[c];
#pragma unroll
      for (int rt = 0; rt < 4; ++rt)
#pragma unroll
        for (int i = 0; i < 4; ++i)
          Xatt[(R0 + rt * 16 + ro4 + i) * 256 + c] = acc[rt][ct][i] + bv;
    }
  }
}

// ---------------------------------------------------------------------------
// x_ = relu([x | x_att] @ att_w^T + b), split operands, f32 in/out.
// ---------------------------------------------------------------------------
__global__ __launch_bounds__(256, 2) void gemm_cat(float* __restrict__ Xa,
                                                   const float* __restrict__ Xb,
                                                   const bf16_t* __restrict__ W,
                                                   const float* __restrict__ Bi) {
  __shared__ bf16_t Chi[64 * 512], Clo[64 * 512];  // 64K + 64K
  const int tid = threadIdx.x, lane = tid & 63, wv = tid >> 6;
  const int rl = lane & 15, kof = (lane >> 4) << 3, ro4 = (lane >> 4) << 2;
  const long m0 = (long)blockIdx.x * 64;
  stage_split(Chi, Clo, Xa, m0, 1024, 0, tid, 256);
  stage_split(Chi, Clo, Xb, m0, 1024, 512, tid, 256);
  __syncthreads();
  f32x4 acc[4][4] = {};
  for (int kk = 0; kk < 512; kk += 32) {
    bf16x8 ah[4], al[4], bb[4];
#pragma unroll
    for (int rt = 0; rt < 4; ++rt) {
      ah[rt] = lds_frag(Chi, rt * 16 + rl, kk + kof, 1024);
      al[rt] = lds_frag(Clo, rt * 16 + rl, kk + kof, 1024);
    }
#pragma unroll
    for (int ct = 0; ct < 4; ++ct)
      bb[ct] = *reinterpret_cast<const bf16x8*>(W + (long)(wv * 64 + ct * 16 + rl) * 512 + kk + kof);
#pragma unroll
    for (int rt = 0; rt < 4; ++rt)
#pragma unroll
      for (int ct = 0; ct < 4; ++ct) {
        acc[rt][ct] = mfma16(ah[rt], bb[ct], acc[rt][ct]);
        acc[rt][ct] = mfma16(al[rt], bb[ct], acc[rt][ct]);
      }
  }
#pragma unroll
  for (int ct = 0; ct < 4; ++ct) {
    int c = wv * 64 + ct * 16 + rl;
    float bv = Bi[c];
#pragma unroll
    for (int rt = 0; rt < 4; ++rt)
#pragma unroll
      for (int i = 0; i < 4; ++i)
        Xa[(m0 + rt * 16 + ro4 + i) * 256 + c] = fmaxf(acc[rt][ct][i] + bv, 0.f);
  }
}

// ---------------------------------------------------------------------------
// Fused GRUCell, register-frugal. Key fix vs r8: epilogue reads h_in from the
// staged LDS tile (bf16) instead of 16 per-lane global loads -- that global-load
// burst + live accumulators was the spill source (WRITE_SIZE 1.46GB vs 128MB
// legit). 4 M-tiles/block for weight L2 locality. 64 KB LDS -> 2 blocks/CU.
// ---------------------------------------------------------------------------
__global__ __launch_bounds__(512) void gru_kernel(const float* __restrict__ Xf,
                                                  const float* __restrict__ Hin,
                                                  const bf16_t* __restrict__ Wih,
                                                  const bf16_t* __restrict__ Whh,
                                                  const float* __restrict__ bih,
                                                  const float* __restrict__ bhh,
                                                  float* __restrict__ Hout) {
  __shared__ bf16_t Xs[64 * 256], Hs[64 * 256];
  const int tid = threadIdx.x, lane = tid & 63, wv = tid >> 6;
  const int rl = lane & 15, kof = (lane >> 4) << 3, ro4 = (lane >> 4) << 2;
  for (int t = 0; t < 4; ++t) {
    const long m0 = ((long)blockIdx.x * 4 + t) * 64;
    if (t) __syncthreads();  // all waves done with LDS before re-stage
    stage_f32(Xs, Xf, m0, tid, 512);
    stage_f32(Hs, Hin, m0, tid, 512);
    __syncthreads();
    for (int p = 0; p < 2; ++p) {
      const int c0 = p * 128 + wv * 16;
      f32x4 aRZ[2][4] = {}, aIN[4] = {}, aHN[4] = {};
      // x-phase: accumulate x@Wih^T into r,z (merged) and i_n
      for (int kk = 0; kk < 256; kk += 32) {
        bf16x8 ax[4], bI[3];
#pragma unroll
        for (int rt = 0; rt < 4; ++rt) ax[rt] = lds_frag(Xs, rt * 16 + rl, kk + kof, 512);
#pragma unroll
        for (int g = 0; g < 3; ++g)
          bI[g] = *reinterpret_cast<const bf16x8*>(Wih + (long)(g * 256 + c0 + rl) * 256 + kk + kof);
#pragma unroll
        for (int rt = 0; rt < 4; ++rt) {
          aRZ[0][rt] = mfma16(ax[rt], bI[0], aRZ[0][rt]);
          aRZ[1][rt] = mfma16(ax[rt], bI[1], aRZ[1][rt]);
          aIN[rt]    = mfma16(ax[rt], bI[2], aIN[rt]);
        }
      }
      // h-phase: accumulate h@Whh^T into r,z (same accs) and h_n (separate)
      for (int kk = 0; kk < 256; kk += 32) {
        bf16x8 ah_[4], bH[3];
#pragma unroll
        for (int rt = 0; rt < 4; ++rt) ah_[rt] = lds_frag(Hs, rt * 16 + rl, kk + kof, 512);
#pragma unroll
        for (int g = 0; g < 3; ++g)
          bH[g] = *reinterpret_cast<const bf16x8*>(Whh + (long)(g * 256 + c0 + rl) * 256 + kk + kof);
#pragma unroll
        for (int rt = 0; rt < 4; ++rt) {
          aRZ[0][rt] = mfma16(ah_[rt], bH[0], aRZ[0][rt]);
          aRZ[1][rt] = mfma16(ah_[rt], bH[1], aRZ[1][rt]);
          aHN[rt]    = mfma16(ah_[rt], bH[2], aHN[rt]);
        }
      }
      const int c = c0 + rl;
      float br  = bih[c] + bhh[c];
      float bz  = bih[256 + c] + bhh[256 + c];
      float bin_ = bih[512 + c], bhn = bhh[512 + c];
#pragma unroll
      for (int rt = 0; rt < 4; ++rt)
#pragma unroll
        for (int i = 0; i < 4; ++i) {
          int rloc = rt * 16 + ro4 + i;
          float rg = 1.f / (1.f + __expf(-(aRZ[0][rt][i] + br)));
          float zg = 1.f / (1.f + __expf(-(aRZ[1][rt][i] + bz)));
          float nx = aIN[rt][i] + bin_ + rg * (aHN[rt][i] + bhn);
          float ng = 1.f - 2.f / (__expf(2.f * nx) + 1.f);  // tanh, saturation-safe
          float hv = lds_get1(Hs, rloc, c, 512);            // h_in from LDS (bf16)
          Hout[(m0 + rloc) * 256 + c] = (1.f - zg) * ng + zg * hv;
        }
    }
  }
}

// tactic_q = h @ fc2_w^T + b, split h. 256 thr / 4 waves, 16 rows per wave.
__global__ __launch_bounds__(256, 2) void fc2_kernel(const float* __restrict__ h,
                                                     const bf16_t* __restrict__ Wt,
                                                     const float* __restrict__ bt,
                                                     float* __restrict__ out) {
  __shared__ bf16_t Hhi[64 * 256], Hlo[64 * 256];
  const int tid = threadIdx.x, lane = tid & 63, wv = tid >> 6;
  const int rl = lane & 15, kof = (lane >> 4) << 3, ro4 = (lane >> 4) << 2;
  const long m0 = (long)blockIdx.x * 64;
  stage_split(Hhi, Hlo, h, m0, 512, 0, tid, 256);
  __syncthreads();
  f32x4 acc = {};
  for (int kk = 0; kk < 256; kk += 32) {
    bf16x8 ah = lds_frag(Hhi, wv * 16 + rl, kk + kof, 512);
    bf16x8 al = lds_frag(Hlo, wv * 16 + rl, kk + kof, 512);
    bf16x8 bb = *reinterpret_cast<const bf16x8*>(Wt + (long)rl * 256 + kk + kof);
    acc = mfma16(ah, bb, acc);
    acc = mfma16(al, bb, acc);
  }
  float bv = bt[rl];
#pragma unroll
  for (int i = 0; i < 4; ++i) out[(m0 + wv * 16 + ro4 + i) * 16 + rl] = acc[i] + bv;
}

// int32 bool -> f32 {0,1} copy, 4 elems/thread
__global__ __launch_bounds__(256) void drop_copy(const int* __restrict__ d,
                                                 float* __restrict__ o) {
  long i = (long)blockIdx.x * 256 + threadIdx.x;
  int4 v = reinterpret_cast<const int4*>(d)[i];
  float4 r;
  r.x = v.x ? 1.f : 0.f;
  r.y = v.y ? 1.f : 0.f;
  r.z = v.z ? 1.f : 0.f;
  r.w = v.w ? 1.f : 0.f;
  reinterpret_cast<float4*>(o)[i] = r;
}

extern "C" void kernel_launch(void* const* d_in, const int* in_sizes, int n_in,
                              void* d_out, int out_size, void* d_ws, size_t ws_size,
                              hipStream_t stream) {
  (void)in_sizes; (void)n_in; (void)out_size; (void)ws_size;
  const float* inputs      = (const float*)d_in[0];
  const float* hidden      = (const float*)d_in[1];
  const int*   drp         = (const int*)d_in[2];   // bool pushed as int32
  // d_in[3] = t (unused)
  const float* fc_gru_w    = (const float*)d_in[4];
  const float* fc_gru_b    = (const float*)d_in[5];
  const float* in_proj_w   = (const float*)d_in[6];
  const float* in_proj_b   = (const float*)d_in[7];
  const float* out_proj_w  = (const float*)d_in[8];
  const float* out_proj_b  = (const float*)d_in[9];
  const float* att_w       = (const float*)d_in[10];
  const float* att_b       = (const float*)d_in[11];
  const float* gru_wih     = (const float*)d_in[12];
  const float* gru_whh     = (const float*)d_in[13];
  const float* gru_bih     = (const float*)d_in[14];
  const float* gru_bhh     = (const float*)d_in[15];
  const float* fc2_w       = (const float*)d_in[16];
  const float* fc2_b       = (const float*)d_in[17];

  float* out_t = (float*)d_out;          // [M,16]
  float* out_h = out_t + MTOT * 16;      // [M,256] f32: x_att, then h
  float* out_d = out_h + MTOT * 256;     // [B*64*64] f32

  float*  A  = (float*)d_ws;             // [M,256] f32: x, then x_   (128 MB)
  bf16_t* Wb = (bf16_t*)(A + MTOT * 256);  // bf16 weights (1.7 MB)

  // 0) weights f32 -> bf16
  cvt_weights<<<836, 256, 0, stream>>>(fc_gru_w, in_proj_w, out_proj_w, att_w,
                                       gru_wih, gru_whh, fc2_w, Wb);
  // 1) x = relu(inputs @ fc_gru_w^T + b) -> A (f32)
  gemm1<<<2048, 256, 0, stream>>>(inputs, Wb, fc_gru_b, A);
  // 2) fused attention: x -> x_att (f32, parked in out_h)
  attn_kernel<<<2048, 512, 0, stream>>>(A, out_h, Wb + 65536, in_proj_b,
                                        Wb + 262144, out_proj_b, drp);
  // 3) x_ = relu([x | x_att] @ att_w^T + b) -> A (f32, in-place)
  gemm_cat<<<2048, 256, 0, stream>>>(A, out_h, Wb + 327680, att_b);
  // 4) GRU: x_ (A) + hidden -> h -> out_h (f32, overwrites x_att); 4 tiles/block
  gru_kernel<<<512, 512, 0, stream>>>(A, hidden, Wb + 458752, Wb + 655360,
                                      gru_bih, gru_bhh, out_h);
  // 5) tactic_q = h @ fc2_w^T + b -> out_t
  fc2_kernel<<<2048, 256, 0, stream>>>(out_h, Wb + 851968, fc2_b, out_t);
  // 6) drop mask echo as f32 (8388608 elems / 4 per thread / 256 = 8192 blocks)
  drop_copy<<<8192, 256, 0, stream>>>(drp, out_d);
}

// Round 10
// 1038.989 us; speedup vs baseline: 1.7787x; 1.7428x over previous
//
#include <hip/hip_runtime.h>

typedef __bf16 bf16_t;
using bf16x8 = __bf16 __attribute__((ext_vector_type(8)));
using f32x4  = float __attribute__((ext_vector_type(4)));

// B=2048, N=64, D=256, H=256, T=16
static constexpr long MTOT = 131072;   // B*N

__device__ __forceinline__ f32x4 mfma16(bf16x8 a, bf16x8 b, f32x4 c) {
  return __builtin_amdgcn_mfma_f32_16x16x32_bf16(a, b, c, 0, 0, 0);
}

// Swizzled LDS tiles: element (row,k) at byte row*rowBytes + ((k*2 + colOff) ^ ((row&7)<<4)).
__device__ __forceinline__ bf16x8 lds_frag(const bf16_t* base, int row, int k, int rowBytes) {
  int byte = row * rowBytes + ((k << 1) ^ ((row & 7) << 4));
  return *reinterpret_cast<const bf16x8*>(reinterpret_cast<const char*>(base) + byte);
}
__device__ __forceinline__ float lds_get1(const bf16_t* base, int row, int col, int rowBytes) {
  int byte = row * rowBytes + ((col << 1) ^ ((row & 7) << 4));
  return (float)*reinterpret_cast<const bf16_t*>(reinterpret_cast<const char*>(base) + byte);
}
__device__ __forceinline__ void lds_put(bf16_t* base, int row, int col, int rowBytes, float v) {
  int byte = row * rowBytes + ((col << 1) ^ ((row & 7) << 4));
  *reinterpret_cast<bf16_t*>(reinterpret_cast<char*>(base) + byte) = (bf16_t)v;
}
__device__ __forceinline__ void lds_put2(bf16_t* hi, bf16_t* lo, int row, int col,
                                         int rowBytes, float v) {
  int byte = row * rowBytes + ((col << 1) ^ ((row & 7) << 4));
  bf16_t h = (bf16_t)v;
  bf16_t l = (bf16_t)(v - (float)h);
  *reinterpret_cast<bf16_t*>(reinterpret_cast<char*>(hi) + byte) = h;
  *reinterpret_cast<bf16_t*>(reinterpret_cast<char*>(lo) + byte) = l;
}

// Stage a [64 x 256] f32 tile (lda=256) -> split hi/lo bf16 swizzled LDS tiles.
__device__ __forceinline__ void stage_split(bf16_t* hi, bf16_t* lo, const float* src,
                                            long row0, int rowBytesLds, int colOffBytes,
                                            int tid, int nthr) {
  for (int e = tid * 4; e < 64 * 256; e += nthr * 4) {
    int r = e >> 8, c = e & 255;
    float4 v = *reinterpret_cast<const float4*>(src + (row0 + r) * 256 + c);
    bf16_t h4[4], l4[4];
    h4[0] = (bf16_t)v.x; l4[0] = (bf16_t)(v.x - (float)h4[0]);
    h4[1] = (bf16_t)v.y; l4[1] = (bf16_t)(v.y - (float)h4[1]);
    h4[2] = (bf16_t)v.z; l4[2] = (bf16_t)(v.z - (float)h4[2]);
    h4[3] = (bf16_t)v.w; l4[3] = (bf16_t)(v.w - (float)h4[3]);
    int db = r * rowBytesLds + (((c << 1) + colOffBytes) ^ ((r & 7) << 4));
    *reinterpret_cast<uint2*>(reinterpret_cast<char*>(hi) + db) = *reinterpret_cast<const uint2*>(h4);
    *reinterpret_cast<uint2*>(reinterpret_cast<char*>(lo) + db) = *reinterpret_cast<const uint2*>(l4);
  }
}

// Stage a [64 x 256] f32 tile -> single bf16 swizzled LDS (rowBytes=512).
__device__ __forceinline__ void stage_f32(bf16_t* lds, const float* src, long row0,
                                          int tid, int nthr) {
  for (int e = tid * 4; e < 64 * 256; e += nthr * 4) {
    int r = e >> 8, c = e & 255;
    float4 v = *reinterpret_cast<const float4*>(src + (row0 + r) * 256 + c);
    bf16_t t4[4] = {(bf16_t)v.x, (bf16_t)v.y, (bf16_t)v.z, (bf16_t)v.w};
    int db = r * 512 + ((c << 1) ^ ((r & 7) << 4));
    *reinterpret_cast<uint2*>(reinterpret_cast<char*>(lds) + db) =
        *reinterpret_cast<const uint2*>(t4);
  }
}

// ---------------------------------------------------------------------------
// Weights f32 -> bf16 in ws. Offsets (elements): fc_gru_w 0, in_proj_w 65536,
// out_proj_w 262144, att_w 327680, gru_wih 458752, gru_whh 655360, fc2_w 851968.
// ---------------------------------------------------------------------------
__global__ __launch_bounds__(256) void cvt_weights(const float* __restrict__ w0,
                                                   const float* __restrict__ w1,
                                                   const float* __restrict__ w2,
                                                   const float* __restrict__ w3,
                                                   const float* __restrict__ w4,
                                                   const float* __restrict__ w5,
                                                   const float* __restrict__ w6,
                                                   bf16_t* __restrict__ dst) {
  long e = ((long)blockIdx.x * 256 + threadIdx.x) * 4;
  const float* src; long off;
  if (e < 65536)       { src = w0; off = 0; }
  else if (e < 262144) { src = w1; off = 65536; }
  else if (e < 327680) { src = w2; off = 262144; }
  else if (e < 458752) { src = w3; off = 327680; }
  else if (e < 655360) { src = w4; off = 458752; }
  else if (e < 851968) { src = w5; off = 655360; }
  else                 { src = w6; off = 851968; }
  float4 v = *reinterpret_cast<const float4*>(src + (e - off));
  bf16_t o[4] = {(bf16_t)v.x, (bf16_t)v.y, (bf16_t)v.z, (bf16_t)v.w};
  *reinterpret_cast<uint2*>(dst + e) = *reinterpret_cast<const uint2*>(o);
}

// ---------------------------------------------------------------------------
// x = relu(inputs @ fc_gru_w^T + b): f32 in (split), f32 out. Tile 64x256.
// ---------------------------------------------------------------------------
__global__ __launch_bounds__(256, 2) void gemm1(const float* __restrict__ X,
                                                const bf16_t* __restrict__ W,
                                                const float* __restrict__ Bi,
                                                float* __restrict__ C) {
  __shared__ bf16_t Ihi[64 * 256], Ilo[64 * 256];
  const int tid = threadIdx.x, lane = tid & 63, wv = tid >> 6;
  const int rl = lane & 15, kof = (lane >> 4) << 3, ro4 = (lane >> 4) << 2;
  const long m0 = (long)blockIdx.x * 64;
  stage_split(Ihi, Ilo, X, m0, 512, 0, tid, 256);
  __syncthreads();
  f32x4 acc[4][4] = {};
  for (int kk = 0; kk < 256; kk += 32) {
    bf16x8 ah[4], al[4], bb[4];
#pragma unroll
    for (int rt = 0; rt < 4; ++rt) {
      ah[rt] = lds_frag(Ihi, rt * 16 + rl, kk + kof, 512);
      al[rt] = lds_frag(Ilo, rt * 16 + rl, kk + kof, 512);
    }
#pragma unroll
    for (int ct = 0; ct < 4; ++ct)
      bb[ct] = *reinterpret_cast<const bf16x8*>(W + (long)(wv * 64 + ct * 16 + rl) * 256 + kk + kof);
#pragma unroll
    for (int rt = 0; rt < 4; ++rt)
#pragma unroll
      for (int ct = 0; ct < 4; ++ct) {
        acc[rt][ct] = mfma16(ah[rt], bb[ct], acc[rt][ct]);
        acc[rt][ct] = mfma16(al[rt], bb[ct], acc[rt][ct]);
      }
  }
#pragma unroll
  for (int ct = 0; ct < 4; ++ct) {
    int c = wv * 64 + ct * 16 + rl;
    float bv = Bi[c];
#pragma unroll
    for (int rt = 0; rt < 4; ++rt)
#pragma unroll
      for (int i = 0; i < 4; ++i)
        C[(m0 + rt * 16 + ro4 + i) * 256 + c] = fmaxf(acc[rt][ct][i] + bv, 0.f);
  }
}

// ---------------------------------------------------------------------------
// Fused per-sample attention, split-precision. Block = 1 sample, 512 thr/8 waves.
// Reads x (f32 [M,256]), writes x_att (f32 [M,256]). Mask is INT32 (bool->int).
// ---------------------------------------------------------------------------
__global__ __launch_bounds__(512, 2) void attn_kernel(const float* __restrict__ Xf,
                                                      float* __restrict__ Xatt,
                                                      const bf16_t* __restrict__ Wqkv,
                                                      const float* __restrict__ Bqkv,
                                                      const bf16_t* __restrict__ Wo,
                                                      const float* __restrict__ Bo,
                                                      const int* __restrict__ drop) {
  __shared__ __align__(16) char buf[147456];
  bf16_t* XHI = reinterpret_cast<bf16_t*>(buf);            // 32K, swz rowBytes 512
  bf16_t* XLO = reinterpret_cast<bf16_t*>(buf + 32768);    // 32K
  bf16_t* QS  = reinterpret_cast<bf16_t*>(buf + 65536);    // 32K, swz 512; later V^T swz 128
  bf16_t* KS  = reinterpret_cast<bf16_t*>(buf + 98304);    // 32K, swz 512; later PHI/PLO swz 128
  bf16_t* PHI = KS;                                        // 8K  [64][64]
  bf16_t* PLO = reinterpret_cast<bf16_t*>(buf + 98304 + 8192);
  float*  SS  = reinterpret_cast<float*>(buf + 131072);    // 16K [64][64]
  const int tid = threadIdx.x, lane = tid & 63, wv = tid >> 6;
  const int rl = lane & 15, kof = (lane >> 4) << 3, ro4 = (lane >> 4) << 2;
  const int b = blockIdx.x;
  const long R0 = (long)b * 64;
  stage_split(XHI, XLO, Xf, R0, 512, 0, tid, 512);
  __syncthreads();
  const int c0 = wv * 32;

  // q and k GEMMs (split x) -> bf16 swizzled LDS
  for (int which = 0; which < 2; ++which) {
    const bf16_t* Wp = Wqkv + (long)which * 65536;
    bf16_t* outp = which ? KS : QS;
    f32x4 acc[4][2] = {};
    for (int kk = 0; kk < 256; kk += 32) {
      bf16x8 ah[4], al[4], bb[2];
#pragma unroll
      for (int rt = 0; rt < 4; ++rt) {
        ah[rt] = lds_frag(XHI, rt * 16 + rl, kk + kof, 512);
        al[rt] = lds_frag(XLO, rt * 16 + rl, kk + kof, 512);
      }
#pragma unroll
      for (int ct = 0; ct < 2; ++ct)
        bb[ct] = *reinterpret_cast<const bf16x8*>(Wp + (long)(c0 + ct * 16 + rl) * 256 + kk + kof);
#pragma unroll
      for (int rt = 0; rt < 4; ++rt)
#pragma unroll
        for (int ct = 0; ct < 2; ++ct) {
          acc[rt][ct] = mfma16(ah[rt], bb[ct], acc[rt][ct]);
          acc[rt][ct] = mfma16(al[rt], bb[ct], acc[rt][ct]);
        }
    }
#pragma unroll
    for (int ct = 0; ct < 2; ++ct) {
      int c = c0 + ct * 16 + rl;
      float bv = Bqkv[which * 256 + c];
#pragma unroll
      for (int rt = 0; rt < 4; ++rt)
#pragma unroll
        for (int i = 0; i < 4; ++i) lds_put(outp, rt * 16 + ro4 + i, c, 512, acc[rt][ct][i] + bv);
    }
  }
  __syncthreads();

  // scores = q k^T * scale, masked (int32 mask) -> SS f32
  {
    const int rt0 = (wv & 3) * 16, sc0 = (wv >> 2) * 32;
    f32x4 acc[2] = {};
    for (int kk = 0; kk < 256; kk += 32) {
      bf16x8 a = lds_frag(QS, rt0 + rl, kk + kof, 512);
#pragma unroll
      for (int ct = 0; ct < 2; ++ct) {
        bf16x8 bb = lds_frag(KS, sc0 + ct * 16 + rl, kk + kof, 512);
        acc[ct] = mfma16(a, bb, acc[ct]);
      }
    }
#pragma unroll
    for (int ct = 0; ct < 2; ++ct)
#pragma unroll
      for (int i = 0; i < 4; ++i) {
        int rr = rt0 + ro4 + i, cc = sc0 + ct * 16 + rl;
        float s = acc[ct][i] * 0.0625f;
        if (drop[(long)b * 4096 + rr * 64 + cc]) s = -1e9f;
        SS[rr * 64 + cc] = s;
      }
  }
  __syncthreads();

  // v GEMM (split x) -> V^T [256][64] bf16 over Q region (q dead)
  {
    const bf16_t* Wp = Wqkv + (long)2 * 65536;
    f32x4 acc[4][2] = {};
    for (int kk = 0; kk < 256; kk += 32) {
      bf16x8 ah[4], al[4], bb[2];
#pragma unroll
      for (int rt = 0; rt < 4; ++rt) {
        ah[rt] = lds_frag(XHI, rt * 16 + rl, kk + kof, 512);
        al[rt] = lds_frag(XLO, rt * 16 + rl, kk + kof, 512);
      }
#pragma unroll
      for (int ct = 0; ct < 2; ++ct)
        bb[ct] = *reinterpret_cast<const bf16x8*>(Wp + (long)(c0 + ct * 16 + rl) * 256 + kk + kof);
#pragma unroll
      for (int rt = 0; rt < 4; ++rt)
#pragma unroll
        for (int ct = 0; ct < 2; ++ct) {
          acc[rt][ct] = mfma16(ah[rt], bb[ct], acc[rt][ct]);
          acc[rt][ct] = mfma16(al[rt], bb[ct], acc[rt][ct]);
        }
    }
#pragma unroll
    for (int ct = 0; ct < 2; ++ct) {
      int c = c0 + ct * 16 + rl;
      float bv = Bqkv[512 + c];
#pragma unroll
      for (int rt = 0; rt < 4; ++rt)
#pragma unroll
        for (int i = 0; i < 4; ++i) {
          int j = rt * 16 + ro4 + i;                    // agent (key) index
          lds_put(QS, c, j, 128, acc[rt][ct][i] + bv);  // V^T[c][j]
        }
    }
  }
  // wave-parallel softmax -> split P over K region (k dead)
  for (int j = 0; j < 8; ++j) {
    int rr = wv * 8 + j;
    float s = SS[rr * 64 + lane];
    float m = s;
#pragma unroll
    for (int off = 32; off >= 1; off >>= 1) m = fmaxf(m, __shfl_xor(m, off));
    float e = __expf(s - m);
    float sum = e;
#pragma unroll
    for (int off = 32; off >= 1; off >>= 1) sum += __shfl_xor(sum, off);
    lds_put2(PHI, PLO, rr, lane, 128, e / sum);
  }
  __syncthreads();

  // ctx = P @ V (split P) -> split ctx over X region (x dead)
  {
    f32x4 acc[4][2] = {};
    for (int kk = 0; kk < 64; kk += 32) {
      bf16x8 ah[4], al[4], bb[2];
#pragma unroll
      for (int rt = 0; rt < 4; ++rt) {
        ah[rt] = lds_frag(PHI, rt * 16 + rl, kk + kof, 128);
        al[rt] = lds_frag(PLO, rt * 16 + rl, kk + kof, 128);
      }
#pragma unroll
      for (int ct = 0; ct < 2; ++ct) bb[ct] = lds_frag(QS, c0 + ct * 16 + rl, kk + kof, 128);
#pragma unroll
      for (int rt = 0; rt < 4; ++rt)
#pragma unroll
        for (int ct = 0; ct < 2; ++ct) {
          acc[rt][ct] = mfma16(ah[rt], bb[ct], acc[rt][ct]);
          acc[rt][ct] = mfma16(al[rt], bb[ct], acc[rt][ct]);
        }
    }
    __syncthreads();
#pragma unroll
    for (int ct = 0; ct < 2; ++ct)
#pragma unroll
      for (int rt = 0; rt < 4; ++rt)
#pragma unroll
        for (int i = 0; i < 4; ++i)
          lds_put2(XHI, XLO, rt * 16 + ro4 + i, c0 + ct * 16 + rl, 512, acc[rt][ct][i]);
  }
  __syncthreads();

  // x_att = ctx @ Wo^T + Bo (split ctx) -> f32 global
  {
    f32x4 acc[4][2] = {};
    for (int kk = 0; kk < 256; kk += 32) {
      bf16x8 ah[4], al[4], bb[2];
#pragma unroll
      for (int rt = 0; rt < 4; ++rt) {
        ah[rt] = lds_frag(XHI, rt * 16 + rl, kk + kof, 512);
        al[rt] = lds_frag(XLO, rt * 16 + rl, kk + kof, 512);
      }
#pragma unroll
      for (int ct = 0; ct < 2; ++ct)
        bb[ct] = *reinterpret_cast<const bf16x8*>(Wo + (long)(c0 + ct * 16 + rl) * 256 + kk + kof);
#pragma unroll
      for (int rt = 0; rt < 4; ++rt)
#pragma unroll
        for (int ct = 0; ct < 2; ++ct) {
          acc[rt][ct] = mfma16(ah[rt], bb[ct], acc[rt][ct]);
          acc[rt][ct] = mfma16(al[rt], bb[ct], acc[rt][ct]);
        }
    }
#pragma unroll
    for (int ct = 0; ct < 2; ++ct) {
      int c = c0 + ct * 16 + rl;
      float bv = Bo[c];
#pragma unroll
      for (int rt = 0; rt < 4; ++rt)
#pragma unroll
        for (int i = 0; i < 4; ++i)
          Xatt[(R0 + rt * 16 + ro4 + i) * 256 + c] = acc[rt][ct][i] + bv;
    }
  }
}

// ---------------------------------------------------------------------------
// x_ = relu([x | x_att] @ att_w^T + b), split operands, f32 in/out.
// ---------------------------------------------------------------------------
__global__ __launch_bounds__(256, 2) void gemm_cat(float* __restrict__ Xa,
                                                   const float* __restrict__ Xb,
                                                   const bf16_t* __restrict__ W,
                                                   const float* __restrict__ Bi) {
  __shared__ bf16_t Chi[64 * 512], Clo[64 * 512];  // 64K + 64K
  const int tid = threadIdx.x, lane = tid & 63, wv = tid >> 6;
  const int rl = lane & 15, kof = (lane >> 4) << 3, ro4 = (lane >> 4) << 2;
  const long m0 = (long)blockIdx.x * 64;
  stage_split(Chi, Clo, Xa, m0, 1024, 0, tid, 256);
  stage_split(Chi, Clo, Xb, m0, 1024, 512, tid, 256);
  __syncthreads();
  f32x4 acc[4][4] = {};
  for (int kk = 0; kk < 512; kk += 32) {
    bf16x8 ah[4], al[4], bb[4];
#pragma unroll
    for (int rt = 0; rt < 4; ++rt) {
      ah[rt] = lds_frag(Chi, rt * 16 + rl, kk + kof, 1024);
      al[rt] = lds_frag(Clo, rt * 16 + rl, kk + kof, 1024);
    }
#pragma unroll
    for (int ct = 0; ct < 4; ++ct)
      bb[ct] = *reinterpret_cast<const bf16x8*>(W + (long)(wv * 64 + ct * 16 + rl) * 512 + kk + kof);
#pragma unroll
    for (int rt = 0; rt < 4; ++rt)
#pragma unroll
      for (int ct = 0; ct < 4; ++ct) {
        acc[rt][ct] = mfma16(ah[rt], bb[ct], acc[rt][ct]);
        acc[rt][ct] = mfma16(al[rt], bb[ct], acc[rt][ct]);
      }
  }
#pragma unroll
  for (int ct = 0; ct < 4; ++ct) {
    int c = wv * 64 + ct * 16 + rl;
    float bv = Bi[c];
#pragma unroll
    for (int rt = 0; rt < 4; ++rt)
#pragma unroll
      for (int i = 0; i < 4; ++i)
        Xa[(m0 + rt * 16 + ro4 + i) * 256 + c] = fmaxf(acc[rt][ct][i] + bv, 0.f);
  }
}

// ---------------------------------------------------------------------------
// Fused GRUCell v3: anti-spill layout.
//  - wave = 32 rows x 16 cols (waves: 2 row-halves x 4 col-strips); p = 4 passes
//    -> accumulators 32 VGPR (was 64)
//  - #pragma unroll 2 on kk loops bounds the compiler's global-load hoisting
//    (r8/r9 PMC: equal ~1.37GB FETCH/WRITE surplus = spill round-trips from
//    full-unroll hoist of weight frags over live accs)
//  - h_in from staged LDS; merged r/z gate accumulators; 4 M-tiles/block
// ---------------------------------------------------------------------------
__global__ __launch_bounds__(512) void gru_kernel(const float* __restrict__ Xf,
                                                  const float* __restrict__ Hin,
                                                  const bf16_t* __restrict__ Wih,
                                                  const bf16_t* __restrict__ Whh,
                                                  const float* __restrict__ bih,
                                                  const float* __restrict__ bhh,
                                                  float* __restrict__ Hout) {
  __shared__ bf16_t Xs[64 * 256], Hs[64 * 256];
  const int tid = threadIdx.x, lane = tid & 63, wv = tid >> 6;
  const int rl = lane & 15, kof = (lane >> 4) << 3, ro4 = (lane >> 4) << 2;
  const int r0w = (wv & 1) * 32;          // row half
  const int cw  = (wv >> 1) * 16;         // col strip within 64-col pass
  for (int t = 0; t < 4; ++t) {
    const long m0 = ((long)blockIdx.x * 4 + t) * 64;
    if (t) __syncthreads();  // all waves done with LDS before re-stage
    stage_f32(Xs, Xf, m0, tid, 512);
    stage_f32(Hs, Hin, m0, tid, 512);
    __syncthreads();
#pragma unroll 1
    for (int p = 0; p < 4; ++p) {
      const int c0 = p * 64 + cw;
      f32x4 aRZ[2][2] = {}, aIN[2] = {}, aHN[2] = {};
      // x-phase: x@Wih^T into r,z (merged) and i_n
#pragma unroll 2
      for (int kk = 0; kk < 256; kk += 32) {
        bf16x8 ax[2], bI[3];
#pragma unroll
        for (int rt = 0; rt < 2; ++rt) ax[rt] = lds_frag(Xs, r0w + rt * 16 + rl, kk + kof, 512);
#pragma unroll
        for (int g = 0; g < 3; ++g)
          bI[g] = *reinterpret_cast<const bf16x8*>(Wih + (long)(g * 256 + c0 + rl) * 256 + kk + kof);
#pragma unroll
        for (int rt = 0; rt < 2; ++rt) {
          aRZ[0][rt] = mfma16(ax[rt], bI[0], aRZ[0][rt]);
          aRZ[1][rt] = mfma16(ax[rt], bI[1], aRZ[1][rt]);
          aIN[rt]    = mfma16(ax[rt], bI[2], aIN[rt]);
        }
      }
      // h-phase: h@Whh^T into r,z (same accs) and h_n (separate)
#pragma unroll 2
      for (int kk = 0; kk < 256; kk += 32) {
        bf16x8 ah_[2], bH[3];
#pragma unroll
        for (int rt = 0; rt < 2; ++rt) ah_[rt] = lds_frag(Hs, r0w + rt * 16 + rl, kk + kof, 512);
#pragma unroll
        for (int g = 0; g < 3; ++g)
          bH[g] = *reinterpret_cast<const bf16x8*>(Whh + (long)(g * 256 + c0 + rl) * 256 + kk + kof);
#pragma unroll
        for (int rt = 0; rt < 2; ++rt) {
          aRZ[0][rt] = mfma16(ah_[rt], bH[0], aRZ[0][rt]);
          aRZ[1][rt] = mfma16(ah_[rt], bH[1], aRZ[1][rt]);
          aHN[rt]    = mfma16(ah_[rt], bH[2], aHN[rt]);
        }
      }
      const int c = c0 + rl;
      float br  = bih[c] + bhh[c];
      float bz  = bih[256 + c] + bhh[256 + c];
      float bin_ = bih[512 + c], bhn = bhh[512 + c];
#pragma unroll
      for (int rt = 0; rt < 2; ++rt)
#pragma unroll
        for (int i = 0; i < 4; ++i) {
          int rloc = r0w + rt * 16 + ro4 + i;
          float rg = 1.f / (1.f + __expf(-(aRZ[0][rt][i] + br)));
          float zg = 1.f / (1.f + __expf(-(aRZ[1][rt][i] + bz)));
          float nx = aIN[rt][i] + bin_ + rg * (aHN[rt][i] + bhn);
          float ng = 1.f - 2.f / (__expf(2.f * nx) + 1.f);  // tanh, saturation-safe
          float hv = lds_get1(Hs, rloc, c, 512);            // h_in from LDS (bf16)
          Hout[(m0 + rloc) * 256 + c] = (1.f - zg) * ng + zg * hv;
        }
    }
  }
}

// tactic_q = h @ fc2_w^T + b, split h. 256 thr / 4 waves, 16 rows per wave.
__global__ __launch_bounds__(256, 2) void fc2_kernel(const float* __restrict__ h,
                                                     const bf16_t* __restrict__ Wt,
                                                     const float* __restrict__ bt,
                                                     float* __restrict__ out) {
  __shared__ bf16_t Hhi[64 * 256], Hlo[64 * 256];
  const int tid = threadIdx.x, lane = tid & 63, wv = tid >> 6;
  const int rl = lane & 15, kof = (lane >> 4) << 3, ro4 = (lane >> 4) << 2;
  const long m0 = (long)blockIdx.x * 64;
  stage_split(Hhi, Hlo, h, m0, 512, 0, tid, 256);
  __syncthreads();
  f32x4 acc = {};
  for (int kk = 0; kk < 256; kk += 32) {
    bf16x8 ah = lds_frag(Hhi, wv * 16 + rl, kk + kof, 512);
    bf16x8 al = lds_frag(Hlo, wv * 16 + rl, kk + kof, 512);
    bf16x8 bb = *reinterpret_cast<const bf16x8*>(Wt + (long)rl * 256 + kk + kof);
    acc = mfma16(ah, bb, acc);
    acc = mfma16(al, bb, acc);
  }
  float bv = bt[rl];
#pragma unroll
  for (int i = 0; i < 4; ++i) out[(m0 + wv * 16 + ro4 + i) * 16 + rl] = acc[i] + bv;
}

// int32 bool -> f32 {0,1} copy, 4 elems/thread
__global__ __launch_bounds__(256) void drop_copy(const int* __restrict__ d,
                                                 float* __restrict__ o) {
  long i = (long)blockIdx.x * 256 + threadIdx.x;
  int4 v = reinterpret_cast<const int4*>(d)[i];
  float4 r;
  r.x = v.x ? 1.f : 0.f;
  r.y = v.y ? 1.f : 0.f;
  r.z = v.z ? 1.f : 0.f;
  r.w = v.w ? 1.f : 0.f;
  reinterpret_cast<float4*>(o)[i] = r;
}

extern "C" void kernel_launch(void* const* d_in, const int* in_sizes, int n_in,
                              void* d_out, int out_size, void* d_ws, size_t ws_size,
                              hipStream_t stream) {
  (void)in_sizes; (void)n_in; (void)out_size; (void)ws_size;
  const float* inputs      = (const float*)d_in[0];
  const float* hidden      = (const float*)d_in[1];
  const int*   drp         = (const int*)d_in[2];   // bool pushed as int32
  // d_in[3] = t (unused)
  const float* fc_gru_w    = (const float*)d_in[4];
  const float* fc_gru_b    = (const float*)d_in[5];
  const float* in_proj_w   = (const float*)d_in[6];
  const float* in_proj_b   = (const float*)d_in[7];
  const float* out_proj_w  = (const float*)d_in[8];
  const float* out_proj_b  = (const float*)d_in[9];
  const float* att_w       = (const float*)d_in[10];
  const float* att_b       = (const float*)d_in[11];
  const float* gru_wih     = (const float*)d_in[12];
  const float* gru_whh     = (const float*)d_in[13];
  const float* gru_bih     = (const float*)d_in[14];
  const float* gru_bhh     = (const float*)d_in[15];
  const float* fc2_w       = (const float*)d_in[16];
  const float* fc2_b       = (const float*)d_in[17];

  float* out_t = (float*)d_out;          // [M,16]
  float* out_h = out_t + MTOT * 16;      // [M,256] f32: x_att, then h
  float* out_d = out_h + MTOT * 256;     // [B*64*64] f32

  float*  A  = (float*)d_ws;             // [M,256] f32: x, then x_   (128 MB)
  bf16_t* Wb = (bf16_t*)(A + MTOT * 256);  // bf16 weights (1.7 MB)

  // 0) weights f32 -> bf16
  cvt_weights<<<836, 256, 0, stream>>>(fc_gru_w, in_proj_w, out_proj_w, att_w,
                                       gru_wih, gru_whh, fc2_w, Wb);
  // 1) x = relu(inputs @ fc_gru_w^T + b) -> A (f32)
  gemm1<<<2048, 256, 0, stream>>>(inputs, Wb, fc_gru_b, A);
  // 2) fused attention: x -> x_att (f32, parked in out_h)
  attn_kernel<<<2048, 512, 0, stream>>>(A, out_h, Wb + 65536, in_proj_b,
                                        Wb + 262144, out_proj_b, drp);
  // 3) x_ = relu([x | x_att] @ att_w^T + b) -> A (f32, in-place)
  gemm_cat<<<2048, 256, 0, stream>>>(A, out_h, Wb + 327680, att_b);
  // 4) GRU: x_ (A) + hidden -> h -> out_h (f32, overwrites x_att); 4 tiles/block
  gru_kernel<<<512, 512, 0, stream>>>(A, hidden, Wb + 458752, Wb + 655360,
                                      gru_bih, gru_bhh, out_h);
  // 5) tactic_q = h @ fc2_w^T + b -> out_t
  fc2_kernel<<<2048, 256, 0, stream>>>(out_h, Wb + 851968, fc2_b, out_t);
  // 6) drop mask echo as f32 (8388608 elems / 4 per thread / 256 = 8192 blocks)
  drop_copy<<<8192, 256, 0, stream>>>(drp, out_d);
}

// Round 12
// 833.400 us; speedup vs baseline: 2.2175x; 1.2467x over previous
//
#include <hip/hip_runtime.h>

typedef __bf16 bf16_t;
using bf16x8 = __bf16 __attribute__((ext_vector_type(8)));
using f32x4  = float __attribute__((ext_vector_type(4)));

// B=2048, N=64, D=256, H=256, T=16
static constexpr long MTOT = 131072;   // B*N

__device__ __forceinline__ f32x4 mfma16(bf16x8 a, bf16x8 b, f32x4 c) {
  return __builtin_amdgcn_mfma_f32_16x16x32_bf16(a, b, c, 0, 0, 0);
}

// Swizzled LDS tiles: element (row,k) at byte row*rowBytes + ((k*2 + colOff) ^ ((row&7)<<4)).
__device__ __forceinline__ bf16x8 lds_frag(const bf16_t* base, int row, int k, int rowBytes) {
  int byte = row * rowBytes + ((k << 1) ^ ((row & 7) << 4));
  return *reinterpret_cast<const bf16x8*>(reinterpret_cast<const char*>(base) + byte);
}
__device__ __forceinline__ float lds_get1(const bf16_t* base, int row, int col, int rowBytes) {
  int byte = row * rowBytes + ((col << 1) ^ ((row & 7) << 4));
  return (float)*reinterpret_cast<const bf16_t*>(reinterpret_cast<const char*>(base) + byte);
}
__device__ __forceinline__ void lds_put(bf16_t* base, int row, int col, int rowBytes, float v) {
  int byte = row * rowBytes + ((col << 1) ^ ((row & 7) << 4));
  *reinterpret_cast<bf16_t*>(reinterpret_cast<char*>(base) + byte) = (bf16_t)v;
}
__device__ __forceinline__ void lds_put2(bf16_t* hi, bf16_t* lo, int row, int col,
                                         int rowBytes, float v) {
  int byte = row * rowBytes + ((col << 1) ^ ((row & 7) << 4));
  bf16_t h = (bf16_t)v;
  bf16_t l = (bf16_t)(v - (float)h);
  *reinterpret_cast<bf16_t*>(reinterpret_cast<char*>(hi) + byte) = h;
  *reinterpret_cast<bf16_t*>(reinterpret_cast<char*>(lo) + byte) = l;
}

// Stage a [64 x 256] f32 tile (lda=256) -> split hi/lo bf16 swizzled LDS tiles.
__device__ __forceinline__ void stage_split(bf16_t* hi, bf16_t* lo, const float* src,
                                            long row0, int rowBytesLds, int colOffBytes,
                                            int tid, int nthr) {
  for (int e = tid * 4; e < 64 * 256; e += nthr * 4) {
    int r = e >> 8, c = e & 255;
    float4 v = *reinterpret_cast<const float4*>(src + (row0 + r) * 256 + c);
    bf16_t h4[4], l4[4];
    h4[0] = (bf16_t)v.x; l4[0] = (bf16_t)(v.x - (float)h4[0]);
    h4[1] = (bf16_t)v.y; l4[1] = (bf16_t)(v.y - (float)h4[1]);
    h4[2] = (bf16_t)v.z; l4[2] = (bf16_t)(v.z - (float)h4[2]);
    h4[3] = (bf16_t)v.w; l4[3] = (bf16_t)(v.w - (float)h4[3]);
    int db = r * rowBytesLds + (((c << 1) + colOffBytes) ^ ((r & 7) << 4));
    *reinterpret_cast<uint2*>(reinterpret_cast<char*>(hi) + db) = *reinterpret_cast<const uint2*>(h4);
    *reinterpret_cast<uint2*>(reinterpret_cast<char*>(lo) + db) = *reinterpret_cast<const uint2*>(l4);
  }
}

// Stage a [64 x 256] f32 tile -> single bf16 swizzled LDS (rowBytes/colOff params).
__device__ __forceinline__ void stage_f32c(bf16_t* lds, const float* src, long row0,
                                           int rowBytesLds, int colOffBytes,
                                           int tid, int nthr) {
  for (int e = tid * 4; e < 64 * 256; e += nthr * 4) {
    int r = e >> 8, c = e & 255;
    float4 v = *reinterpret_cast<const float4*>(src + (row0 + r) * 256 + c);
    bf16_t t4[4] = {(bf16_t)v.x, (bf16_t)v.y, (bf16_t)v.z, (bf16_t)v.w};
    int db = r * rowBytesLds + (((c << 1) + colOffBytes) ^ ((r & 7) << 4));
    *reinterpret_cast<uint2*>(reinterpret_cast<char*>(lds) + db) =
        *reinterpret_cast<const uint2*>(t4);
  }
}

// ---------------------------------------------------------------------------
// Weights f32 -> bf16 in ws. Offsets (elements): fc_gru_w 0, in_proj_w 65536,
// out_proj_w 262144, att_w 327680, gru_wih 458752, gru_whh 655360, fc2_w 851968.
// ---------------------------------------------------------------------------
__global__ __launch_bounds__(256) void cvt_weights(const float* __restrict__ w0,
                                                   const float* __restrict__ w1,
                                                   const float* __restrict__ w2,
                                                   const float* __restrict__ w3,
                                                   const float* __restrict__ w4,
                                                   const float* __restrict__ w5,
                                                   const float* __restrict__ w6,
                                                   bf16_t* __restrict__ dst) {
  long e = ((long)blockIdx.x * 256 + threadIdx.x) * 4;
  const float* src; long off;
  if (e < 65536)       { src = w0; off = 0; }
  else if (e < 262144) { src = w1; off = 65536; }
  else if (e < 327680) { src = w2; off = 262144; }
  else if (e < 458752) { src = w3; off = 327680; }
  else if (e < 655360) { src = w4; off = 458752; }
  else if (e < 851968) { src = w5; off = 655360; }
  else                 { src = w6; off = 851968; }
  float4 v = *reinterpret_cast<const float4*>(src + (e - off));
  bf16_t o[4] = {(bf16_t)v.x, (bf16_t)v.y, (bf16_t)v.z, (bf16_t)v.w};
  *reinterpret_cast<uint2*>(dst + e) = *reinterpret_cast<const uint2*>(o);
}

// ---------------------------------------------------------------------------
// x = relu(inputs @ fc_gru_w^T + b): f32 in (split), f32 out. Tile 64x256.
// ---------------------------------------------------------------------------
__global__ __launch_bounds__(256, 2) void gemm1(const float* __restrict__ X,
                                                const bf16_t* __restrict__ W,
                                                const float* __restrict__ Bi,
                                                float* __restrict__ C) {
  __shared__ bf16_t Ihi[64 * 256], Ilo[64 * 256];
  const int tid = threadIdx.x, lane = tid & 63, wv = tid >> 6;
  const int rl = lane & 15, kof = (lane >> 4) << 3, ro4 = (lane >> 4) << 2;
  const long m0 = (long)blockIdx.x * 64;
  stage_split(Ihi, Ilo, X, m0, 512, 0, tid, 256);
  __syncthreads();
  f32x4 acc[4][4] = {};
  for (int kk = 0; kk < 256; kk += 32) {
    bf16x8 ah[4], al[4], bb[4];
#pragma unroll
    for (int rt = 0; rt < 4; ++rt) {
      ah[rt] = lds_frag(Ihi, rt * 16 + rl, kk + kof, 512);
      al[rt] = lds_frag(Ilo, rt * 16 + rl, kk + kof, 512);
    }
#pragma unroll
    for (int ct = 0; ct < 4; ++ct)
      bb[ct] = *reinterpret_cast<const bf16x8*>(W + (long)(wv * 64 + ct * 16 + rl) * 256 + kk + kof);
#pragma unroll
    for (int rt = 0; rt < 4; ++rt)
#pragma unroll
      for (int ct = 0; ct < 4; ++ct) {
        acc[rt][ct] = mfma16(ah[rt], bb[ct], acc[rt][ct]);
        acc[rt][ct] = mfma16(al[rt], bb[ct], acc[rt][ct]);
      }
  }
#pragma unroll
  for (int ct = 0; ct < 4; ++ct) {
    int c = wv * 64 + ct * 16 + rl;
    float bv = Bi[c];
#pragma unroll
    for (int rt = 0; rt < 4; ++rt)
#pragma unroll
      for (int i = 0; i < 4; ++i)
        C[(m0 + rt * 16 + ro4 + i) * 256 + c] = fmaxf(acc[rt][ct][i] + bv, 0.f);
  }
}

// ---------------------------------------------------------------------------
// Fused per-sample attention, split-precision. Block = 1 sample, 512 thr/8 waves.
// Reads x (f32 [M,256]), writes x_att (f32 [M,256]). Mask is INT32 (bool->int).
// ---------------------------------------------------------------------------
__global__ __launch_bounds__(512, 2) void attn_kernel(const float* __restrict__ Xf,
                                                      float* __restrict__ Xatt,
                                                      const bf16_t* __restrict__ Wqkv,
                                                      const float* __restrict__ Bqkv,
                                                      const bf16_t* __restrict__ Wo,
                                                      const float* __restrict__ Bo,
                                                      const int* __restrict__ drop) {
  __shared__ __align__(16) char buf[147456];
  bf16_t* XHI = reinterpret_cast<bf16_t*>(buf);            // 32K, swz rowBytes 512
  bf16_t* XLO = reinterpret_cast<bf16_t*>(buf + 32768);    // 32K
  bf16_t* QS  = reinterpret_cast<bf16_t*>(buf + 65536);    // 32K, swz 512; later V^T swz 128
  bf16_t* KS  = reinterpret_cast<bf16_t*>(buf + 98304);    // 32K, swz 512; later PHI/PLO swz 128
  bf16_t* PHI = KS;                                        // 8K  [64][64]
  bf16_t* PLO = reinterpret_cast<bf16_t*>(buf + 98304 + 8192);
  float*  SS  = reinterpret_cast<float*>(buf + 131072);    // 16K [64][64]
  const int tid = threadIdx.x, lane = tid & 63, wv = tid >> 6;
  const int rl = lane & 15, kof = (lane >> 4) << 3, ro4 = (lane >> 4) << 2;
  const int b = blockIdx.x;
  const long R0 = (long)b * 64;
  stage_split(XHI, XLO, Xf, R0, 512, 0, tid, 512);
  __syncthreads();
  const int c0 = wv * 32;

  // q and k GEMMs (split x) -> bf16 swizzled LDS
  for (int which = 0; which < 2; ++which) {
    const bf16_t* Wp = Wqkv + (long)which * 65536;
    bf16_t* outp = which ? KS : QS;
    f32x4 acc[4][2] = {};
    for (int kk = 0; kk < 256; kk += 32) {
      bf16x8 ah[4], al[4], bb[2];
#pragma unroll
      for (int rt = 0; rt < 4; ++rt) {
        ah[rt] = lds_frag(XHI, rt * 16 + rl, kk + kof, 512);
        al[rt] = lds_frag(XLO, rt * 16 + rl, kk + kof, 512);
      }
#pragma unroll
      for (int ct = 0; ct < 2; ++ct)
        bb[ct] = *reinterpret_cast<const bf16x8*>(Wp + (long)(c0 + ct * 16 + rl) * 256 + kk + kof);
#pragma unroll
      for (int rt = 0; rt < 4; ++rt)
#pragma unroll
        for (int ct = 0; ct < 2; ++ct) {
          acc[rt][ct] = mfma16(ah[rt], bb[ct], acc[rt][ct]);
          acc[rt][ct] = mfma16(al[rt], bb[ct], acc[rt][ct]);
        }
    }
#pragma unroll
    for (int ct = 0; ct < 2; ++ct) {
      int c = c0 + ct * 16 + rl;
      float bv = Bqkv[which * 256 + c];
#pragma unroll
      for (int rt = 0; rt < 4; ++rt)
#pragma unroll
        for (int i = 0; i < 4; ++i) lds_put(outp, rt * 16 + ro4 + i, c, 512, acc[rt][ct][i] + bv);
    }
  }
  __syncthreads();

  // scores = q k^T * scale, masked (int32 mask) -> SS f32
  {
    const int rt0 = (wv & 3) * 16, sc0 = (wv >> 2) * 32;
    f32x4 acc[2] = {};
    for (int kk = 0; kk < 256; kk += 32) {
      bf16x8 a = lds_frag(QS, rt0 + rl, kk + kof, 512);
#pragma unroll
      for (int ct = 0; ct < 2; ++ct) {
        bf16x8 bb = lds_frag(KS, sc0 + ct * 16 + rl, kk + kof, 512);
        acc[ct] = mfma16(a, bb, acc[ct]);
      }
    }
#pragma unroll
    for (int ct = 0; ct < 2; ++ct)
#pragma unroll
      for (int i = 0; i < 4; ++i) {
        int rr = rt0 + ro4 + i, cc = sc0 + ct * 16 + rl;
        float s = acc[ct][i] * 0.0625f;
        if (drop[(long)b * 4096 + rr * 64 + cc]) s = -1e9f;
        SS[rr * 64 + cc] = s;
      }
  }
  __syncthreads();

  // v GEMM (split x) -> V^T [256][64] bf16 over Q region (q dead)
  {
    const bf16_t* Wp = Wqkv + (long)2 * 65536;
    f32x4 acc[4][2] = {};
    for (int kk = 0; kk < 256; kk += 32) {
      bf16x8 ah[4], al[4], bb[2];
#pragma unroll
      for (int rt = 0; rt < 4; ++rt) {
        ah[rt] = lds_frag(XHI, rt * 16 + rl, kk + kof, 512);
        al[rt] = lds_frag(XLO, rt * 16 + rl, kk + kof, 512);
      }
#pragma unroll
      for (int ct = 0; ct < 2; ++ct)
        bb[ct] = *reinterpret_cast<const bf16x8*>(Wp + (long)(c0 + ct * 16 + rl) * 256 + kk + kof);
#pragma unroll
      for (int rt = 0; rt < 4; ++rt)
#pragma unroll
        for (int ct = 0; ct < 2; ++ct) {
          acc[rt][ct] = mfma16(ah[rt], bb[ct], acc[rt][ct]);
          acc[rt][ct] = mfma16(al[rt], bb[ct], acc[rt][ct]);
        }
    }
#pragma unroll
    for (int ct = 0; ct < 2; ++ct) {
      int c = c0 + ct * 16 + rl;
      float bv = Bqkv[512 + c];
#pragma unroll
      for (int rt = 0; rt < 4; ++rt)
#pragma unroll
        for (int i = 0; i < 4; ++i) {
          int j = rt * 16 + ro4 + i;                    // agent (key) index
          lds_put(QS, c, j, 128, acc[rt][ct][i] + bv);  // V^T[c][j]
        }
    }
  }
  // wave-parallel softmax -> split P over K region (k dead)
  for (int j = 0; j < 8; ++j) {
    int rr = wv * 8 + j;
    float s = SS[rr * 64 + lane];
    float m = s;
#pragma unroll
    for (int off = 32; off >= 1; off >>= 1) m = fmaxf(m, __shfl_xor(m, off));
    float e = __expf(s - m);
    float sum = e;
#pragma unroll
    for (int off = 32; off >= 1; off >>= 1) sum += __shfl_xor(sum, off);
    lds_put2(PHI, PLO, rr, lane, 128, e / sum);
  }
  __syncthreads();

  // ctx = P @ V (split P) -> split ctx over X region (x dead)
  {
    f32x4 acc[4][2] = {};
    for (int kk = 0; kk < 64; kk += 32) {
      bf16x8 ah[4], al[4], bb[2];
#pragma unroll
      for (int rt = 0; rt < 4; ++rt) {
        ah[rt] = lds_frag(PHI, rt * 16 + rl, kk + kof, 128);
        al[rt] = lds_frag(PLO, rt * 16 + rl, kk + kof, 128);
      }
#pragma unroll
      for (int ct = 0; ct < 2; ++ct) bb[ct] = lds_frag(QS, c0 + ct * 16 + rl, kk + kof, 128);
#pragma unroll
      for (int rt = 0; rt < 4; ++rt)
#pragma unroll
        for (int ct = 0; ct < 2; ++ct) {
          acc[rt][ct] = mfma16(ah[rt], bb[ct], acc[rt][ct]);
          acc[rt][ct] = mfma16(al[rt], bb[ct], acc[rt][ct]);
        }
    }
    __syncthreads();
#pragma unroll
    for (int ct = 0; ct < 2; ++ct)
#pragma unroll
      for (int rt = 0; rt < 4; ++rt)
#pragma unroll
        for (int i = 0; i < 4; ++i)
          lds_put2(XHI, XLO, rt * 16 + ro4 + i, c0 + ct * 16 + rl, 512, acc[rt][ct][i]);
  }
  __syncthreads();

  // x_att = ctx @ Wo^T + Bo (split ctx) -> f32 global
  {
    f32x4 acc[4][2] = {};
    for (int kk = 0; kk < 256; kk += 32) {
      bf16x8 ah[4], al[4], bb[2];
#pragma unroll
      for (int rt = 0; rt < 4; ++rt) {
        ah[rt] = lds_frag(XHI, rt * 16 + rl, kk + kof, 512);
        al[rt] = lds_frag(XLO, rt * 16 + rl, kk + kof, 512);
      }
#pragma unroll
      for (int ct = 0; ct < 2; ++ct)
        bb[ct] = *reinterpret_cast<const bf16x8*>(Wo + (long)(c0 + ct * 16 + rl) * 256 + kk + kof);
#pragma unroll
      for (int rt = 0; rt < 4; ++rt)
#pragma unroll
        for (int ct = 0; ct < 2; ++ct) {
          acc[rt][ct] = mfma16(ah[rt], bb[ct], acc[rt][ct]);
          acc[rt][ct] = mfma16(al[rt], bb[ct], acc[rt][ct]);
        }
    }
#pragma unroll
    for (int ct = 0; ct < 2; ++ct) {
      int c = c0 + ct * 16 + rl;
      float bv = Bo[c];
#pragma unroll
      for (int rt = 0; rt < 4; ++rt)
#pragma unroll
        for (int i = 0; i < 4; ++i)
          Xatt[(R0 + rt * 16 + ro4 + i) * 256 + c] = acc[rt][ct][i] + bv;
    }
  }
}

// ---------------------------------------------------------------------------
// x_ = relu([x | x_att] @ att_w^T + b), single-bf16 operands (de-split: error
// ~2e-3 on pre-acts << comparator half-ulp), f32 in/out. LDS 64KB -> 2 blk/CU.
// ---------------------------------------------------------------------------
__global__ __launch_bounds__(256, 2) void gemm_cat(float* __restrict__ Xa,
                                                   const float* __restrict__ Xb,
                                                   const bf16_t* __restrict__ W,
                                                   const float* __restrict__ Bi) {
  __shared__ bf16_t Cs[64 * 512];  // 64K
  const int tid = threadIdx.x, lane = tid & 63, wv = tid >> 6;
  const int rl = lane & 15, kof = (lane >> 4) << 3, ro4 = (lane >> 4) << 2;
  const long m0 = (long)blockIdx.x * 64;
  stage_f32c(Cs, Xa, m0, 1024, 0, tid, 256);
  stage_f32c(Cs, Xb, m0, 1024, 512, tid, 256);
  __syncthreads();
  f32x4 acc[4][4] = {};
#pragma unroll 1
  for (int kk = 0; kk < 512; kk += 32) {
    bf16x8 a[4], bb[4];
#pragma unroll
    for (int rt = 0; rt < 4; ++rt) a[rt] = lds_frag(Cs, rt * 16 + rl, kk + kof, 1024);
#pragma unroll
    for (int ct = 0; ct < 4; ++ct)
      bb[ct] = *reinterpret_cast<const bf16x8*>(W + (long)(wv * 64 + ct * 16 + rl) * 512 + kk + kof);
#pragma unroll
    for (int rt = 0; rt < 4; ++rt)
#pragma unroll
      for (int ct = 0; ct < 4; ++ct) acc[rt][ct] = mfma16(a[rt], bb[ct], acc[rt][ct]);
  }
#pragma unroll
  for (int ct = 0; ct < 4; ++ct) {
    int c = wv * 64 + ct * 16 + rl;
    float bv = Bi[c];
#pragma unroll
    for (int rt = 0; rt < 4; ++rt)
#pragma unroll
      for (int i = 0; i < 4; ++i)
        Xa[(m0 + rt * 16 + ro4 + i) * 256 + c] = fmaxf(acc[rt][ct][i] + bv, 0.f);
  }
}

// ---------------------------------------------------------------------------
// Fused GRUCell v4: wave = 64 rows x 16 cols (8 waves = 8 distinct col strips,
// no weight-read redundancy; 2 passes of 128 cols). kk loops unroll 1 (bounded
// hoist; r10 proved this kills spill). Accs 64 VGPR: aRZ[2][4]+aIN[4]+aHN[4].
// h_in from staged LDS; 4 M-tiles/block; 64 KB LDS -> 2 blocks/CU.
// ---------------------------------------------------------------------------
__global__ __launch_bounds__(512) void gru_kernel(const float* __restrict__ Xf,
                                                  const float* __restrict__ Hin,
                                                  const bf16_t* __restrict__ Wih,
                                                  const bf16_t* __restrict__ Whh,
                                                  const float* __restrict__ bih,
                                                  const float* __restrict__ bhh,
                                                  float* __restrict__ Hout) {
  __shared__ bf16_t Xs[64 * 256], Hs[64 * 256];
  const int tid = threadIdx.x, lane = tid & 63, wv = tid >> 6;
  const int rl = lane & 15, kof = (lane >> 4) << 3, ro4 = (lane >> 4) << 2;
  for (int t = 0; t < 4; ++t) {
    const long m0 = ((long)blockIdx.x * 4 + t) * 64;
    if (t) __syncthreads();  // all waves done with LDS before re-stage
    stage_f32c(Xs, Xf, m0, 512, 0, tid, 512);
    stage_f32c(Hs, Hin, m0, 512, 0, tid, 512);
    __syncthreads();
#pragma unroll 1
    for (int p = 0; p < 2; ++p) {
      const int c0 = p * 128 + wv * 16;
      f32x4 aRZ[2][4] = {}, aIN[4] = {}, aHN[4] = {};
      // x-phase: x@Wih^T into r,z (merged) and i_n
#pragma unroll 1
      for (int kk = 0; kk < 256; kk += 32) {
        bf16x8 ax[4], bI[3];
#pragma unroll
        for (int rt = 0; rt < 4; ++rt) ax[rt] = lds_frag(Xs, rt * 16 + rl, kk + kof, 512);
#pragma unroll
        for (int g = 0; g < 3; ++g)
          bI[g] = *reinterpret_cast<const bf16x8*>(Wih + (long)(g * 256 + c0 + rl) * 256 + kk + kof);
#pragma unroll
        for (int rt = 0; rt < 4; ++rt) {
          aRZ[0][rt] = mfma16(ax[rt], bI[0], aRZ[0][rt]);
          aRZ[1][rt] = mfma16(ax[rt], bI[1], aRZ[1][rt]);
          aIN[rt]    = mfma16(ax[rt], bI[2], aIN[rt]);
        }
      }
      // h-phase: h@Whh^T into r,z (same accs) and h_n (separate)
#pragma unroll 1
      for (int kk = 0; kk < 256; kk += 32) {
        bf16x8 ah_[4], bH[3];
#pragma unroll
        for (int rt = 0; rt < 4; ++rt) ah_[rt] = lds_frag(Hs, rt * 16 + rl, kk + kof, 512);
#pragma unroll
        for (int g = 0; g < 3; ++g)
          bH[g] = *reinterpret_cast<const bf16x8*>(Whh + (long)(g * 256 + c0 + rl) * 256 + kk + kof);
#pragma unroll
        for (int rt = 0; rt < 4; ++rt) {
          aRZ[0][rt] = mfma16(ah_[rt], bH[0], aRZ[0][rt]);
          aRZ[1][rt] = mfma16(ah_[rt], bH[1], aRZ[1][rt]);
          aHN[rt]    = mfma16(ah_[rt], bH[2], aHN[rt]);
        }
      }
      const int c = c0 + rl;
      float br  = bih[c] + bhh[c];
      float bz  = bih[256 + c] + bhh[256 + c];
      float bin_ = bih[512 + c], bhn = bhh[512 + c];
#pragma unroll
      for (int rt = 0; rt < 4; ++rt)
#pragma unroll
        for (int i = 0; i < 4; ++i) {
          int rloc = rt * 16 + ro4 + i;
          float rg = 1.f / (1.f + __expf(-(aRZ[0][rt][i] + br)));
          float zg = 1.f / (1.f + __expf(-(aRZ[1][rt][i] + bz)));
          float nx = aIN[rt][i] + bin_ + rg * (aHN[rt][i] + bhn);
          float ng = 1.f - 2.f / (__expf(2.f * nx) + 1.f);  // tanh, saturation-safe
          float hv = lds_get1(Hs, rloc, c, 512);            // h_in from LDS (bf16)
          Hout[(m0 + rloc) * 256 + c] = (1.f - zg) * ng + zg * hv;
        }
    }
  }
}

// tactic_q = h @ fc2_w^T + b, split h. 256 thr / 4 waves, 16 rows per wave.
__global__ __launch_bounds__(256, 2) void fc2_kernel(const float* __restrict__ h,
                                                     const bf16_t* __restrict__ Wt,
                                                     const float* __restrict__ bt,
                                                     float* __restrict__ out) {
  __shared__ bf16_t Hhi[64 * 256], Hlo[64 * 256];
  const int tid = threadIdx.x, lane = tid & 63, wv = tid >> 6;
  const int rl = lane & 15, kof = (lane >> 4) << 3, ro4 = (lane >> 4) << 2;
  const long m0 = (long)blockIdx.x * 64;
  stage_split(Hhi, Hlo, h, m0, 512, 0, tid, 256);
  __syncthreads();
  f32x4 acc = {};
  for (int kk = 0; kk < 256; kk += 32) {
    bf16x8 ah = lds_frag(Hhi, wv * 16 + rl, kk + kof, 512);
    bf16x8 al = lds_frag(Hlo, wv * 16 + rl, kk + kof, 512);
    bf16x8 bb = *reinterpret_cast<const bf16x8*>(Wt + (long)rl * 256 + kk + kof);
    acc = mfma16(ah, bb, acc);
    acc = mfma16(al, bb, acc);
  }
  float bv = bt[rl];
#pragma unroll
  for (int i = 0; i < 4; ++i) out[(m0 + wv * 16 + ro4 + i) * 16 + rl] = acc[i] + bv;
}

// int32 bool -> f32 {0,1} copy, 4 elems/thread
__global__ __launch_bounds__(256) void drop_copy(const int* __restrict__ d,
                                                 float* __restrict__ o) {
  long i = (long)blockIdx.x * 256 + threadIdx.x;
  int4 v = reinterpret_cast<const int4*>(d)[i];
  float4 r;
  r.x = v.x ? 1.f : 0.f;
  r.y = v.y ? 1.f : 0.f;
  r.z = v.z ? 1.f : 0.f;
  r.w = v.w ? 1.f : 0.f;
  reinterpret_cast<float4*>(o)[i] = r;
}

extern "C" void kernel_launch(void* const* d_in, const int* in_sizes, int n_in,
                              void* d_out, int out_size, void* d_ws, size_t ws_size,
                              hipStream_t stream) {
  (void)in_sizes; (void)n_in; (void)out_size; (void)ws_size;
  const float* inputs      = (const float*)d_in[0];
  const float* hidden      = (const float*)d_in[1];
  const int*   drp         = (const int*)d_in[2];   // bool pushed as int32
  // d_in[3] = t (unused)
  const float* fc_gru_w    = (const float*)d_in[4];
  const float* fc_gru_b    = (const float*)d_in[5];
  const float* in_proj_w   = (const float*)d_in[6];
  const float* in_proj_b   = (const float*)d_in[7];
  const float* out_proj_w  = (const float*)d_in[8];
  const float* out_proj_b  = (const float*)d_in[9];
  const float* att_w       = (const float*)d_in[10];
  const float* att_b       = (const float*)d_in[11];
  const float* gru_wih     = (const float*)d_in[12];
  const float* gru_whh     = (const float*)d_in[13];
  const float* gru_bih     = (const float*)d_in[14];
  const float* gru_bhh     = (const float*)d_in[15];
  const float* fc2_w       = (const float*)d_in[16];
  const float* fc2_b       = (const float*)d_in[17];

  float* out_t = (float*)d_out;          // [M,16]
  float* out_h = out_t + MTOT * 16;      // [M,256] f32: x_att, then h
  float* out_d = out_h + MTOT * 256;     // [B*64*64] f32

  float*  A  = (float*)d_ws;             // [M,256] f32: x, then x_   (128 MB)
  bf16_t* Wb = (bf16_t*)(A + MTOT * 256);  // bf16 weights (1.7 MB)

  // 0) weights f32 -> bf16
  cvt_weights<<<836, 256, 0, stream>>>(fc_gru_w, in_proj_w, out_proj_w, att_w,
                                       gru_wih, gru_whh, fc2_w, Wb);
  // 1) x = relu(inputs @ fc_gru_w^T + b) -> A (f32)
  gemm1<<<2048, 256, 0, stream>>>(inputs, Wb, fc_gru_b, A);
  // 2) fused attention: x -> x_att (f32, parked in out_h)
  attn_kernel<<<2048, 512, 0, stream>>>(A, out_h, Wb + 65536, in_proj_b,
                                        Wb + 262144, out_proj_b, drp);
  // 3) x_ = relu([x | x_att] @ att_w^T + b) -> A (f32, in-place)
  gemm_cat<<<2048, 256, 0, stream>>>(A, out_h, Wb + 327680, att_b);
  // 4) GRU: x_ (A) + hidden -> h -> out_h (f32, overwrites x_att); 4 tiles/block
  gru_kernel<<<512, 512, 0, stream>>>(A, hidden, Wb + 458752, Wb + 655360,
                                      gru_bih, gru_bhh, out_h);
  // 5) tactic_q = h @ fc2_w^T + b -> out_t
  fc2_kernel<<<2048, 256, 0, stream>>>(out_h, Wb + 851968, fc2_b, out_t);
  // 6) drop mask echo as f32 (8388608 elems / 4 per thread / 256 = 8192 blocks)
  drop_copy<<<8192, 256, 0, stream>>>(drp, out_d);
}

// Round 13
// 832.320 us; speedup vs baseline: 2.2203x; 1.0013x over previous
//
#include <hip/hip_runtime.h>

typedef __bf16 bf16_t;
using bf16x8 = __bf16 __attribute__((ext_vector_type(8)));
using f32x4  = float __attribute__((ext_vector_type(4)));

// B=2048, N=64, D=256, H=256, T=16
static constexpr long MTOT = 131072;   // B*N

__device__ __forceinline__ f32x4 mfma16(bf16x8 a, bf16x8 b, f32x4 c) {
  return __builtin_amdgcn_mfma_f32_16x16x32_bf16(a, b, c, 0, 0, 0);
}

// Swizzled LDS tiles: element (row,k) at byte row*rowBytes + ((k*2 + colOff) ^ ((row&7)<<4)).
__device__ __forceinline__ bf16x8 lds_frag(const bf16_t* base, int row, int k, int rowBytes) {
  int byte = row * rowBytes + ((k << 1) ^ ((row & 7) << 4));
  return *reinterpret_cast<const bf16x8*>(reinterpret_cast<const char*>(base) + byte);
}
__device__ __forceinline__ float lds_get1(const bf16_t* base, int row, int col, int rowBytes) {
  int byte = row * rowBytes + ((col << 1) ^ ((row & 7) << 4));
  return (float)*reinterpret_cast<const bf16_t*>(reinterpret_cast<const char*>(base) + byte);
}
__device__ __forceinline__ void lds_put(bf16_t* base, int row, int col, int rowBytes, float v) {
  int byte = row * rowBytes + ((col << 1) ^ ((row & 7) << 4));
  *reinterpret_cast<bf16_t*>(reinterpret_cast<char*>(base) + byte) = (bf16_t)v;
}

// Stage a [64 x 256] f32 tile -> single bf16 swizzled LDS (rowBytes/colOff params).
__device__ __forceinline__ void stage_f32c(bf16_t* lds, const float* src, long row0,
                                           int rowBytesLds, int colOffBytes,
                                           int tid, int nthr) {
  for (int e = tid * 4; e < 64 * 256; e += nthr * 4) {
    int r = e >> 8, c = e & 255;
    float4 v = *reinterpret_cast<const float4*>(src + (row0 + r) * 256 + c);
    bf16_t t4[4] = {(bf16_t)v.x, (bf16_t)v.y, (bf16_t)v.z, (bf16_t)v.w};
    int db = r * rowBytesLds + (((c << 1) + colOffBytes) ^ ((r & 7) << 4));
    *reinterpret_cast<uint2*>(reinterpret_cast<char*>(lds) + db) =
        *reinterpret_cast<const uint2*>(t4);
  }
}

// ---------------------------------------------------------------------------
// Weights f32 -> bf16 in ws. Offsets (elements): fc_gru_w 0, in_proj_w 65536,
// out_proj_w 262144, att_w 327680, gru_wih 458752, gru_whh 655360, fc2_w 851968.
// ---------------------------------------------------------------------------
__global__ __launch_bounds__(256) void cvt_weights(const float* __restrict__ w0,
                                                   const float* __restrict__ w1,
                                                   const float* __restrict__ w2,
                                                   const float* __restrict__ w3,
                                                   const float* __restrict__ w4,
                                                   const float* __restrict__ w5,
                                                   const float* __restrict__ w6,
                                                   bf16_t* __restrict__ dst) {
  long e = ((long)blockIdx.x * 256 + threadIdx.x) * 4;
  const float* src; long off;
  if (e < 65536)       { src = w0; off = 0; }
  else if (e < 262144) { src = w1; off = 65536; }
  else if (e < 327680) { src = w2; off = 262144; }
  else if (e < 458752) { src = w3; off = 327680; }
  else if (e < 655360) { src = w4; off = 458752; }
  else if (e < 851968) { src = w5; off = 655360; }
  else                 { src = w6; off = 851968; }
  float4 v = *reinterpret_cast<const float4*>(src + (e - off));
  bf16_t o[4] = {(bf16_t)v.x, (bf16_t)v.y, (bf16_t)v.z, (bf16_t)v.w};
  *reinterpret_cast<uint2*>(dst + e) = *reinterpret_cast<const uint2*>(o);
}

// ---------------------------------------------------------------------------
// x = relu(inputs @ fc_gru_w^T + b): f32 in (single bf16 operand), f32 out.
// 32 KB LDS -> multi-block/CU.
// ---------------------------------------------------------------------------
__global__ __launch_bounds__(256, 2) void gemm1(const float* __restrict__ X,
                                                const bf16_t* __restrict__ W,
                                                const float* __restrict__ Bi,
                                                float* __restrict__ C) {
  __shared__ bf16_t Xs[64 * 256];
  const int tid = threadIdx.x, lane = tid & 63, wv = tid >> 6;
  const int rl = lane & 15, kof = (lane >> 4) << 3, ro4 = (lane >> 4) << 2;
  const long m0 = (long)blockIdx.x * 64;
  stage_f32c(Xs, X, m0, 512, 0, tid, 256);
  __syncthreads();
  f32x4 acc[4][4] = {};
#pragma unroll 1
  for (int kk = 0; kk < 256; kk += 32) {
    bf16x8 a[4], bb[4];
#pragma unroll
    for (int rt = 0; rt < 4; ++rt) a[rt] = lds_frag(Xs, rt * 16 + rl, kk + kof, 512);
#pragma unroll
    for (int ct = 0; ct < 4; ++ct)
      bb[ct] = *reinterpret_cast<const bf16x8*>(W + (long)(wv * 64 + ct * 16 + rl) * 256 + kk + kof);
#pragma unroll
    for (int rt = 0; rt < 4; ++rt)
#pragma unroll
      for (int ct = 0; ct < 4; ++ct) acc[rt][ct] = mfma16(a[rt], bb[ct], acc[rt][ct]);
  }
#pragma unroll
  for (int ct = 0; ct < 4; ++ct) {
    int c = wv * 64 + ct * 16 + rl;
    float bv = Bi[c];
#pragma unroll
    for (int rt = 0; rt < 4; ++rt)
#pragma unroll
      for (int i = 0; i < 4; ++i)
        C[(m0 + rt * 16 + ro4 + i) * 256 + c] = fmaxf(acc[rt][ct][i] + bv, 0.f);
  }
}

// ---------------------------------------------------------------------------
// Fused per-sample attention, single-bf16 operands. Block = 1 sample, 512 thr.
// LDS 112 KB: X 32K (later ctx) | Q 32K (later V^T) | K 32K (later P 8K) | SS 16K.
// ---------------------------------------------------------------------------
__global__ __launch_bounds__(512, 2) void attn_kernel(const float* __restrict__ Xf,
                                                      float* __restrict__ Xatt,
                                                      const bf16_t* __restrict__ Wqkv,
                                                      const float* __restrict__ Bqkv,
                                                      const bf16_t* __restrict__ Wo,
                                                      const float* __restrict__ Bo,
                                                      const int* __restrict__ drop) {
  __shared__ __align__(16) char buf[114688];
  bf16_t* XS = reinterpret_cast<bf16_t*>(buf);            // 32K, swz 512; later ctx
  bf16_t* QS = reinterpret_cast<bf16_t*>(buf + 32768);    // 32K, swz 512; later V^T swz 128
  bf16_t* KS = reinterpret_cast<bf16_t*>(buf + 65536);    // 32K, swz 512; later P swz 128
  float*  SS = reinterpret_cast<float*>(buf + 98304);     // 16K [64][64]
  bf16_t* PS = KS;                                        // 8K  [64][64] over K
  const int tid = threadIdx.x, lane = tid & 63, wv = tid >> 6;
  const int rl = lane & 15, kof = (lane >> 4) << 3, ro4 = (lane >> 4) << 2;
  const int b = blockIdx.x;
  const long R0 = (long)b * 64;
  stage_f32c(XS, Xf, R0, 512, 0, tid, 512);
  __syncthreads();
  const int c0 = wv * 32;

  // q and k GEMMs -> bf16 swizzled LDS
  for (int which = 0; which < 2; ++which) {
    const bf16_t* Wp = Wqkv + (long)which * 65536;
    bf16_t* outp = which ? KS : QS;
    f32x4 acc[4][2] = {};
#pragma unroll 1
    for (int kk = 0; kk < 256; kk += 32) {
      bf16x8 a[4], bb[2];
#pragma unroll
      for (int rt = 0; rt < 4; ++rt) a[rt] = lds_frag(XS, rt * 16 + rl, kk + kof, 512);
#pragma unroll
      for (int ct = 0; ct < 2; ++ct)
        bb[ct] = *reinterpret_cast<const bf16x8*>(Wp + (long)(c0 + ct * 16 + rl) * 256 + kk + kof);
#pragma unroll
      for (int rt = 0; rt < 4; ++rt)
#pragma unroll
        for (int ct = 0; ct < 2; ++ct) acc[rt][ct] = mfma16(a[rt], bb[ct], acc[rt][ct]);
    }
#pragma unroll
    for (int ct = 0; ct < 2; ++ct) {
      int c = c0 + ct * 16 + rl;
      float bv = Bqkv[which * 256 + c];
#pragma unroll
      for (int rt = 0; rt < 4; ++rt)
#pragma unroll
        for (int i = 0; i < 4; ++i) lds_put(outp, rt * 16 + ro4 + i, c, 512, acc[rt][ct][i] + bv);
    }
  }
  __syncthreads();

  // scores = q k^T * scale, masked (int32 mask) -> SS f32
  {
    const int rt0 = (wv & 3) * 16, sc0 = (wv >> 2) * 32;
    f32x4 acc[2] = {};
#pragma unroll 1
    for (int kk = 0; kk < 256; kk += 32) {
      bf16x8 a = lds_frag(QS, rt0 + rl, kk + kof, 512);
#pragma unroll
      for (int ct = 0; ct < 2; ++ct) {
        bf16x8 bb = lds_frag(KS, sc0 + ct * 16 + rl, kk + kof, 512);
        acc[ct] = mfma16(a, bb, acc[ct]);
      }
    }
#pragma unroll
    for (int ct = 0; ct < 2; ++ct)
#pragma unroll
      for (int i = 0; i < 4; ++i) {
        int rr = rt0 + ro4 + i, cc = sc0 + ct * 16 + rl;
        float s = acc[ct][i] * 0.0625f;
        if (drop[(long)b * 4096 + rr * 64 + cc]) s = -1e9f;
        SS[rr * 64 + cc] = s;
      }
  }
  __syncthreads();

  // v GEMM -> V^T [256][64] bf16 over Q region (q dead)
  {
    const bf16_t* Wp = Wqkv + (long)2 * 65536;
    f32x4 acc[4][2] = {};
#pragma unroll 1
    for (int kk = 0; kk < 256; kk += 32) {
      bf16x8 a[4], bb[2];
#pragma unroll
      for (int rt = 0; rt < 4; ++rt) a[rt] = lds_frag(XS, rt * 16 + rl, kk + kof, 512);
#pragma unroll
      for (int ct = 0; ct < 2; ++ct)
        bb[ct] = *reinterpret_cast<const bf16x8*>(Wp + (long)(c0 + ct * 16 + rl) * 256 + kk + kof);
#pragma unroll
      for (int rt = 0; rt < 4; ++rt)
#pragma unroll
        for (int ct = 0; ct < 2; ++ct) acc[rt][ct] = mfma16(a[rt], bb[ct], acc[rt][ct]);
    }
#pragma unroll
    for (int ct = 0; ct < 2; ++ct) {
      int c = c0 + ct * 16 + rl;
      float bv = Bqkv[512 + c];
#pragma unroll
      for (int rt = 0; rt < 4; ++rt)
#pragma unroll
        for (int i = 0; i < 4; ++i) {
          int j = rt * 16 + ro4 + i;                    // agent (key) index
          lds_put(QS, c, j, 128, acc[rt][ct][i] + bv);  // V^T[c][j]
        }
    }
  }
  // wave-parallel softmax -> P (bf16) over K region (k dead)
  for (int j = 0; j < 8; ++j) {
    int rr = wv * 8 + j;
    float s = SS[rr * 64 + lane];
    float m = s;
#pragma unroll
    for (int off = 32; off >= 1; off >>= 1) m = fmaxf(m, __shfl_xor(m, off));
    float e = __expf(s - m);
    float sum = e;
#pragma unroll
    for (int off = 32; off >= 1; off >>= 1) sum += __shfl_xor(sum, off);
    lds_put(PS, rr, lane, 128, e / sum);
  }
  __syncthreads();

  // ctx = P @ V -> ctx over X region (x dead)
  {
    f32x4 acc[4][2] = {};
#pragma unroll
    for (int kk = 0; kk < 64; kk += 32) {
      bf16x8 a[4], bb[2];
#pragma unroll
      for (int rt = 0; rt < 4; ++rt) a[rt] = lds_frag(PS, rt * 16 + rl, kk + kof, 128);
#pragma unroll
      for (int ct = 0; ct < 2; ++ct) bb[ct] = lds_frag(QS, c0 + ct * 16 + rl, kk + kof, 128);
#pragma unroll
      for (int rt = 0; rt < 4; ++rt)
#pragma unroll
        for (int ct = 0; ct < 2; ++ct) acc[rt][ct] = mfma16(a[rt], bb[ct], acc[rt][ct]);
    }
    __syncthreads();
#pragma unroll
    for (int ct = 0; ct < 2; ++ct)
#pragma unroll
      for (int rt = 0; rt < 4; ++rt)
#pragma unroll
        for (int i = 0; i < 4; ++i)
          lds_put(XS, rt * 16 + ro4 + i, c0 + ct * 16 + rl, 512, acc[rt][ct][i]);
  }
  __syncthreads();

  // x_att = ctx @ Wo^T + Bo -> f32 global
  {
    f32x4 acc[4][2] = {};
#pragma unroll 1
    for (int kk = 0; kk < 256; kk += 32) {
      bf16x8 a[4], bb[2];
#pragma unroll
      for (int rt = 0; rt < 4; ++rt) a[rt] = lds_frag(XS, rt * 16 + rl, kk + kof, 512);
#pragma unroll
      for (int ct = 0; ct < 2; ++ct)
        bb[ct] = *reinterpret_cast<const bf16x8*>(Wo + (long)(c0 + ct * 16 + rl) * 256 + kk + kof);
#pragma unroll
      for (int rt = 0; rt < 4; ++rt)
#pragma unroll
        for (int ct = 0; ct < 2; ++ct) acc[rt][ct] = mfma16(a[rt], bb[ct], acc[rt][ct]);
    }
#pragma unroll
    for (int ct = 0; ct < 2; ++ct) {
      int c = c0 + ct * 16 + rl;
      float bv = Bo[c];
#pragma unroll
      for (int rt = 0; rt < 4; ++rt)
#pragma unroll
        for (int i = 0; i < 4; ++i)
          Xatt[(R0 + rt * 16 + ro4 + i) * 256 + c] = acc[rt][ct][i] + bv;
    }
  }
}

// ---------------------------------------------------------------------------
// x_ = relu([x | x_att] @ att_w^T + b), single-bf16 operands, f32 in/out.
// ---------------------------------------------------------------------------
__global__ __launch_bounds__(256, 2) void gemm_cat(float* __restrict__ Xa,
                                                   const float* __restrict__ Xb,
                                                   const bf16_t* __restrict__ W,
                                                   const float* __restrict__ Bi) {
  __shared__ bf16_t Cs[64 * 512];  // 64K
  const int tid = threadIdx.x, lane = tid & 63, wv = tid >> 6;
  const int rl = lane & 15, kof = (lane >> 4) << 3, ro4 = (lane >> 4) << 2;
  const long m0 = (long)blockIdx.x * 64;
  stage_f32c(Cs, Xa, m0, 1024, 0, tid, 256);
  stage_f32c(Cs, Xb, m0, 1024, 512, tid, 256);
  __syncthreads();
  f32x4 acc[4][4] = {};
#pragma unroll 1
  for (int kk = 0; kk < 512; kk += 32) {
    bf16x8 a[4], bb[4];
#pragma unroll
    for (int rt = 0; rt < 4; ++rt) a[rt] = lds_frag(Cs, rt * 16 + rl, kk + kof, 1024);
#pragma unroll
    for (int ct = 0; ct < 4; ++ct)
      bb[ct] = *reinterpret_cast<const bf16x8*>(W + (long)(wv * 64 + ct * 16 + rl) * 512 + kk + kof);
#pragma unroll
    for (int rt = 0; rt < 4; ++rt)
#pragma unroll
      for (int ct = 0; ct < 4; ++ct) acc[rt][ct] = mfma16(a[rt], bb[ct], acc[rt][ct]);
  }
#pragma unroll
  for (int ct = 0; ct < 4; ++ct) {
    int c = wv * 64 + ct * 16 + rl;
    float bv = Bi[c];
#pragma unroll
    for (int rt = 0; rt < 4; ++rt)
#pragma unroll
      for (int i = 0; i < 4; ++i)
        Xa[(m0 + rt * 16 + ro4 + i) * 256 + c] = fmaxf(acc[rt][ct][i] + bv, 0.f);
  }
}

// ---------------------------------------------------------------------------
// Fused GRUCell v4 (r12 proven) + (512,4) to co-reside 2 blocks/CU
// (r12 Occupancy 23% = 1 block/CU despite 64KB LDS; VGPR 100 <= 128 cap).
// ---------------------------------------------------------------------------
__global__ __launch_bounds__(512, 4) void gru_kernel(const float* __restrict__ Xf,
                                                     const float* __restrict__ Hin,
                                                     const bf16_t* __restrict__ Wih,
                                                     const bf16_t* __restrict__ Whh,
                                                     const float* __restrict__ bih,
                                                     const float* __restrict__ bhh,
                                                     float* __restrict__ Hout) {
  __shared__ bf16_t Xs[64 * 256], Hs[64 * 256];
  const int tid = threadIdx.x, lane = tid & 63, wv = tid >> 6;
  const int rl = lane & 15, kof = (lane >> 4) << 3, ro4 = (lane >> 4) << 2;
  for (int t = 0; t < 4; ++t) {
    const long m0 = ((long)blockIdx.x * 4 + t) * 64;
    if (t) __syncthreads();  // all waves done with LDS before re-stage
    stage_f32c(Xs, Xf, m0, 512, 0, tid, 512);
    stage_f32c(Hs, Hin, m0, 512, 0, tid, 512);
    __syncthreads();
#pragma unroll 1
    for (int p = 0; p < 2; ++p) {
      const int c0 = p * 128 + wv * 16;
      f32x4 aRZ[2][4] = {}, aIN[4] = {}, aHN[4] = {};
      // x-phase: x@Wih^T into r,z (merged) and i_n
#pragma unroll 1
      for (int kk = 0; kk < 256; kk += 32) {
        bf16x8 ax[4], bI[3];
#pragma unroll
        for (int rt = 0; rt < 4; ++rt) ax[rt] = lds_frag(Xs, rt * 16 + rl, kk + kof, 512);
#pragma unroll
        for (int g = 0; g < 3; ++g)
          bI[g] = *reinterpret_cast<const bf16x8*>(Wih + (long)(g * 256 + c0 + rl) * 256 + kk + kof);
#pragma unroll
        for (int rt = 0; rt < 4; ++rt) {
          aRZ[0][rt] = mfma16(ax[rt], bI[0], aRZ[0][rt]);
          aRZ[1][rt] = mfma16(ax[rt], bI[1], aRZ[1][rt]);
          aIN[rt]    = mfma16(ax[rt], bI[2], aIN[rt]);
        }
      }
      // h-phase: h@Whh^T into r,z (same accs) and h_n (separate)
#pragma unroll 1
      for (int kk = 0; kk < 256; kk += 32) {
        bf16x8 ah_[4], bH[3];
#pragma unroll
        for (int rt = 0; rt < 4; ++rt) ah_[rt] = lds_frag(Hs, rt * 16 + rl, kk + kof, 512);
#pragma unroll
        for (int g = 0; g < 3; ++g)
          bH[g] = *reinterpret_cast<const bf16x8*>(Whh + (long)(g * 256 + c0 + rl) * 256 + kk + kof);
#pragma unroll
        for (int rt = 0; rt < 4; ++rt) {
          aRZ[0][rt] = mfma16(ah_[rt], bH[0], aRZ[0][rt]);
          aRZ[1][rt] = mfma16(ah_[rt], bH[1], aRZ[1][rt]);
          aHN[rt]    = mfma16(ah_[rt], bH[2], aHN[rt]);
        }
      }
      const int c = c0 + rl;
      float br  = bih[c] + bhh[c];
      float bz  = bih[256 + c] + bhh[256 + c];
      float bin_ = bih[512 + c], bhn = bhh[512 + c];
#pragma unroll
      for (int rt = 0; rt < 4; ++rt)
#pragma unroll
        for (int i = 0; i < 4; ++i) {
          int rloc = rt * 16 + ro4 + i;
          float rg = 1.f / (1.f + __expf(-(aRZ[0][rt][i] + br)));
          float zg = 1.f / (1.f + __expf(-(aRZ[1][rt][i] + bz)));
          float nx = aIN[rt][i] + bin_ + rg * (aHN[rt][i] + bhn);
          float ng = 1.f - 2.f / (__expf(2.f * nx) + 1.f);  // tanh, saturation-safe
          float hv = lds_get1(Hs, rloc, c, 512);            // h_in from LDS (bf16)
          Hout[(m0 + rloc) * 256 + c] = (1.f - zg) * ng + zg * hv;
        }
    }
  }
}

// tactic_q = h @ fc2_w^T + b, single-bf16 h. 256 thr / 4 waves, 16 rows/wave.
__global__ __launch_bounds__(256, 2) void fc2_kernel(const float* __restrict__ h,
                                                     const bf16_t* __restrict__ Wt,
                                                     const float* __restrict__ bt,
                                                     float* __restrict__ out) {
  __shared__ bf16_t Hs[64 * 256];
  const int tid = threadIdx.x, lane = tid & 63, wv = tid >> 6;
  const int rl = lane & 15, kof = (lane >> 4) << 3, ro4 = (lane >> 4) << 2;
  const long m0 = (long)blockIdx.x * 64;
  stage_f32c(Hs, h, m0, 512, 0, tid, 256);
  __syncthreads();
  f32x4 acc = {};
#pragma unroll 1
  for (int kk = 0; kk < 256; kk += 32) {
    bf16x8 a = lds_frag(Hs, wv * 16 + rl, kk + kof, 512);
    bf16x8 bb = *reinterpret_cast<const bf16x8*>(Wt + (long)rl * 256 + kk + kof);
    acc = mfma16(a, bb, acc);
  }
  float bv = bt[rl];
#pragma unroll
  for (int i = 0; i < 4; ++i) out[(m0 + wv * 16 + ro4 + i) * 16 + rl] = acc[i] + bv;
}

// int32 bool -> f32 {0,1} copy, 4 elems/thread
__global__ __launch_bounds__(256) void drop_copy(const int* __restrict__ d,
                                                 float* __restrict__ o) {
  long i = (long)blockIdx.x * 256 + threadIdx.x;
  int4 v = reinterpret_cast<const int4*>(d)[i];
  float4 r;
  r.x = v.x ? 1.f : 0.f;
  r.y = v.y ? 1.f : 0.f;
  r.z = v.z ? 1.f : 0.f;
  r.w = v.w ? 1.f : 0.f;
  reinterpret_cast<float4*>(o)[i] = r;
}

extern "C" void kernel_launch(void* const* d_in, const int* in_sizes, int n_in,
                              void* d_out, int out_size, void* d_ws, size_t ws_size,
                              hipStream_t stream) {
  (void)in_sizes; (void)n_in; (void)out_size; (void)ws_size;
  const float* inputs      = (const float*)d_in[0];
  const float* hidden      = (const float*)d_in[1];
  const int*   drp         = (const int*)d_in[2];   // bool pushed as int32
  // d_in[3] = t (unused)
  const float* fc_gru_w    = (const float*)d_in[4];
  const float* fc_gru_b    = (const float*)d_in[5];
  const float* in_proj_w   = (const float*)d_in[6];
  const float* in_proj_b   = (const float*)d_in[7];
  const float* out_proj_w  = (const float*)d_in[8];
  const float* out_proj_b  = (const float*)d_in[9];
  const float* att_w       = (const float*)d_in[10];
  const float* att_b       = (const float*)d_in[11];
  const float* gru_wih     = (const float*)d_in[12];
  const float* gru_whh     = (const float*)d_in[13];
  const float* gru_bih     = (const float*)d_in[14];
  const float* gru_bhh     = (const float*)d_in[15];
  const float* fc2_w       = (const float*)d_in[16];
  const float* fc2_b       = (const float*)d_in[17];

  float* out_t = (float*)d_out;          // [M,16]
  float* out_h = out_t + MTOT * 16;      // [M,256] f32: x_att, then h
  float* out_d = out_h + MTOT * 256;     // [B*64*64] f32

  float*  A  = (float*)d_ws;             // [M,256] f32: x, then x_   (128 MB)
  bf16_t* Wb = (bf16_t*)(A + MTOT * 256);  // bf16 weights (1.7 MB)

  // 0) weights f32 -> bf16
  cvt_weights<<<836, 256, 0, stream>>>(fc_gru_w, in_proj_w, out_proj_w, att_w,
                                       gru_wih, gru_whh, fc2_w, Wb);
  // 1) x = relu(inputs @ fc_gru_w^T + b) -> A (f32)
  gemm1<<<2048, 256, 0, stream>>>(inputs, Wb, fc_gru_b, A);
  // 2) fused attention: x -> x_att (f32, parked in out_h)
  attn_kernel<<<2048, 512, 0, stream>>>(A, out_h, Wb + 65536, in_proj_b,
                                        Wb + 262144, out_proj_b, drp);
  // 3) x_ = relu([x | x_att] @ att_w^T + b) -> A (f32, in-place)
  gemm_cat<<<2048, 256, 0, stream>>>(A, out_h, Wb + 327680, att_b);
  // 4) GRU: x_ (A) + hidden -> h -> out_h (f32, overwrites x_att); 4 tiles/block
  gru_kernel<<<512, 512, 0, stream>>>(A, hidden, Wb + 458752, Wb + 655360,
                                      gru_bih, gru_bhh, out_h);
  // 5) tactic_q = h @ fc2_w^T + b -> out_t
  fc2_kernel<<<2048, 256, 0, stream>>>(out_h, Wb + 851968, fc2_b, out_t);
  // 6) drop mask echo as f32 (8388608 elems / 4 per thread / 256 = 8192 blocks)
  drop_copy<<<8192, 256, 0, stream>>>(drp, out_d);
}

// Round 14
// 782.577 us; speedup vs baseline: 2.3615x; 1.0636x over previous
//
#include <hip/hip_runtime.h>

typedef __bf16 bf16_t;
using bf16x8 = __bf16 __attribute__((ext_vector_type(8)));
using f32x4  = float __attribute__((ext_vector_type(4)));

// B=2048, N=64, D=256, H=256, T=16
static constexpr long MTOT = 131072;   // B*N

__device__ __forceinline__ f32x4 mfma16(bf16x8 a, bf16x8 b, f32x4 c) {
  return __builtin_amdgcn_mfma_f32_16x16x32_bf16(a, b, c, 0, 0, 0);
}

// Swizzled LDS tiles: element (row,k) at byte row*rowBytes + ((k*2 + colOff) ^ ((row&7)<<4)).
__device__ __forceinline__ bf16x8 lds_frag(const bf16_t* base, int row, int k, int rowBytes) {
  int byte = row * rowBytes + ((k << 1) ^ ((row & 7) << 4));
  return *reinterpret_cast<const bf16x8*>(reinterpret_cast<const char*>(base) + byte);
}
__device__ __forceinline__ float lds_get1(const bf16_t* base, int row, int col, int rowBytes) {
  int byte = row * rowBytes + ((col << 1) ^ ((row & 7) << 4));
  return (float)*reinterpret_cast<const bf16_t*>(reinterpret_cast<const char*>(base) + byte);
}
__device__ __forceinline__ void lds_put(bf16_t* base, int row, int col, int rowBytes, float v) {
  int byte = row * rowBytes + ((col << 1) ^ ((row & 7) << 4));
  *reinterpret_cast<bf16_t*>(reinterpret_cast<char*>(base) + byte) = (bf16_t)v;
}

// Stage a [64 x 256] f32 tile -> single bf16 swizzled LDS (rowBytes/colOff params).
__device__ __forceinline__ void stage_f32c(bf16_t* lds, const float* src, long row0,
                                           int rowBytesLds, int colOffBytes,
                                           int tid, int nthr) {
  for (int e = tid * 4; e < 64 * 256; e += nthr * 4) {
    int r = e >> 8, c = e & 255;
    float4 v = *reinterpret_cast<const float4*>(src + (row0 + r) * 256 + c);
    bf16_t t4[4] = {(bf16_t)v.x, (bf16_t)v.y, (bf16_t)v.z, (bf16_t)v.w};
    int db = r * rowBytesLds + (((c << 1) + colOffBytes) ^ ((r & 7) << 4));
    *reinterpret_cast<uint2*>(reinterpret_cast<char*>(lds) + db) =
        *reinterpret_cast<const uint2*>(t4);
  }
}

// ---------------------------------------------------------------------------
// Weights f32 -> bf16 in ws. Offsets (elements): fc_gru_w 0, in_proj_w 65536,
// out_proj_w 262144, att_w 327680, gru_wih 458752, gru_whh 655360, fc2_w 851968.
// ---------------------------------------------------------------------------
__global__ __launch_bounds__(256) void cvt_weights(const float* __restrict__ w0,
                                                   const float* __restrict__ w1,
                                                   const float* __restrict__ w2,
                                                   const float* __restrict__ w3,
                                                   const float* __restrict__ w4,
                                                   const float* __restrict__ w5,
                                                   const float* __restrict__ w6,
                                                   bf16_t* __restrict__ dst) {
  long e = ((long)blockIdx.x * 256 + threadIdx.x) * 4;
  const float* src; long off;
  if (e < 65536)       { src = w0; off = 0; }
  else if (e < 262144) { src = w1; off = 65536; }
  else if (e < 327680) { src = w2; off = 262144; }
  else if (e < 458752) { src = w3; off = 327680; }
  else if (e < 655360) { src = w4; off = 458752; }
  else if (e < 851968) { src = w5; off = 655360; }
  else                 { src = w6; off = 851968; }
  float4 v = *reinterpret_cast<const float4*>(src + (e - off));
  bf16_t o[4] = {(bf16_t)v.x, (bf16_t)v.y, (bf16_t)v.z, (bf16_t)v.w};
  *reinterpret_cast<uint2*>(dst + e) = *reinterpret_cast<const uint2*>(o);
}

// ---------------------------------------------------------------------------
// x = relu(inputs @ fc_gru_w^T + b): f32 in (single bf16 operand), f32 out.
// ---------------------------------------------------------------------------
__global__ __launch_bounds__(256, 2) void gemm1(const float* __restrict__ X,
                                                const bf16_t* __restrict__ W,
                                                const float* __restrict__ Bi,
                                                float* __restrict__ C) {
  __shared__ bf16_t Xs[64 * 256];
  const int tid = threadIdx.x, lane = tid & 63, wv = tid >> 6;
  const int rl = lane & 15, kof = (lane >> 4) << 3, ro4 = (lane >> 4) << 2;
  const long m0 = (long)blockIdx.x * 64;
  stage_f32c(Xs, X, m0, 512, 0, tid, 256);
  __syncthreads();
  f32x4 acc[4][4] = {};
#pragma unroll 1
  for (int kk = 0; kk < 256; kk += 32) {
    bf16x8 a[4], bb[4];
#pragma unroll
    for (int rt = 0; rt < 4; ++rt) a[rt] = lds_frag(Xs, rt * 16 + rl, kk + kof, 512);
#pragma unroll
    for (int ct = 0; ct < 4; ++ct)
      bb[ct] = *reinterpret_cast<const bf16x8*>(W + (long)(wv * 64 + ct * 16 + rl) * 256 + kk + kof);
#pragma unroll
    for (int rt = 0; rt < 4; ++rt)
#pragma unroll
      for (int ct = 0; ct < 4; ++ct) acc[rt][ct] = mfma16(a[rt], bb[ct], acc[rt][ct]);
  }
#pragma unroll
  for (int ct = 0; ct < 4; ++ct) {
    int c = wv * 64 + ct * 16 + rl;
    float bv = Bi[c];
#pragma unroll
    for (int rt = 0; rt < 4; ++rt)
#pragma unroll
      for (int i = 0; i < 4; ++i)
        C[(m0 + rt * 16 + ro4 + i) * 256 + c] = fmaxf(acc[rt][ct][i] + bv, 0.f);
  }
}

// ---------------------------------------------------------------------------
// Fused per-sample attention, single-bf16 operands. Block = 1 sample, 512 thr.
// LDS 112 KB: X 32K (later ctx) | Q 32K (later V^T) | K 32K (later P 8K) | SS 16K.
// ---------------------------------------------------------------------------
__global__ __launch_bounds__(512, 2) void attn_kernel(const float* __restrict__ Xf,
                                                      float* __restrict__ Xatt,
                                                      const bf16_t* __restrict__ Wqkv,
                                                      const float* __restrict__ Bqkv,
                                                      const bf16_t* __restrict__ Wo,
                                                      const float* __restrict__ Bo,
                                                      const int* __restrict__ drop) {
  __shared__ __align__(16) char buf[114688];
  bf16_t* XS = reinterpret_cast<bf16_t*>(buf);            // 32K, swz 512; later ctx
  bf16_t* QS = reinterpret_cast<bf16_t*>(buf + 32768);    // 32K, swz 512; later V^T swz 128
  bf16_t* KS = reinterpret_cast<bf16_t*>(buf + 65536);    // 32K, swz 512; later P swz 128
  float*  SS = reinterpret_cast<float*>(buf + 98304);     // 16K [64][64]
  bf16_t* PS = KS;                                        // 8K  [64][64] over K
  const int tid = threadIdx.x, lane = tid & 63, wv = tid >> 6;
  const int rl = lane & 15, kof = (lane >> 4) << 3, ro4 = (lane >> 4) << 2;
  const int b = blockIdx.x;
  const long R0 = (long)b * 64;
  stage_f32c(XS, Xf, R0, 512, 0, tid, 512);
  __syncthreads();
  const int c0 = wv * 32;

  // q and k GEMMs -> bf16 swizzled LDS
  for (int which = 0; which < 2; ++which) {
    const bf16_t* Wp = Wqkv + (long)which * 65536;
    bf16_t* outp = which ? KS : QS;
    f32x4 acc[4][2] = {};
#pragma unroll 1
    for (int kk = 0; kk < 256; kk += 32) {
      bf16x8 a[4], bb[2];
#pragma unroll
      for (int rt = 0; rt < 4; ++rt) a[rt] = lds_frag(XS, rt * 16 + rl, kk + kof, 512);
#pragma unroll
      for (int ct = 0; ct < 2; ++ct)
        bb[ct] = *reinterpret_cast<const bf16x8*>(Wp + (long)(c0 + ct * 16 + rl) * 256 + kk + kof);
#pragma unroll
      for (int rt = 0; rt < 4; ++rt)
#pragma unroll
        for (int ct = 0; ct < 2; ++ct) acc[rt][ct] = mfma16(a[rt], bb[ct], acc[rt][ct]);
    }
#pragma unroll
    for (int ct = 0; ct < 2; ++ct) {
      int c = c0 + ct * 16 + rl;
      float bv = Bqkv[which * 256 + c];
#pragma unroll
      for (int rt = 0; rt < 4; ++rt)
#pragma unroll
        for (int i = 0; i < 4; ++i) lds_put(outp, rt * 16 + ro4 + i, c, 512, acc[rt][ct][i] + bv);
    }
  }
  __syncthreads();

  // scores = q k^T * scale, masked (int32 mask) -> SS f32
  {
    const int rt0 = (wv & 3) * 16, sc0 = (wv >> 2) * 32;
    f32x4 acc[2] = {};
#pragma unroll 1
    for (int kk = 0; kk < 256; kk += 32) {
      bf16x8 a = lds_frag(QS, rt0 + rl, kk + kof, 512);
#pragma unroll
      for (int ct = 0; ct < 2; ++ct) {
        bf16x8 bb = lds_frag(KS, sc0 + ct * 16 + rl, kk + kof, 512);
        acc[ct] = mfma16(a, bb, acc[ct]);
      }
    }
#pragma unroll
    for (int ct = 0; ct < 2; ++ct)
#pragma unroll
      for (int i = 0; i < 4; ++i) {
        int rr = rt0 + ro4 + i, cc = sc0 + ct * 16 + rl;
        float s = acc[ct][i] * 0.0625f;
        if (drop[(long)b * 4096 + rr * 64 + cc]) s = -1e9f;
        SS[rr * 64 + cc] = s;
      }
  }
  __syncthreads();

  // v GEMM -> V^T [256][64] bf16 over Q region (q dead)
  {
    const bf16_t* Wp = Wqkv + (long)2 * 65536;
    f32x4 acc[4][2] = {};
#pragma unroll 1
    for (int kk = 0; kk < 256; kk += 32) {
      bf16x8 a[4], bb[2];
#pragma unroll
      for (int rt = 0; rt < 4; ++rt) a[rt] = lds_frag(XS, rt * 16 + rl, kk + kof, 512);
#pragma unroll
      for (int ct = 0; ct < 2; ++ct)
        bb[ct] = *reinterpret_cast<const bf16x8*>(Wp + (long)(c0 + ct * 16 + rl) * 256 + kk + kof);
#pragma unroll
      for (int rt = 0; rt < 4; ++rt)
#pragma unroll
        for (int ct = 0; ct < 2; ++ct) acc[rt][ct] = mfma16(a[rt], bb[ct], acc[rt][ct]);
    }
#pragma unroll
    for (int ct = 0; ct < 2; ++ct) {
      int c = c0 + ct * 16 + rl;
      float bv = Bqkv[512 + c];
#pragma unroll
      for (int rt = 0; rt < 4; ++rt)
#pragma unroll
        for (int i = 0; i < 4; ++i) {
          int j = rt * 16 + ro4 + i;                    // agent (key) index
          lds_put(QS, c, j, 128, acc[rt][ct][i] + bv);  // V^T[c][j]
        }
    }
  }
  // wave-parallel softmax -> P (bf16) over K region (k dead)
  for (int j = 0; j < 8; ++j) {
    int rr = wv * 8 + j;
    float s = SS[rr * 64 + lane];
    float m = s;
#pragma unroll
    for (int off = 32; off >= 1; off >>= 1) m = fmaxf(m, __shfl_xor(m, off));
    float e = __expf(s - m);
    float sum = e;
#pragma unroll
    for (int off = 32; off >= 1; off >>= 1) sum += __shfl_xor(sum, off);
    lds_put(PS, rr, lane, 128, e / sum);
  }
  __syncthreads();

  // ctx = P @ V -> ctx over X region (x dead)
  {
    f32x4 acc[4][2] = {};
#pragma unroll
    for (int kk = 0; kk < 64; kk += 32) {
      bf16x8 a[4], bb[2];
#pragma unroll
      for (int rt = 0; rt < 4; ++rt) a[rt] = lds_frag(PS, rt * 16 + rl, kk + kof, 128);
#pragma unroll
      for (int ct = 0; ct < 2; ++ct) bb[ct] = lds_frag(QS, c0 + ct * 16 + rl, kk + kof, 128);
#pragma unroll
      for (int rt = 0; rt < 4; ++rt)
#pragma unroll
        for (int ct = 0; ct < 2; ++ct) acc[rt][ct] = mfma16(a[rt], bb[ct], acc[rt][ct]);
    }
    __syncthreads();
#pragma unroll
    for (int ct = 0; ct < 2; ++ct)
#pragma unroll
      for (int rt = 0; rt < 4; ++rt)
#pragma unroll
        for (int i = 0; i < 4; ++i)
          lds_put(XS, rt * 16 + ro4 + i, c0 + ct * 16 + rl, 512, acc[rt][ct][i]);
  }
  __syncthreads();

  // x_att = ctx @ Wo^T + Bo -> f32 global
  {
    f32x4 acc[4][2] = {};
#pragma unroll 1
    for (int kk = 0; kk < 256; kk += 32) {
      bf16x8 a[4], bb[2];
#pragma unroll
      for (int rt = 0; rt < 4; ++rt) a[rt] = lds_frag(XS, rt * 16 + rl, kk + kof, 512);
#pragma unroll
      for (int ct = 0; ct < 2; ++ct)
        bb[ct] = *reinterpret_cast<const bf16x8*>(Wo + (long)(c0 + ct * 16 + rl) * 256 + kk + kof);
#pragma unroll
      for (int rt = 0; rt < 4; ++rt)
#pragma unroll
        for (int ct = 0; ct < 2; ++ct) acc[rt][ct] = mfma16(a[rt], bb[ct], acc[rt][ct]);
    }
#pragma unroll
    for (int ct = 0; ct < 2; ++ct) {
      int c = c0 + ct * 16 + rl;
      float bv = Bo[c];
#pragma unroll
      for (int rt = 0; rt < 4; ++rt)
#pragma unroll
        for (int i = 0; i < 4; ++i)
          Xatt[(R0 + rt * 16 + ro4 + i) * 256 + c] = acc[rt][ct][i] + bv;
    }
  }
}

// ---------------------------------------------------------------------------
// x_ = relu([x | x_att] @ att_w^T + b), single-bf16 operands, f32 in/out.
// ---------------------------------------------------------------------------
__global__ __launch_bounds__(256, 2) void gemm_cat(float* __restrict__ Xa,
                                                   const float* __restrict__ Xb,
                                                   const bf16_t* __restrict__ W,
                                                   const float* __restrict__ Bi) {
  __shared__ bf16_t Cs[64 * 512];  // 64K
  const int tid = threadIdx.x, lane = tid & 63, wv = tid >> 6;
  const int rl = lane & 15, kof = (lane >> 4) << 3, ro4 = (lane >> 4) << 2;
  const long m0 = (long)blockIdx.x * 64;
  stage_f32c(Cs, Xa, m0, 1024, 0, tid, 256);
  stage_f32c(Cs, Xb, m0, 1024, 512, tid, 256);
  __syncthreads();
  f32x4 acc[4][4] = {};
#pragma unroll 1
  for (int kk = 0; kk < 512; kk += 32) {
    bf16x8 a[4], bb[4];
#pragma unroll
    for (int rt = 0; rt < 4; ++rt) a[rt] = lds_frag(Cs, rt * 16 + rl, kk + kof, 1024);
#pragma unroll
    for (int ct = 0; ct < 4; ++ct)
      bb[ct] = *reinterpret_cast<const bf16x8*>(W + (long)(wv * 64 + ct * 16 + rl) * 512 + kk + kof);
#pragma unroll
    for (int rt = 0; rt < 4; ++rt)
#pragma unroll
      for (int ct = 0; ct < 4; ++ct) acc[rt][ct] = mfma16(a[rt], bb[ct], acc[rt][ct]);
  }
#pragma unroll
  for (int ct = 0; ct < 4; ++ct) {
    int c = wv * 64 + ct * 16 + rl;
    float bv = Bi[c];
#pragma unroll
    for (int rt = 0; rt < 4; ++rt)
#pragma unroll
      for (int i = 0; i < 4; ++i)
        Xa[(m0 + rt * 16 + ro4 + i) * 256 + c] = fmaxf(acc[rt][ct][i] + bv, 0.f);
  }
}

// ---------------------------------------------------------------------------
// Fused GRUCell v4 + fc2 epilogue. GRU config = r12's proven 321us shape
// (plain (512), VGPR ~100, 1 blk/CU, unroll 1, 4 M-tiles/block).
// Each pass writes h to Hnew (bf16 LDS); after barrier, waves 0-3 compute
// tactic_q = h @ fc2_w^T + bt from Hnew (same bf16(h) operand as the old
// standalone fc2 kernel -> bit-compatible). Saves fc2 launch + 128MB h read.
// ---------------------------------------------------------------------------
__global__ __launch_bounds__(512) void gru_fc2_kernel(const float* __restrict__ Xf,
                                                      const float* __restrict__ Hin,
                                                      const bf16_t* __restrict__ Wih,
                                                      const bf16_t* __restrict__ Whh,
                                                      const float* __restrict__ bih,
                                                      const float* __restrict__ bhh,
                                                      float* __restrict__ Hout,
                                                      const bf16_t* __restrict__ Wt,
                                                      const float* __restrict__ bt,
                                                      float* __restrict__ outT) {
  __shared__ bf16_t Xs[64 * 256], Hs[64 * 256], Hnew[64 * 256];
  const int tid = threadIdx.x, lane = tid & 63, wv = tid >> 6;
  const int rl = lane & 15, kof = (lane >> 4) << 3, ro4 = (lane >> 4) << 2;
  for (int t = 0; t < 4; ++t) {
    const long m0 = ((long)blockIdx.x * 4 + t) * 64;
    if (t) __syncthreads();  // all waves done with LDS before re-stage
    stage_f32c(Xs, Xf, m0, 512, 0, tid, 512);
    stage_f32c(Hs, Hin, m0, 512, 0, tid, 512);
    __syncthreads();
#pragma unroll 1
    for (int p = 0; p < 2; ++p) {
      const int c0 = p * 128 + wv * 16;
      f32x4 aRZ[2][4] = {}, aIN[4] = {}, aHN[4] = {};
      // x-phase: x@Wih^T into r,z (merged) and i_n
#pragma unroll 1
      for (int kk = 0; kk < 256; kk += 32) {
        bf16x8 ax[4], bI[3];
#pragma unroll
        for (int rt = 0; rt < 4; ++rt) ax[rt] = lds_frag(Xs, rt * 16 + rl, kk + kof, 512);
#pragma unroll
        for (int g = 0; g < 3; ++g)
          bI[g] = *reinterpret_cast<const bf16x8*>(Wih + (long)(g * 256 + c0 + rl) * 256 + kk + kof);
#pragma unroll
        for (int rt = 0; rt < 4; ++rt) {
          aRZ[0][rt] = mfma16(ax[rt], bI[0], aRZ[0][rt]);
          aRZ[1][rt] = mfma16(ax[rt], bI[1], aRZ[1][rt]);
          aIN[rt]    = mfma16(ax[rt], bI[2], aIN[rt]);
        }
      }
      // h-phase: h@Whh^T into r,z (same accs) and h_n (separate)
#pragma unroll 1
      for (int kk = 0; kk < 256; kk += 32) {
        bf16x8 ah_[4], bH[3];
#pragma unroll
        for (int rt = 0; rt < 4; ++rt) ah_[rt] = lds_frag(Hs, rt * 16 + rl, kk + kof, 512);
#pragma unroll
        for (int g = 0; g < 3; ++g)
          bH[g] = *reinterpret_cast<const bf16x8*>(Whh + (long)(g * 256 + c0 + rl) * 256 + kk + kof);
#pragma unroll
        for (int rt = 0; rt < 4; ++rt) {
          aRZ[0][rt] = mfma16(ah_[rt], bH[0], aRZ[0][rt]);
          aRZ[1][rt] = mfma16(ah_[rt], bH[1], aRZ[1][rt]);
          aHN[rt]    = mfma16(ah_[rt], bH[2], aHN[rt]);
        }
      }
      const int c = c0 + rl;
      float br  = bih[c] + bhh[c];
      float bz  = bih[256 + c] + bhh[256 + c];
      float bin_ = bih[512 + c], bhn = bhh[512 + c];
#pragma unroll
      for (int rt = 0; rt < 4; ++rt)
#pragma unroll
        for (int i = 0; i < 4; ++i) {
          int rloc = rt * 16 + ro4 + i;
          float rg = 1.f / (1.f + __expf(-(aRZ[0][rt][i] + br)));
          float zg = 1.f / (1.f + __expf(-(aRZ[1][rt][i] + bz)));
          float nx = aIN[rt][i] + bin_ + rg * (aHN[rt][i] + bhn);
          float ng = 1.f - 2.f / (__expf(2.f * nx) + 1.f);  // tanh, saturation-safe
          float hv = lds_get1(Hs, rloc, c, 512);            // h_in from LDS (bf16)
          float h = (1.f - zg) * ng + zg * hv;
          Hout[(m0 + rloc) * 256 + c] = h;
          lds_put(Hnew, rloc, c, 512, h);                   // for fused fc2
        }
    }
    __syncthreads();  // all Hnew strips written
    // fc2: tactic_q[64x16] = Hnew @ fc2_w^T + bt (waves 0-3, 16 rows each)
    if (wv < 4) {
      f32x4 acc = {};
#pragma unroll 1
      for (int kk = 0; kk < 256; kk += 32) {
        bf16x8 a = lds_frag(Hnew, wv * 16 + rl, kk + kof, 512);
        bf16x8 bb = *reinterpret_cast<const bf16x8*>(Wt + (long)rl * 256 + kk + kof);
        acc = mfma16(a, bb, acc);
      }
      float bv = bt[rl];
#pragma unroll
      for (int i = 0; i < 4; ++i) outT[(m0 + wv * 16 + ro4 + i) * 16 + rl] = acc[i] + bv;
    }
  }
}

// int32 bool -> f32 {0,1} copy, 4 elems/thread
__global__ __launch_bounds__(256) void drop_copy(const int* __restrict__ d,
                                                 float* __restrict__ o) {
  long i = (long)blockIdx.x * 256 + threadIdx.x;
  int4 v = reinterpret_cast<const int4*>(d)[i];
  float4 r;
  r.x = v.x ? 1.f : 0.f;
  r.y = v.y ? 1.f : 0.f;
  r.z = v.z ? 1.f : 0.f;
  r.w = v.w ? 1.f : 0.f;
  reinterpret_cast<float4*>(o)[i] = r;
}

extern "C" void kernel_launch(void* const* d_in, const int* in_sizes, int n_in,
                              void* d_out, int out_size, void* d_ws, size_t ws_size,
                              hipStream_t stream) {
  (void)in_sizes; (void)n_in; (void)out_size; (void)ws_size;
  const float* inputs      = (const float*)d_in[0];
  const float* hidden      = (const float*)d_in[1];
  const int*   drp         = (const int*)d_in[2];   // bool pushed as int32
  // d_in[3] = t (unused)
  const float* fc_gru_w    = (const float*)d_in[4];
  const float* fc_gru_b    = (const float*)d_in[5];
  const float* in_proj_w   = (const float*)d_in[6];
  const float* in_proj_b   = (const float*)d_in[7];
  const float* out_proj_w  = (const float*)d_in[8];
  const float* out_proj_b  = (const float*)d_in[9];
  const float* att_w       = (const float*)d_in[10];
  const float* att_b       = (const float*)d_in[11];
  const float* gru_wih     = (const float*)d_in[12];
  const float* gru_whh     = (const float*)d_in[13];
  const float* gru_bih     = (const float*)d_in[14];
  const float* gru_bhh     = (const float*)d_in[15];
  const float* fc2_w       = (const float*)d_in[16];
  const float* fc2_b       = (const float*)d_in[17];

  float* out_t = (float*)d_out;          // [M,16]
  float* out_h = out_t + MTOT * 16;      // [M,256] f32: x_att, then h
  float* out_d = out_h + MTOT * 256;     // [B*64*64] f32

  float*  A  = (float*)d_ws;             // [M,256] f32: x, then x_   (128 MB)
  bf16_t* Wb = (bf16_t*)(A + MTOT * 256);  // bf16 weights (1.7 MB)

  // 0) weights f32 -> bf16
  cvt_weights<<<836, 256, 0, stream>>>(fc_gru_w, in_proj_w, out_proj_w, att_w,
                                       gru_wih, gru_whh, fc2_w, Wb);
  // 1) x = relu(inputs @ fc_gru_w^T + b) -> A (f32)
  gemm1<<<2048, 256, 0, stream>>>(inputs, Wb, fc_gru_b, A);
  // 2) fused attention: x -> x_att (f32, parked in out_h)
  attn_kernel<<<2048, 512, 0, stream>>>(A, out_h, Wb + 65536, in_proj_b,
                                        Wb + 262144, out_proj_b, drp);
  // 3) x_ = relu([x | x_att] @ att_w^T + b) -> A (f32, in-place)
  gemm_cat<<<2048, 256, 0, stream>>>(A, out_h, Wb + 327680, att_b);
  // 4) GRU + fc2: h -> out_h (overwrites x_att), tactic_q -> out_t
  gru_fc2_kernel<<<512, 512, 0, stream>>>(A, hidden, Wb + 458752, Wb + 655360,
                                          gru_bih, gru_bhh, out_h,
                                          Wb + 851968, fc2_b, out_t);
  // 5) drop mask echo as f32 (8388608 elems / 4 per thread / 256 = 8192 blocks)
  drop_copy<<<8192, 256, 0, stream>>>(drp, out_d);
}

// Round 15
// 631.246 us; speedup vs baseline: 2.9276x; 1.2397x over previous
//
#include <hip/hip_runtime.h>

typedef __bf16 bf16_t;
using bf16x8 = __bf16 __attribute__((ext_vector_type(8)));
using f32x4  = float __attribute__((ext_vector_type(4)));

// B=2048, N=64, D=256, H=256, T=16
static constexpr long MTOT = 131072;   // B*N

__device__ __forceinline__ f32x4 mfma16(bf16x8 a, bf16x8 b, f32x4 c) {
  return __builtin_amdgcn_mfma_f32_16x16x32_bf16(a, b, c, 0, 0, 0);
}

// Swizzled LDS tiles: element (row,k) at byte row*rowBytes + ((k*2) ^ ((row&7)<<4)).
__device__ __forceinline__ bf16x8 lds_frag(const bf16_t* base, int row, int k, int rowBytes) {
  int byte = row * rowBytes + ((k << 1) ^ ((row & 7) << 4));
  return *reinterpret_cast<const bf16x8*>(reinterpret_cast<const char*>(base) + byte);
}
__device__ __forceinline__ float lds_get1(const bf16_t* base, int row, int col, int rowBytes) {
  int byte = row * rowBytes + ((col << 1) ^ ((row & 7) << 4));
  return (float)*reinterpret_cast<const bf16_t*>(reinterpret_cast<const char*>(base) + byte);
}
__device__ __forceinline__ void lds_put(bf16_t* base, int row, int col, int rowBytes, float v) {
  int byte = row * rowBytes + ((col << 1) ^ ((row & 7) << 4));
  *reinterpret_cast<bf16_t*>(reinterpret_cast<char*>(base) + byte) = (bf16_t)v;
}

// Stage a [64 x 256] f32 tile -> single bf16 swizzled LDS.
__device__ __forceinline__ void stage_f32c(bf16_t* lds, const float* src, long row0,
                                           int rowBytesLds, int colOffBytes,
                                           int tid, int nthr) {
  for (int e = tid * 4; e < 64 * 256; e += nthr * 4) {
    int r = e >> 8, c = e & 255;
    float4 v = *reinterpret_cast<const float4*>(src + (row0 + r) * 256 + c);
    bf16_t t4[4] = {(bf16_t)v.x, (bf16_t)v.y, (bf16_t)v.z, (bf16_t)v.w};
    int db = r * rowBytesLds + (((c << 1) + colOffBytes) ^ ((r & 7) << 4));
    *reinterpret_cast<uint2*>(reinterpret_cast<char*>(lds) + db) =
        *reinterpret_cast<const uint2*>(t4);
  }
}

// ---------------------------------------------------------------------------
// Weights f32 -> bf16 in ws. Offsets (elements): fc_gru_w 0, in_proj_w 65536,
// out_proj_w 262144, att_w 327680, gru_wih 458752, gru_whh 655360, fc2_w 851968.
// ---------------------------------------------------------------------------
__global__ __launch_bounds__(256) void cvt_weights(const float* __restrict__ w0,
                                                   const float* __restrict__ w1,
                                                   const float* __restrict__ w2,
                                                   const float* __restrict__ w3,
                                                   const float* __restrict__ w4,
                                                   const float* __restrict__ w5,
                                                   const float* __restrict__ w6,
                                                   bf16_t* __restrict__ dst) {
  long e = ((long)blockIdx.x * 256 + threadIdx.x) * 4;
  const float* src; long off;
  if (e < 65536)       { src = w0; off = 0; }
  else if (e < 262144) { src = w1; off = 65536; }
  else if (e < 327680) { src = w2; off = 262144; }
  else if (e < 458752) { src = w3; off = 327680; }
  else if (e < 655360) { src = w4; off = 458752; }
  else if (e < 851968) { src = w5; off = 655360; }
  else                 { src = w6; off = 851968; }
  float4 v = *reinterpret_cast<const float4*>(src + (e - off));
  bf16_t o[4] = {(bf16_t)v.x, (bf16_t)v.y, (bf16_t)v.z, (bf16_t)v.w};
  *reinterpret_cast<uint2*>(dst + e) = *reinterpret_cast<const uint2*>(o);
}

// ---------------------------------------------------------------------------
// MEGA kernel: the whole per-sample chain in one block (sample = 64 rows).
// LDS 144K, phase-rotated:
//   A_[0,32K):   x (ph1 out)            -> Hnew (ph8 out, fc2 in)
//   B_[32,64K):  IN (ph0) -> q (ph2) -> ctx (ph5) -> Hs (ph7 stage)
//   C_[64,96K):  k (ph2) -> P 8K (ph4) -> x_att (ph6)
//   D_[96,128K): V^T (ph2) -> x_ (ph7)
//   SS[128,144K): scores f32
// Phase math is byte-identical to the r14 kernels it replaces.
// ---------------------------------------------------------------------------
__global__ __launch_bounds__(512, 2) void mega_kernel(
    const float* __restrict__ inputs, const float* __restrict__ hidden,
    const int* __restrict__ drop, const bf16_t* __restrict__ Wb,
    const float* __restrict__ b0, const float* __restrict__ Bqkv,
    const float* __restrict__ Bo, const float* __restrict__ Batt,
    const float* __restrict__ bih, const float* __restrict__ bhh,
    const float* __restrict__ bt,
    float* __restrict__ Hout, float* __restrict__ outT) {
  __shared__ __align__(16) char buf[147456];
  bf16_t* A_ = reinterpret_cast<bf16_t*>(buf);
  bf16_t* B_ = reinterpret_cast<bf16_t*>(buf + 32768);
  bf16_t* C_ = reinterpret_cast<bf16_t*>(buf + 65536);
  bf16_t* D_ = reinterpret_cast<bf16_t*>(buf + 98304);
  float*  SS = reinterpret_cast<float*>(buf + 131072);
  const int tid = threadIdx.x, lane = tid & 63, wv = tid >> 6;
  const int rl = lane & 15, kof = (lane >> 4) << 3, ro4 = (lane >> 4) << 2;
  const int b = blockIdx.x;
  const long R0 = (long)b * 64;
  const int c0 = wv * 32;

  // ph0: stage inputs -> B_
  stage_f32c(B_, inputs, R0, 512, 0, tid, 512);
  __syncthreads();

  // ph1: x = relu(IN @ fc_gru_w^T + b0) -> A_
  {
    f32x4 acc[4][2] = {};
#pragma unroll 1
    for (int kk = 0; kk < 256; kk += 32) {
      bf16x8 a[4], bb[2];
#pragma unroll
      for (int rt = 0; rt < 4; ++rt) a[rt] = lds_frag(B_, rt * 16 + rl, kk + kof, 512);
#pragma unroll
      for (int ct = 0; ct < 2; ++ct)
        bb[ct] = *reinterpret_cast<const bf16x8*>(Wb + (long)(c0 + ct * 16 + rl) * 256 + kk + kof);
#pragma unroll
      for (int rt = 0; rt < 4; ++rt)
#pragma unroll
        for (int ct = 0; ct < 2; ++ct) acc[rt][ct] = mfma16(a[rt], bb[ct], acc[rt][ct]);
    }
#pragma unroll
    for (int ct = 0; ct < 2; ++ct) {
      int c = c0 + ct * 16 + rl;
      float bv = b0[c];
#pragma unroll
      for (int rt = 0; rt < 4; ++rt)
#pragma unroll
        for (int i = 0; i < 4; ++i)
          lds_put(A_, rt * 16 + ro4 + i, c, 512, fmaxf(acc[rt][ct][i] + bv, 0.f));
    }
  }
  __syncthreads();

  // ph2: q -> B_, k -> C_, V^T -> D_ (A-operand: x in A_)
  for (int which = 0; which < 3; ++which) {
    const bf16_t* Wp = Wb + 65536 + (long)which * 65536;
    f32x4 acc[4][2] = {};
#pragma unroll 1
    for (int kk = 0; kk < 256; kk += 32) {
      bf16x8 a[4], bb[2];
#pragma unroll
      for (int rt = 0; rt < 4; ++rt) a[rt] = lds_frag(A_, rt * 16 + rl, kk + kof, 512);
#pragma unroll
      for (int ct = 0; ct < 2; ++ct)
        bb[ct] = *reinterpret_cast<const bf16x8*>(Wp + (long)(c0 + ct * 16 + rl) * 256 + kk + kof);
#pragma unroll
      for (int rt = 0; rt < 4; ++rt)
#pragma unroll
        for (int ct = 0; ct < 2; ++ct) acc[rt][ct] = mfma16(a[rt], bb[ct], acc[rt][ct]);
    }
#pragma unroll
    for (int ct = 0; ct < 2; ++ct) {
      int c = c0 + ct * 16 + rl;
      float bv = Bqkv[which * 256 + c];
#pragma unroll
      for (int rt = 0; rt < 4; ++rt)
#pragma unroll
        for (int i = 0; i < 4; ++i) {
          int r = rt * 16 + ro4 + i;
          if (which == 0)      lds_put(B_, r, c, 512, acc[rt][ct][i] + bv);
          else if (which == 1) lds_put(C_, r, c, 512, acc[rt][ct][i] + bv);
          else                 lds_put(D_, c, r, 128, acc[rt][ct][i] + bv);  // V^T[c][r]
        }
    }
  }
  __syncthreads();

  // ph3: scores = q k^T * scale, masked -> SS
  {
    const int rt0 = (wv & 3) * 16, sc0 = (wv >> 2) * 32;
    f32x4 acc[2] = {};
#pragma unroll 1
    for (int kk = 0; kk < 256; kk += 32) {
      bf16x8 a = lds_frag(B_, rt0 + rl, kk + kof, 512);
#pragma unroll
      for (int ct = 0; ct < 2; ++ct) {
        bf16x8 bb = lds_frag(C_, sc0 + ct * 16 + rl, kk + kof, 512);
        acc[ct] = mfma16(a, bb, acc[ct]);
      }
    }
#pragma unroll
    for (int ct = 0; ct < 2; ++ct)
#pragma unroll
      for (int i = 0; i < 4; ++i) {
        int rr = rt0 + ro4 + i, cc = sc0 + ct * 16 + rl;
        float s = acc[ct][i] * 0.0625f;
        if (drop[(long)b * 4096 + rr * 64 + cc]) s = -1e9f;
        SS[rr * 64 + cc] = s;
      }
  }
  __syncthreads();

  // ph4: softmax -> P (bf16) over C_ (k dead)
  for (int j = 0; j < 8; ++j) {
    int rr = wv * 8 + j;
    float s = SS[rr * 64 + lane];
    float m = s;
#pragma unroll
    for (int off = 32; off >= 1; off >>= 1) m = fmaxf(m, __shfl_xor(m, off));
    float e = __expf(s - m);
    float sum = e;
#pragma unroll
    for (int off = 32; off >= 1; off >>= 1) sum += __shfl_xor(sum, off);
    lds_put(C_, rr, lane, 128, e / sum);
  }
  __syncthreads();

  // ph5: ctx = P @ V -> B_ (q dead)
  {
    f32x4 acc[4][2] = {};
#pragma unroll
    for (int kk = 0; kk < 64; kk += 32) {
      bf16x8 a[4], bb[2];
#pragma unroll
      for (int rt = 0; rt < 4; ++rt) a[rt] = lds_frag(C_, rt * 16 + rl, kk + kof, 128);
#pragma unroll
      for (int ct = 0; ct < 2; ++ct) bb[ct] = lds_frag(D_, c0 + ct * 16 + rl, kk + kof, 128);
#pragma unroll
      for (int rt = 0; rt < 4; ++rt)
#pragma unroll
        for (int ct = 0; ct < 2; ++ct) acc[rt][ct] = mfma16(a[rt], bb[ct], acc[rt][ct]);
    }
#pragma unroll
    for (int ct = 0; ct < 2; ++ct)
#pragma unroll
      for (int rt = 0; rt < 4; ++rt)
#pragma unroll
        for (int i = 0; i < 4; ++i)
          lds_put(B_, rt * 16 + ro4 + i, c0 + ct * 16 + rl, 512, acc[rt][ct][i]);
  }
  __syncthreads();

  // ph6: x_att = ctx @ Wo^T + Bo -> C_ (P dead)
  {
    const bf16_t* Wo = Wb + 262144;
    f32x4 acc[4][2] = {};
#pragma unroll 1
    for (int kk = 0; kk < 256; kk += 32) {
      bf16x8 a[4], bb[2];
#pragma unroll
      for (int rt = 0; rt < 4; ++rt) a[rt] = lds_frag(B_, rt * 16 + rl, kk + kof, 512);
#pragma unroll
      for (int ct = 0; ct < 2; ++ct)
        bb[ct] = *reinterpret_cast<const bf16x8*>(Wo + (long)(c0 + ct * 16 + rl) * 256 + kk + kof);
#pragma unroll
      for (int rt = 0; rt < 4; ++rt)
#pragma unroll
        for (int ct = 0; ct < 2; ++ct) acc[rt][ct] = mfma16(a[rt], bb[ct], acc[rt][ct]);
    }
    __syncthreads();  // ctx reads done before x_att overwrites C_? (C_ != B_; this
                      // barrier actually guards nothing critical but keeps phase order)
#pragma unroll
    for (int ct = 0; ct < 2; ++ct) {
      int c = c0 + ct * 16 + rl;
      float bv = Bo[c];
#pragma unroll
      for (int rt = 0; rt < 4; ++rt)
#pragma unroll
        for (int i = 0; i < 4; ++i)
          lds_put(C_, rt * 16 + ro4 + i, c, 512, acc[rt][ct][i] + bv);
    }
  }
  __syncthreads();

  // ph7: stage hidden -> B_ (ctx dead); x_ = relu([x|x_att] @ att_w^T + Batt) -> D_
  stage_f32c(B_, hidden, R0, 512, 0, tid, 512);
  {
    const bf16_t* Wa = Wb + 327680;
    f32x4 acc[4][2] = {};
#pragma unroll 1
    for (int kk = 0; kk < 512; kk += 32) {
      bf16x8 a[4], bb[2];
#pragma unroll
      for (int rt = 0; rt < 4; ++rt)
        a[rt] = (kk < 256) ? lds_frag(A_, rt * 16 + rl, kk + kof, 512)
                           : lds_frag(C_, rt * 16 + rl, kk - 256 + kof, 512);
#pragma unroll
      for (int ct = 0; ct < 2; ++ct)
        bb[ct] = *reinterpret_cast<const bf16x8*>(Wa + (long)(c0 + ct * 16 + rl) * 512 + kk + kof);
#pragma unroll
      for (int rt = 0; rt < 4; ++rt)
#pragma unroll
        for (int ct = 0; ct < 2; ++ct) acc[rt][ct] = mfma16(a[rt], bb[ct], acc[rt][ct]);
    }
#pragma unroll
    for (int ct = 0; ct < 2; ++ct) {
      int c = c0 + ct * 16 + rl;
      float bv = Batt[c];
#pragma unroll
      for (int rt = 0; rt < 4; ++rt)
#pragma unroll
        for (int i = 0; i < 4; ++i)
          lds_put(D_, rt * 16 + ro4 + i, c, 512, fmaxf(acc[rt][ct][i] + bv, 0.f));
    }
  }
  __syncthreads();

  // ph8: GRU (x_ in D_, h_in in B_) -> h to Hout + Hnew in A_ (x dead)
  const bf16_t* Wih = Wb + 458752;
  const bf16_t* Whh = Wb + 655360;
#pragma unroll 1
  for (int p = 0; p < 2; ++p) {
    const int cg = p * 128 + wv * 16;
    f32x4 aRZ[2][4] = {}, aIN[4] = {}, aHN[4] = {};
#pragma unroll 1
    for (int kk = 0; kk < 256; kk += 32) {
      bf16x8 ax[4], bI[3];
#pragma unroll
      for (int rt = 0; rt < 4; ++rt) ax[rt] = lds_frag(D_, rt * 16 + rl, kk + kof, 512);
#pragma unroll
      for (int g = 0; g < 3; ++g)
        bI[g] = *reinterpret_cast<const bf16x8*>(Wih + (long)(g * 256 + cg + rl) * 256 + kk + kof);
#pragma unroll
      for (int rt = 0; rt < 4; ++rt) {
        aRZ[0][rt] = mfma16(ax[rt], bI[0], aRZ[0][rt]);
        aRZ[1][rt] = mfma16(ax[rt], bI[1], aRZ[1][rt]);
        aIN[rt]    = mfma16(ax[rt], bI[2], aIN[rt]);
      }
    }
#pragma unroll 1
    for (int kk = 0; kk < 256; kk += 32) {
      bf16x8 ah_[4], bH[3];
#pragma unroll
      for (int rt = 0; rt < 4; ++rt) ah_[rt] = lds_frag(B_, rt * 16 + rl, kk + kof, 512);
#pragma unroll
      for (int g = 0; g < 3; ++g)
        bH[g] = *reinterpret_cast<const bf16x8*>(Whh + (long)(g * 256 + cg + rl) * 256 + kk + kof);
#pragma unroll
      for (int rt = 0; rt < 4; ++rt) {
        aRZ[0][rt] = mfma16(ah_[rt], bH[0], aRZ[0][rt]);
        aRZ[1][rt] = mfma16(ah_[rt], bH[1], aRZ[1][rt]);
        aHN[rt]    = mfma16(ah_[rt], bH[2], aHN[rt]);
      }
    }
    const int c = cg + rl;
    float br  = bih[c] + bhh[c];
    float bz  = bih[256 + c] + bhh[256 + c];
    float bin_ = bih[512 + c], bhn = bhh[512 + c];
#pragma unroll
    for (int rt = 0; rt < 4; ++rt)
#pragma unroll
      for (int i = 0; i < 4; ++i) {
        int rloc = rt * 16 + ro4 + i;
        float rg = 1.f / (1.f + __expf(-(aRZ[0][rt][i] + br)));
        float zg = 1.f / (1.f + __expf(-(aRZ[1][rt][i] + bz)));
        float nx = aIN[rt][i] + bin_ + rg * (aHN[rt][i] + bhn);
        float ng = 1.f - 2.f / (__expf(2.f * nx) + 1.f);  // tanh, saturation-safe
        float hv = lds_get1(B_, rloc, c, 512);
        float h = (1.f - zg) * ng + zg * hv;
        Hout[(R0 + rloc) * 256 + c] = h;
        lds_put(A_, rloc, c, 512, h);
      }
  }
  __syncthreads();

  // ph9: tactic_q = Hnew @ fc2_w^T + bt (waves 0-3)
  if (wv < 4) {
    const bf16_t* Wt = Wb + 851968;
    f32x4 acc = {};
#pragma unroll 1
    for (int kk = 0; kk < 256; kk += 32) {
      bf16x8 a = lds_frag(A_, wv * 16 + rl, kk + kof, 512);
      bf16x8 bb = *reinterpret_cast<const bf16x8*>(Wt + (long)rl * 256 + kk + kof);
      acc = mfma16(a, bb, acc);
    }
    float bv = bt[rl];
#pragma unroll
    for (int i = 0; i < 4; ++i) outT[(R0 + wv * 16 + ro4 + i) * 16 + rl] = acc[i] + bv;
  }
}

// int32 bool -> f32 {0,1} copy, 4 elems/thread
__global__ __launch_bounds__(256) void drop_copy(const int* __restrict__ d,
                                                 float* __restrict__ o) {
  long i = (long)blockIdx.x * 256 + threadIdx.x;
  int4 v = reinterpret_cast<const int4*>(d)[i];
  float4 r;
  r.x = v.x ? 1.f : 0.f;
  r.y = v.y ? 1.f : 0.f;
  r.z = v.z ? 1.f : 0.f;
  r.w = v.w ? 1.f : 0.f;
  reinterpret_cast<float4*>(o)[i] = r;
}

extern "C" void kernel_launch(void* const* d_in, const int* in_sizes, int n_in,
                              void* d_out, int out_size, void* d_ws, size_t ws_size,
                              hipStream_t stream) {
  (void)in_sizes; (void)n_in; (void)out_size; (void)ws_size;
  const float* inputs      = (const float*)d_in[0];
  const float* hidden      = (const float*)d_in[1];
  const int*   drp         = (const int*)d_in[2];   // bool pushed as int32
  // d_in[3] = t (unused)
  const float* fc_gru_w    = (const float*)d_in[4];
  const float* fc_gru_b    = (const float*)d_in[5];
  const float* in_proj_w   = (const float*)d_in[6];
  const float* in_proj_b   = (const float*)d_in[7];
  const float* out_proj_w  = (const float*)d_in[8];
  const float* out_proj_b  = (const float*)d_in[9];
  const float* att_w       = (const float*)d_in[10];
  const float* att_b       = (const float*)d_in[11];
  const float* gru_wih     = (const float*)d_in[12];
  const float* gru_whh     = (const float*)d_in[13];
  const float* gru_bih     = (const float*)d_in[14];
  const float* gru_bhh     = (const float*)d_in[15];
  const float* fc2_w       = (const float*)d_in[16];
  const float* fc2_b       = (const float*)d_in[17];

  float* out_t = (float*)d_out;          // [M,16]
  float* out_h = out_t + MTOT * 16;      // [M,256] f32 h
  float* out_d = out_h + MTOT * 256;     // [B*64*64] f32

  bf16_t* Wb = (bf16_t*)d_ws;            // bf16 weights (1.7 MB) — only ws use

  // 0) weights f32 -> bf16
  cvt_weights<<<836, 256, 0, stream>>>(fc_gru_w, in_proj_w, out_proj_w, att_w,
                                       gru_wih, gru_whh, fc2_w, Wb);
  // 1) whole per-sample chain fused; h -> out_h, tactic_q -> out_t
  mega_kernel<<<2048, 512, 0, stream>>>(inputs, hidden, drp, Wb,
                                        fc_gru_b, in_proj_b, out_proj_b, att_b,
                                        gru_bih, gru_bhh, fc2_b, out_h, out_t);
  // 2) drop mask echo as f32
  drop_copy<<<8192, 256, 0, stream>>>(drp, out_d);
}

// Round 16
// 587.104 us; speedup vs baseline: 3.1477x; 1.0752x over previous
//
#include <hip/hip_runtime.h>

typedef __bf16 bf16_t;
using bf16x8 = __bf16 __attribute__((ext_vector_type(8)));
using f32x4  = float __attribute__((ext_vector_type(4)));

// B=2048, N=64, D=256, H=256, T=16
static constexpr long MTOT = 131072;   // B*N

__device__ __forceinline__ f32x4 mfma16(bf16x8 a, bf16x8 b, f32x4 c) {
  return __builtin_amdgcn_mfma_f32_16x16x32_bf16(a, b, c, 0, 0, 0);
}

// Swizzled LDS tiles: element (row,k) at byte row*rowBytes + ((k*2) ^ ((row&7)<<4)).
__device__ __forceinline__ bf16x8 lds_frag(const bf16_t* base, int row, int k, int rowBytes) {
  int byte = row * rowBytes + ((k << 1) ^ ((row & 7) << 4));
  return *reinterpret_cast<const bf16x8*>(reinterpret_cast<const char*>(base) + byte);
}
__device__ __forceinline__ float lds_get1(const bf16_t* base, int row, int col, int rowBytes) {
  int byte = row * rowBytes + ((col << 1) ^ ((row & 7) << 4));
  return (float)*reinterpret_cast<const bf16_t*>(reinterpret_cast<const char*>(base) + byte);
}
__device__ __forceinline__ void lds_put(bf16_t* base, int row, int col, int rowBytes, float v) {
  int byte = row * rowBytes + ((col << 1) ^ ((row & 7) << 4));
  *reinterpret_cast<bf16_t*>(reinterpret_cast<char*>(base) + byte) = (bf16_t)v;
}

// Stage a [64 x 256] f32 tile -> single bf16 swizzled LDS.
__device__ __forceinline__ void stage_f32c(bf16_t* lds, const float* src, long row0,
                                           int rowBytesLds, int colOffBytes,
                                           int tid, int nthr) {
  for (int e = tid * 4; e < 64 * 256; e += nthr * 4) {
    int r = e >> 8, c = e & 255;
    float4 v = *reinterpret_cast<const float4*>(src + (row0 + r) * 256 + c);
    bf16_t t4[4] = {(bf16_t)v.x, (bf16_t)v.y, (bf16_t)v.z, (bf16_t)v.w};
    int db = r * rowBytesLds + (((c << 1) + colOffBytes) ^ ((r & 7) << 4));
    *reinterpret_cast<uint2*>(reinterpret_cast<char*>(lds) + db) =
        *reinterpret_cast<const uint2*>(t4);
  }
}

// ---------------------------------------------------------------------------
// Weights f32 -> bf16 in ws. Offsets (elements): fc_gru_w 0, in_proj_w 65536,
// out_proj_w 262144, att_w 327680, gru_wih 458752, gru_whh 655360, fc2_w 851968.
// ---------------------------------------------------------------------------
__global__ __launch_bounds__(256) void cvt_weights(const float* __restrict__ w0,
                                                   const float* __restrict__ w1,
                                                   const float* __restrict__ w2,
                                                   const float* __restrict__ w3,
                                                   const float* __restrict__ w4,
                                                   const float* __restrict__ w5,
                                                   const float* __restrict__ w6,
                                                   bf16_t* __restrict__ dst) {
  long e = ((long)blockIdx.x * 256 + threadIdx.x) * 4;
  const float* src; long off;
  if (e < 65536)       { src = w0; off = 0; }
  else if (e < 262144) { src = w1; off = 65536; }
  else if (e < 327680) { src = w2; off = 262144; }
  else if (e < 458752) { src = w3; off = 327680; }
  else if (e < 655360) { src = w4; off = 458752; }
  else if (e < 851968) { src = w5; off = 655360; }
  else                 { src = w6; off = 851968; }
  float4 v = *reinterpret_cast<const float4*>(src + (e - off));
  bf16_t o[4] = {(bf16_t)v.x, (bf16_t)v.y, (bf16_t)v.z, (bf16_t)v.w};
  *reinterpret_cast<uint2*>(dst + e) = *reinterpret_cast<const uint2*>(o);
}

// ---------------------------------------------------------------------------
// MEGA kernel, 1024 threads (16 waves -> 4 waves/SIMD for latency hiding).
// Block = one sample (64 rows). Same phase math as r15 (bit-identical),
// work split 16 waves x 16 cols. SS padded to stride 65 (bank-conflict fix).
// LDS: A_[0,32K) x->Hnew | B_[32,64K) IN->q->ctx->h | C_[64,96K) k->P->x_att
//      | D_[96,128K) V^T->x_ | SS[128K,+16.6K) scores f32 stride 65.
// ---------------------------------------------------------------------------
__global__ __launch_bounds__(1024) void mega_kernel(
    const float* __restrict__ inputs, const float* __restrict__ hidden,
    const int* __restrict__ drop, const bf16_t* __restrict__ Wb,
    const float* __restrict__ b0, const float* __restrict__ Bqkv,
    const float* __restrict__ Bo, const float* __restrict__ Batt,
    const float* __restrict__ bih, const float* __restrict__ bhh,
    const float* __restrict__ bt,
    float* __restrict__ Hout, float* __restrict__ outT) {
  __shared__ __align__(16) char buf[147712];
  bf16_t* A_ = reinterpret_cast<bf16_t*>(buf);
  bf16_t* B_ = reinterpret_cast<bf16_t*>(buf + 32768);
  bf16_t* C_ = reinterpret_cast<bf16_t*>(buf + 65536);
  bf16_t* D_ = reinterpret_cast<bf16_t*>(buf + 98304);
  float*  SS = reinterpret_cast<float*>(buf + 131072);   // [64][65]
  const int tid = threadIdx.x, lane = tid & 63, wv = tid >> 6;  // wv 0..15
  const int rl = lane & 15, kof = (lane >> 4) << 3, ro4 = (lane >> 4) << 2;
  const int b = blockIdx.x;
  const long R0 = (long)b * 64;
  const int c0 = wv * 16;   // 16-col strip per wave

  // ph0: stage inputs -> B_
  stage_f32c(B_, inputs, R0, 512, 0, tid, 1024);
  __syncthreads();

  // ph1: x = relu(IN @ fc_gru_w^T + b0) -> A_
  {
    f32x4 acc[4] = {};
#pragma unroll 1
    for (int kk = 0; kk < 256; kk += 32) {
      bf16x8 a[4];
#pragma unroll
      for (int rt = 0; rt < 4; ++rt) a[rt] = lds_frag(B_, rt * 16 + rl, kk + kof, 512);
      bf16x8 bb = *reinterpret_cast<const bf16x8*>(Wb + (long)(c0 + rl) * 256 + kk + kof);
#pragma unroll
      for (int rt = 0; rt < 4; ++rt) acc[rt] = mfma16(a[rt], bb, acc[rt]);
    }
    int c = c0 + rl;
    float bv = b0[c];
#pragma unroll
    for (int rt = 0; rt < 4; ++rt)
#pragma unroll
      for (int i = 0; i < 4; ++i)
        lds_put(A_, rt * 16 + ro4 + i, c, 512, fmaxf(acc[rt][i] + bv, 0.f));
  }
  __syncthreads();

  // ph2: q -> B_, k -> C_, V^T -> D_
  for (int which = 0; which < 3; ++which) {
    const bf16_t* Wp = Wb + 65536 + (long)which * 65536;
    f32x4 acc[4] = {};
#pragma unroll 1
    for (int kk = 0; kk < 256; kk += 32) {
      bf16x8 a[4];
#pragma unroll
      for (int rt = 0; rt < 4; ++rt) a[rt] = lds_frag(A_, rt * 16 + rl, kk + kof, 512);
      bf16x8 bb = *reinterpret_cast<const bf16x8*>(Wp + (long)(c0 + rl) * 256 + kk + kof);
#pragma unroll
      for (int rt = 0; rt < 4; ++rt) acc[rt] = mfma16(a[rt], bb, acc[rt]);
    }
    int c = c0 + rl;
    float bv = Bqkv[which * 256 + c];
#pragma unroll
    for (int rt = 0; rt < 4; ++rt)
#pragma unroll
      for (int i = 0; i < 4; ++i) {
        int r = rt * 16 + ro4 + i;
        if (which == 0)      lds_put(B_, r, c, 512, acc[rt][i] + bv);
        else if (which == 1) lds_put(C_, r, c, 512, acc[rt][i] + bv);
        else                 lds_put(D_, c, r, 128, acc[rt][i] + bv);  // V^T[c][r]
      }
  }
  __syncthreads();

  // ph3: scores = q k^T * scale, masked -> SS (stride 65)
  {
    const int rt0 = (wv & 3) * 16, sc0 = (wv >> 2) * 16;
    f32x4 acc = {};
#pragma unroll 1
    for (int kk = 0; kk < 256; kk += 32) {
      bf16x8 a = lds_frag(B_, rt0 + rl, kk + kof, 512);
      bf16x8 bb = lds_frag(C_, sc0 + rl, kk + kof, 512);
      acc = mfma16(a, bb, acc);
    }
#pragma unroll
    for (int i = 0; i < 4; ++i) {
      int rr = rt0 + ro4 + i, cc = sc0 + rl;
      float s = acc[i] * 0.0625f;
      if (drop[(long)b * 4096 + rr * 64 + cc]) s = -1e9f;
      SS[rr * 65 + cc] = s;
    }
  }
  __syncthreads();

  // ph4: softmax -> P (bf16) over C_ (k dead)
#pragma unroll
  for (int j = 0; j < 4; ++j) {
    int rr = wv * 4 + j;
    float s = SS[rr * 65 + lane];
    float m = s;
#pragma unroll
    for (int off = 32; off >= 1; off >>= 1) m = fmaxf(m, __shfl_xor(m, off));
    float e = __expf(s - m);
    float sum = e;
#pragma unroll
    for (int off = 32; off >= 1; off >>= 1) sum += __shfl_xor(sum, off);
    lds_put(C_, rr, lane, 128, e / sum);
  }
  __syncthreads();

  // ph5: ctx = P @ V -> B_ (q dead)
  {
    f32x4 acc[4] = {};
#pragma unroll
    for (int kk = 0; kk < 64; kk += 32) {
      bf16x8 a[4];
#pragma unroll
      for (int rt = 0; rt < 4; ++rt) a[rt] = lds_frag(C_, rt * 16 + rl, kk + kof, 128);
      bf16x8 bb = lds_frag(D_, c0 + rl, kk + kof, 128);
#pragma unroll
      for (int rt = 0; rt < 4; ++rt) acc[rt] = mfma16(a[rt], bb, acc[rt]);
    }
    __syncthreads();  // all P reads complete before x_att overwrites C_
#pragma unroll
    for (int rt = 0; rt < 4; ++rt)
#pragma unroll
      for (int i = 0; i < 4; ++i)
        lds_put(B_, rt * 16 + ro4 + i, c0 + rl, 512, acc[rt][i]);
  }
  __syncthreads();

  // ph6: x_att = ctx @ Wo^T + Bo -> C_
  {
    const bf16_t* Wo = Wb + 262144;
    f32x4 acc[4] = {};
#pragma unroll 1
    for (int kk = 0; kk < 256; kk += 32) {
      bf16x8 a[4];
#pragma unroll
      for (int rt = 0; rt < 4; ++rt) a[rt] = lds_frag(B_, rt * 16 + rl, kk + kof, 512);
      bf16x8 bb = *reinterpret_cast<const bf16x8*>(Wo + (long)(c0 + rl) * 256 + kk + kof);
#pragma unroll
      for (int rt = 0; rt < 4; ++rt) acc[rt] = mfma16(a[rt], bb, acc[rt]);
    }
    int c = c0 + rl;
    float bv = Bo[c];
#pragma unroll
    for (int rt = 0; rt < 4; ++rt)
#pragma unroll
      for (int i = 0; i < 4; ++i)
        lds_put(C_, rt * 16 + ro4 + i, c, 512, acc[rt][i] + bv);
  }
  __syncthreads();

  // ph7: stage hidden -> B_ (ctx dead); x_ = relu([x|x_att] @ att_w^T + Batt) -> D_
  stage_f32c(B_, hidden, R0, 512, 0, tid, 1024);
  {
    const bf16_t* Wa = Wb + 327680;
    f32x4 acc[4] = {};
#pragma unroll 1
    for (int kk = 0; kk < 512; kk += 32) {
      bf16x8 a[4];
#pragma unroll
      for (int rt = 0; rt < 4; ++rt)
        a[rt] = (kk < 256) ? lds_frag(A_, rt * 16 + rl, kk + kof, 512)
                           : lds_frag(C_, rt * 16 + rl, kk - 256 + kof, 512);
      bf16x8 bb = *reinterpret_cast<const bf16x8*>(Wa + (long)(c0 + rl) * 512 + kk + kof);
#pragma unroll
      for (int rt = 0; rt < 4; ++rt) acc[rt] = mfma16(a[rt], bb, acc[rt]);
    }
    int c = c0 + rl;
    float bv = Batt[c];
#pragma unroll
    for (int rt = 0; rt < 4; ++rt)
#pragma unroll
      for (int i = 0; i < 4; ++i)
        lds_put(D_, rt * 16 + ro4 + i, c, 512, fmaxf(acc[rt][i] + bv, 0.f));
  }
  __syncthreads();

  // ph8: GRU (x_ in D_, h_in in B_) -> h to Hout + Hnew in A_ (x dead)
  {
    const bf16_t* Wih = Wb + 458752;
    const bf16_t* Whh = Wb + 655360;
    const int cg = c0;  // 16 waves x 16 cols = 256 cols in one pass
    f32x4 aRZ[2][4] = {}, aIN[4] = {}, aHN[4] = {};
#pragma unroll 1
    for (int kk = 0; kk < 256; kk += 32) {
      bf16x8 ax[4], bI[3];
#pragma unroll
      for (int rt = 0; rt < 4; ++rt) ax[rt] = lds_frag(D_, rt * 16 + rl, kk + kof, 512);
#pragma unroll
      for (int g = 0; g < 3; ++g)
        bI[g] = *reinterpret_cast<const bf16x8*>(Wih + (long)(g * 256 + cg + rl) * 256 + kk + kof);
#pragma unroll
      for (int rt = 0; rt < 4; ++rt) {
        aRZ[0][rt] = mfma16(ax[rt], bI[0], aRZ[0][rt]);
        aRZ[1][rt] = mfma16(ax[rt], bI[1], aRZ[1][rt]);
        aIN[rt]    = mfma16(ax[rt], bI[2], aIN[rt]);
      }
    }
#pragma unroll 1
    for (int kk = 0; kk < 256; kk += 32) {
      bf16x8 ah_[4], bH[3];
#pragma unroll
      for (int rt = 0; rt < 4; ++rt) ah_[rt] = lds_frag(B_, rt * 16 + rl, kk + kof, 512);
#pragma unroll
      for (int g = 0; g < 3; ++g)
        bH[g] = *reinterpret_cast<const bf16x8*>(Whh + (long)(g * 256 + cg + rl) * 256 + kk + kof);
#pragma unroll
      for (int rt = 0; rt < 4; ++rt) {
        aRZ[0][rt] = mfma16(ah_[rt], bH[0], aRZ[0][rt]);
        aRZ[1][rt] = mfma16(ah_[rt], bH[1], aRZ[1][rt]);
        aHN[rt]    = mfma16(ah_[rt], bH[2], aHN[rt]);
      }
    }
    const int c = cg + rl;
    float br  = bih[c] + bhh[c];
    float bz  = bih[256 + c] + bhh[256 + c];
    float bin_ = bih[512 + c], bhn = bhh[512 + c];
#pragma unroll
    for (int rt = 0; rt < 4; ++rt)
#pragma unroll
      for (int i = 0; i < 4; ++i) {
        int rloc = rt * 16 + ro4 + i;
        float rg = 1.f / (1.f + __expf(-(aRZ[0][rt][i] + br)));
        float zg = 1.f / (1.f + __expf(-(aRZ[1][rt][i] + bz)));
        float nx = aIN[rt][i] + bin_ + rg * (aHN[rt][i] + bhn);
        float ng = 1.f - 2.f / (__expf(2.f * nx) + 1.f);  // tanh, saturation-safe
        float hv = lds_get1(B_, rloc, c, 512);
        float h = (1.f - zg) * ng + zg * hv;
        Hout[(R0 + rloc) * 256 + c] = h;
        lds_put(A_, rloc, c, 512, h);
      }
  }
  __syncthreads();

  // ph9: tactic_q = Hnew @ fc2_w^T + bt (waves 0-3)
  if (wv < 4) {
    const bf16_t* Wt = Wb + 851968;
    f32x4 acc = {};
#pragma unroll 1
    for (int kk = 0; kk < 256; kk += 32) {
      bf16x8 a = lds_frag(A_, wv * 16 + rl, kk + kof, 512);
      bf16x8 bb = *reinterpret_cast<const bf16x8*>(Wt + (long)rl * 256 + kk + kof);
      acc = mfma16(a, bb, acc);
    }
    float bv = bt[rl];
#pragma unroll
    for (int i = 0; i < 4; ++i) outT[(R0 + wv * 16 + ro4 + i) * 16 + rl] = acc[i] + bv;
  }
}

// int32 bool -> f32 {0,1} copy, 4 elems/thread
__global__ __launch_bounds__(256) void drop_copy(const int* __restrict__ d,
                                                 float* __restrict__ o) {
  long i = (long)blockIdx.x * 256 + threadIdx.x;
  int4 v = reinterpret_cast<const int4*>(d)[i];
  float4 r;
  r.x = v.x ? 1.f : 0.f;
  r.y = v.y ? 1.f : 0.f;
  r.z = v.z ? 1.f : 0.f;
  r.w = v.w ? 1.f : 0.f;
  reinterpret_cast<float4*>(o)[i] = r;
}

extern "C" void kernel_launch(void* const* d_in, const int* in_sizes, int n_in,
                              void* d_out, int out_size, void* d_ws, size_t ws_size,
                              hipStream_t stream) {
  (void)in_sizes; (void)n_in; (void)out_size; (void)ws_size;
  const float* inputs      = (const float*)d_in[0];
  const float* hidden      = (const float*)d_in[1];
  const int*   drp         = (const int*)d_in[2];   // bool pushed as int32
  // d_in[3] = t (unused)
  const float* fc_gru_w    = (const float*)d_in[4];
  const float* fc_gru_b    = (const float*)d_in[5];
  const float* in_proj_w   = (const float*)d_in[6];
  const float* in_proj_b   = (const float*)d_in[7];
  const float* out_proj_w  = (const float*)d_in[8];
  const float* out_proj_b  = (const float*)d_in[9];
  const float* att_w       = (const float*)d_in[10];
  const float* att_b       = (const float*)d_in[11];
  const float* gru_wih     = (const float*)d_in[12];
  const float* gru_whh     = (const float*)d_in[13];
  const float* gru_bih     = (const float*)d_in[14];
  const float* gru_bhh     = (const float*)d_in[15];
  const float* fc2_w       = (const float*)d_in[16];
  const float* fc2_b       = (const float*)d_in[17];

  float* out_t = (float*)d_out;          // [M,16]
  float* out_h = out_t + MTOT * 16;      // [M,256] f32 h
  float* out_d = out_h + MTOT * 256;     // [B*64*64] f32

  bf16_t* Wb = (bf16_t*)d_ws;            // bf16 weights (1.7 MB) — only ws use

  // 0) weights f32 -> bf16
  cvt_weights<<<836, 256, 0, stream>>>(fc_gru_w, in_proj_w, out_proj_w, att_w,
                                       gru_wih, gru_whh, fc2_w, Wb);
  // 1) whole per-sample chain fused; h -> out_h, tactic_q -> out_t
  mega_kernel<<<2048, 1024, 0, stream>>>(inputs, hidden, drp, Wb,
                                         fc_gru_b, in_proj_b, out_proj_b, att_b,
                                         gru_bih, gru_bhh, fc2_b, out_h, out_t);
  // 2) drop mask echo as f32
  drop_copy<<<8192, 256, 0, stream>>>(drp, out_d);
}

// Round 17
// 571.353 us; speedup vs baseline: 3.2345x; 1.0276x over previous
//
#include <hip/hip_runtime.h>

typedef __bf16 bf16_t;
using bf16x8 = __bf16 __attribute__((ext_vector_type(8)));
using f32x4  = float __attribute__((ext_vector_type(4)));

// B=2048, N=64, D=256, H=256, T=16
static constexpr long MTOT = 131072;   // B*N

__device__ __forceinline__ f32x4 mfma16(bf16x8 a, bf16x8 b, f32x4 c) {
  return __builtin_amdgcn_mfma_f32_16x16x32_bf16(a, b, c, 0, 0, 0);
}

// Swizzled LDS tiles: element (row,k) at byte row*rowBytes + ((k*2) ^ ((row&7)<<4)).
__device__ __forceinline__ bf16x8 lds_frag(const bf16_t* base, int row, int k, int rowBytes) {
  int byte = row * rowBytes + ((k << 1) ^ ((row & 7) << 4));
  return *reinterpret_cast<const bf16x8*>(reinterpret_cast<const char*>(base) + byte);
}
__device__ __forceinline__ float lds_get1(const bf16_t* base, int row, int col, int rowBytes) {
  int byte = row * rowBytes + ((col << 1) ^ ((row & 7) << 4));
  return (float)*reinterpret_cast<const bf16_t*>(reinterpret_cast<const char*>(base) + byte);
}
__device__ __forceinline__ void lds_put(bf16_t* base, int row, int col, int rowBytes, float v) {
  int byte = row * rowBytes + ((col << 1) ^ ((row & 7) << 4));
  *reinterpret_cast<bf16_t*>(reinterpret_cast<char*>(base) + byte) = (bf16_t)v;
}

// Stage a [64 x 256] f32 tile -> single bf16 swizzled LDS.
__device__ __forceinline__ void stage_f32c(bf16_t* lds, const float* src, long row0,
                                           int rowBytesLds, int colOffBytes,
                                           int tid, int nthr) {
  for (int e = tid * 4; e < 64 * 256; e += nthr * 4) {
    int r = e >> 8, c = e & 255;
    float4 v = *reinterpret_cast<const float4*>(src + (row0 + r) * 256 + c);
    bf16_t t4[4] = {(bf16_t)v.x, (bf16_t)v.y, (bf16_t)v.z, (bf16_t)v.w};
    int db = r * rowBytesLds + (((c << 1) + colOffBytes) ^ ((r & 7) << 4));
    *reinterpret_cast<uint2*>(reinterpret_cast<char*>(lds) + db) =
        *reinterpret_cast<const uint2*>(t4);
  }
}

// ---------------------------------------------------------------------------
// Weights f32 -> bf16 in ws. Offsets (elements): fc_gru_w 0, in_proj_w 65536,
// out_proj_w 262144, att_w 327680, gru_wih 458752, gru_whh 655360, fc2_w 851968.
// ---------------------------------------------------------------------------
__global__ __launch_bounds__(256) void cvt_weights(const float* __restrict__ w0,
                                                   const float* __restrict__ w1,
                                                   const float* __restrict__ w2,
                                                   const float* __restrict__ w3,
                                                   const float* __restrict__ w4,
                                                   const float* __restrict__ w5,
                                                   const float* __restrict__ w6,
                                                   bf16_t* __restrict__ dst) {
  long e = ((long)blockIdx.x * 256 + threadIdx.x) * 4;
  const float* src; long off;
  if (e < 65536)       { src = w0; off = 0; }
  else if (e < 262144) { src = w1; off = 65536; }
  else if (e < 327680) { src = w2; off = 262144; }
  else if (e < 458752) { src = w3; off = 327680; }
  else if (e < 655360) { src = w4; off = 458752; }
  else if (e < 851968) { src = w5; off = 655360; }
  else                 { src = w6; off = 851968; }
  float4 v = *reinterpret_cast<const float4*>(src + (e - off));
  bf16_t o[4] = {(bf16_t)v.x, (bf16_t)v.y, (bf16_t)v.z, (bf16_t)v.w};
  *reinterpret_cast<uint2*>(dst + e) = *reinterpret_cast<const uint2*>(o);
}

// ---------------------------------------------------------------------------
// MEGA kernel, 1024 threads (16 waves, 4 waves/SIMD). Block = one sample.
// unroll 2 on single-acc GEMM phases (VGPR headroom 64->~96 under the 128 cap
// for 4 waves/SIMD); GRU phase stays unroll 1 (64 acc VGPRs).
// Drop-mask echo fused into ph3 (each mask element read exactly once there).
// LDS: A_[0,32K) x->Hnew | B_[32,64K) IN->q->ctx->h | C_[64,96K) k->P->x_att
//      | D_[96,128K) V^T->x_ | SS[128K,+16.6K) scores f32 stride 65.
// ---------------------------------------------------------------------------
__global__ __launch_bounds__(1024) void mega_kernel(
    const float* __restrict__ inputs, const float* __restrict__ hidden,
    const int* __restrict__ drop, const bf16_t* __restrict__ Wb,
    const float* __restrict__ b0, const float* __restrict__ Bqkv,
    const float* __restrict__ Bo, const float* __restrict__ Batt,
    const float* __restrict__ bih, const float* __restrict__ bhh,
    const float* __restrict__ bt,
    float* __restrict__ Hout, float* __restrict__ outT,
    float* __restrict__ outD) {
  __shared__ __align__(16) char buf[147968];
  bf16_t* A_ = reinterpret_cast<bf16_t*>(buf);
  bf16_t* B_ = reinterpret_cast<bf16_t*>(buf + 32768);
  bf16_t* C_ = reinterpret_cast<bf16_t*>(buf + 65536);
  bf16_t* D_ = reinterpret_cast<bf16_t*>(buf + 98304);
  float*  SS = reinterpret_cast<float*>(buf + 131072);   // [64][65]
  const int tid = threadIdx.x, lane = tid & 63, wv = tid >> 6;  // wv 0..15
  const int rl = lane & 15, kof = (lane >> 4) << 3, ro4 = (lane >> 4) << 2;
  const int b = blockIdx.x;
  const long R0 = (long)b * 64;
  const int c0 = wv * 16;   // 16-col strip per wave

  // ph0: stage inputs -> B_
  stage_f32c(B_, inputs, R0, 512, 0, tid, 1024);
  __syncthreads();

  // ph1: x = relu(IN @ fc_gru_w^T + b0) -> A_
  {
    f32x4 acc[4] = {};
#pragma unroll 2
    for (int kk = 0; kk < 256; kk += 32) {
      bf16x8 a[4];
#pragma unroll
      for (int rt = 0; rt < 4; ++rt) a[rt] = lds_frag(B_, rt * 16 + rl, kk + kof, 512);
      bf16x8 bb = *reinterpret_cast<const bf16x8*>(Wb + (long)(c0 + rl) * 256 + kk + kof);
#pragma unroll
      for (int rt = 0; rt < 4; ++rt) acc[rt] = mfma16(a[rt], bb, acc[rt]);
    }
    int c = c0 + rl;
    float bv = b0[c];
#pragma unroll
    for (int rt = 0; rt < 4; ++rt)
#pragma unroll
      for (int i = 0; i < 4; ++i)
        lds_put(A_, rt * 16 + ro4 + i, c, 512, fmaxf(acc[rt][i] + bv, 0.f));
  }
  __syncthreads();

  // ph2: q -> B_, k -> C_, V^T -> D_
  for (int which = 0; which < 3; ++which) {
    const bf16_t* Wp = Wb + 65536 + (long)which * 65536;
    f32x4 acc[4] = {};
#pragma unroll 2
    for (int kk = 0; kk < 256; kk += 32) {
      bf16x8 a[4];
#pragma unroll
      for (int rt = 0; rt < 4; ++rt) a[rt] = lds_frag(A_, rt * 16 + rl, kk + kof, 512);
      bf16x8 bb = *reinterpret_cast<const bf16x8*>(Wp + (long)(c0 + rl) * 256 + kk + kof);
#pragma unroll
      for (int rt = 0; rt < 4; ++rt) acc[rt] = mfma16(a[rt], bb, acc[rt]);
    }
    int c = c0 + rl;
    float bv = Bqkv[which * 256 + c];
#pragma unroll
    for (int rt = 0; rt < 4; ++rt)
#pragma unroll
      for (int i = 0; i < 4; ++i) {
        int r = rt * 16 + ro4 + i;
        if (which == 0)      lds_put(B_, r, c, 512, acc[rt][i] + bv);
        else if (which == 1) lds_put(C_, r, c, 512, acc[rt][i] + bv);
        else                 lds_put(D_, c, r, 128, acc[rt][i] + bv);  // V^T[c][r]
      }
  }
  __syncthreads();

  // ph3: scores = q k^T * scale, masked -> SS; also echo mask -> outD
  {
    const int rt0 = (wv & 3) * 16, sc0 = (wv >> 2) * 16;
    f32x4 acc = {};
#pragma unroll 2
    for (int kk = 0; kk < 256; kk += 32) {
      bf16x8 a = lds_frag(B_, rt0 + rl, kk + kof, 512);
      bf16x8 bb = lds_frag(C_, sc0 + rl, kk + kof, 512);
      acc = mfma16(a, bb, acc);
    }
#pragma unroll
    for (int i = 0; i < 4; ++i) {
      int rr = rt0 + ro4 + i, cc = sc0 + rl;
      int dm = drop[(long)b * 4096 + rr * 64 + cc];
      float s = acc[i] * 0.0625f;
      if (dm) s = -1e9f;
      SS[rr * 65 + cc] = s;
      outD[(long)b * 4096 + rr * 64 + cc] = dm ? 1.f : 0.f;
    }
  }
  __syncthreads();

  // ph4: softmax -> P (bf16) over C_ (k dead)
#pragma unroll
  for (int j = 0; j < 4; ++j) {
    int rr = wv * 4 + j;
    float s = SS[rr * 65 + lane];
    float m = s;
#pragma unroll
    for (int off = 32; off >= 1; off >>= 1) m = fmaxf(m, __shfl_xor(m, off));
    float e = __expf(s - m);
    float sum = e;
#pragma unroll
    for (int off = 32; off >= 1; off >>= 1) sum += __shfl_xor(sum, off);
    lds_put(C_, rr, lane, 128, e / sum);
  }
  __syncthreads();

  // ph5: ctx = P @ V -> B_ (q dead)
  {
    f32x4 acc[4] = {};
#pragma unroll
    for (int kk = 0; kk < 64; kk += 32) {
      bf16x8 a[4];
#pragma unroll
      for (int rt = 0; rt < 4; ++rt) a[rt] = lds_frag(C_, rt * 16 + rl, kk + kof, 128);
      bf16x8 bb = lds_frag(D_, c0 + rl, kk + kof, 128);
#pragma unroll
      for (int rt = 0; rt < 4; ++rt) acc[rt] = mfma16(a[rt], bb, acc[rt]);
    }
    __syncthreads();  // all P reads complete before next phases overwrite
#pragma unroll
    for (int rt = 0; rt < 4; ++rt)
#pragma unroll
      for (int i = 0; i < 4; ++i)
        lds_put(B_, rt * 16 + ro4 + i, c0 + rl, 512, acc[rt][i]);
  }
  __syncthreads();

  // ph6: x_att = ctx @ Wo^T + Bo -> C_
  {
    const bf16_t* Wo = Wb + 262144;
    f32x4 acc[4] = {};
#pragma unroll 2
    for (int kk = 0; kk < 256; kk += 32) {
      bf16x8 a[4];
#pragma unroll
      for (int rt = 0; rt < 4; ++rt) a[rt] = lds_frag(B_, rt * 16 + rl, kk + kof, 512);
      bf16x8 bb = *reinterpret_cast<const bf16x8*>(Wo + (long)(c0 + rl) * 256 + kk + kof);
#pragma unroll
      for (int rt = 0; rt < 4; ++rt) acc[rt] = mfma16(a[rt], bb, acc[rt]);
    }
    int c = c0 + rl;
    float bv = Bo[c];
#pragma unroll
    for (int rt = 0; rt < 4; ++rt)
#pragma unroll
      for (int i = 0; i < 4; ++i)
        lds_put(C_, rt * 16 + ro4 + i, c, 512, acc[rt][i] + bv);
  }
  __syncthreads();

  // ph7: stage hidden -> B_ (ctx dead); x_ = relu([x|x_att] @ att_w^T + Batt) -> D_
  stage_f32c(B_, hidden, R0, 512, 0, tid, 1024);
  {
    const bf16_t* Wa = Wb + 327680;
    f32x4 acc[4] = {};
#pragma unroll 2
    for (int kk = 0; kk < 512; kk += 32) {
      bf16x8 a[4];
#pragma unroll
      for (int rt = 0; rt < 4; ++rt)
        a[rt] = (kk < 256) ? lds_frag(A_, rt * 16 + rl, kk + kof, 512)
                           : lds_frag(C_, rt * 16 + rl, kk - 256 + kof, 512);
      bf16x8 bb = *reinterpret_cast<const bf16x8*>(Wa + (long)(c0 + rl) * 512 + kk + kof);
#pragma unroll
      for (int rt = 0; rt < 4; ++rt) acc[rt] = mfma16(a[rt], bb, acc[rt]);
    }
    int c = c0 + rl;
    float bv = Batt[c];
#pragma unroll
    for (int rt = 0; rt < 4; ++rt)
#pragma unroll
      for (int i = 0; i < 4; ++i)
        lds_put(D_, rt * 16 + ro4 + i, c, 512, fmaxf(acc[rt][i] + bv, 0.f));
  }
  __syncthreads();

  // ph8: GRU (x_ in D_, h_in in B_) -> h to Hout + Hnew in A_ (x dead)
  {
    const bf16_t* Wih = Wb + 458752;
    const bf16_t* Whh = Wb + 655360;
    const int cg = c0;  // 16 waves x 16 cols = 256 cols in one pass
    f32x4 aRZ[2][4] = {}, aIN[4] = {}, aHN[4] = {};
#pragma unroll 1
    for (int kk = 0; kk < 256; kk += 32) {
      bf16x8 ax[4], bI[3];
#pragma unroll
      for (int rt = 0; rt < 4; ++rt) ax[rt] = lds_frag(D_, rt * 16 + rl, kk + kof, 512);
#pragma unroll
      for (int g = 0; g < 3; ++g)
        bI[g] = *reinterpret_cast<const bf16x8*>(Wih + (long)(g * 256 + cg + rl) * 256 + kk + kof);
#pragma unroll
      for (int rt = 0; rt < 4; ++rt) {
        aRZ[0][rt] = mfma16(ax[rt], bI[0], aRZ[0][rt]);
        aRZ[1][rt] = mfma16(ax[rt], bI[1], aRZ[1][rt]);
        aIN[rt]    = mfma16(ax[rt], bI[2], aIN[rt]);
      }
    }
#pragma unroll 1
    for (int kk = 0; kk < 256; kk += 32) {
      bf16x8 ah_[4], bH[3];
#pragma unroll
      for (int rt = 0; rt < 4; ++rt) ah_[rt] = lds_frag(B_, rt * 16 + rl, kk + kof, 512);
#pragma unroll
      for (int g = 0; g < 3; ++g)
        bH[g] = *reinterpret_cast<const bf16x8*>(Whh + (long)(g * 256 + cg + rl) * 256 + kk + kof);
#pragma unroll
      for (int rt = 0; rt < 4; ++rt) {
        aRZ[0][rt] = mfma16(ah_[rt], bH[0], aRZ[0][rt]);
        aRZ[1][rt] = mfma16(ah_[rt], bH[1], aRZ[1][rt]);
        aHN[rt]    = mfma16(ah_[rt], bH[2], aHN[rt]);
      }
    }
    const int c = cg + rl;
    float br  = bih[c] + bhh[c];
    float bz  = bih[256 + c] + bhh[256 + c];
    float bin_ = bih[512 + c], bhn = bhh[512 + c];
#pragma unroll
    for (int rt = 0; rt < 4; ++rt)
#pragma unroll
      for (int i = 0; i < 4; ++i) {
        int rloc = rt * 16 + ro4 + i;
        float rg = 1.f / (1.f + __expf(-(aRZ[0][rt][i] + br)));
        float zg = 1.f / (1.f + __expf(-(aRZ[1][rt][i] + bz)));
        float nx = aIN[rt][i] + bin_ + rg * (aHN[rt][i] + bhn);
        float ng = 1.f - 2.f / (__expf(2.f * nx) + 1.f);  // tanh, saturation-safe
        float hv = lds_get1(B_, rloc, c, 512);
        float h = (1.f - zg) * ng + zg * hv;
        Hout[(R0 + rloc) * 256 + c] = h;
        lds_put(A_, rloc, c, 512, h);
      }
  }
  __syncthreads();

  // ph9: tactic_q = Hnew @ fc2_w^T + bt (waves 0-3)
  if (wv < 4) {
    const bf16_t* Wt = Wb + 851968;
    f32x4 acc = {};
#pragma unroll 2
    for (int kk = 0; kk < 256; kk += 32) {
      bf16x8 a = lds_frag(A_, wv * 16 + rl, kk + kof, 512);
      bf16x8 bb = *reinterpret_cast<const bf16x8*>(Wt + (long)rl * 256 + kk + kof);
      acc = mfma16(a, bb, acc);
    }
    float bv = bt[rl];
#pragma unroll
    for (int i = 0; i < 4; ++i) outT[(R0 + wv * 16 + ro4 + i) * 16 + rl] = acc[i] + bv;
  }
}

extern "C" void kernel_launch(void* const* d_in, const int* in_sizes, int n_in,
                              void* d_out, int out_size, void* d_ws, size_t ws_size,
                              hipStream_t stream) {
  (void)in_sizes; (void)n_in; (void)out_size; (void)ws_size;
  const float* inputs      = (const float*)d_in[0];
  const float* hidden      = (const float*)d_in[1];
  const int*   drp         = (const int*)d_in[2];   // bool pushed as int32
  // d_in[3] = t (unused)
  const float* fc_gru_w    = (const float*)d_in[4];
  const float* fc_gru_b    = (const float*)d_in[5];
  const float* in_proj_w   = (const float*)d_in[6];
  const float* in_proj_b   = (const float*)d_in[7];
  const float* out_proj_w  = (const float*)d_in[8];
  const float* out_proj_b  = (const float*)d_in[9];
  const float* att_w       = (const float*)d_in[10];
  const float* att_b       = (const float*)d_in[11];
  const float* gru_wih     = (const float*)d_in[12];
  const float* gru_whh     = (const float*)d_in[13];
  const float* gru_bih     = (const float*)d_in[14];
  const float* gru_bhh     = (const float*)d_in[15];
  const float* fc2_w       = (const float*)d_in[16];
  const float* fc2_b       = (const float*)d_in[17];

  float* out_t = (float*)d_out;          // [M,16]
  float* out_h = out_t + MTOT * 16;      // [M,256] f32 h
  float* out_d = out_h + MTOT * 256;     // [B*64*64] f32

  bf16_t* Wb = (bf16_t*)d_ws;            // bf16 weights (1.7 MB) — only ws use

  // 0) weights f32 -> bf16
  cvt_weights<<<836, 256, 0, stream>>>(fc_gru_w, in_proj_w, out_proj_w, att_w,
                                       gru_wih, gru_whh, fc2_w, Wb);
  // 1) whole per-sample chain fused (incl. drop echo); h -> out_h, q -> out_t
  mega_kernel<<<2048, 1024, 0, stream>>>(inputs, hidden, drp, Wb,
                                         fc_gru_b, in_proj_b, out_proj_b, att_b,
                                         gru_bih, gru_bhh, fc2_b,
                                         out_h, out_t, out_d);
}

// Round 18
// 536.800 us; speedup vs baseline: 3.4427x; 1.0644x over previous
//
#include <hip/hip_runtime.h>

typedef __bf16 bf16_t;
using bf16x8 = __bf16 __attribute__((ext_vector_type(8)));
using f32x4  = float __attribute__((ext_vector_type(4)));

// B=2048, N=64, D=256, H=256, T=16
static constexpr long MTOT = 131072;   // B*N

__device__ __forceinline__ f32x4 mfma16(bf16x8 a, bf16x8 b, f32x4 c) {
  return __builtin_amdgcn_mfma_f32_16x16x32_bf16(a, b, c, 0, 0, 0);
}

// Swizzled LDS tiles: element (row,k) at byte row*rowBytes + ((k*2) ^ ((row&7)<<4)).
__device__ __forceinline__ bf16x8 lds_frag(const bf16_t* base, int row, int k, int rowBytes) {
  int byte = row * rowBytes + ((k << 1) ^ ((row & 7) << 4));
  return *reinterpret_cast<const bf16x8*>(reinterpret_cast<const char*>(base) + byte);
}
__device__ __forceinline__ void lds_put(bf16_t* base, int row, int col, int rowBytes, float v) {
  int byte = row * rowBytes + ((col << 1) ^ ((row & 7) << 4));
  *reinterpret_cast<bf16_t*>(reinterpret_cast<char*>(base) + byte) = (bf16_t)v;
}
// Write 4 bf16 at (row, col4..col4+3); col4 multiple of 4 -> 8B contiguous
// (swizzle bits >=16 don't affect bits 0-3).
__device__ __forceinline__ void lds_put4(bf16_t* base, int row, int col4, int rowBytes,
                                         float v0, float v1, float v2, float v3) {
  bf16_t t4[4] = {(bf16_t)v0, (bf16_t)v1, (bf16_t)v2, (bf16_t)v3};
  int byte = row * rowBytes + ((col4 << 1) ^ ((row & 7) << 4));
  *reinterpret_cast<uint2*>(reinterpret_cast<char*>(base) + byte) =
      *reinterpret_cast<const uint2*>(t4);
}
// Read 4 bf16 at (row, col4..col4+3).
__device__ __forceinline__ uint2 lds_get4(const bf16_t* base, int row, int col4, int rowBytes) {
  int byte = row * rowBytes + ((col4 << 1) ^ ((row & 7) << 4));
  return *reinterpret_cast<const uint2*>(reinterpret_cast<const char*>(base) + byte);
}

// Stage a [64 x 256] f32 tile -> single bf16 swizzled LDS.
__device__ __forceinline__ void stage_f32c(bf16_t* lds, const float* src, long row0,
                                           int rowBytesLds, int colOffBytes,
                                           int tid, int nthr) {
  for (int e = tid * 4; e < 64 * 256; e += nthr * 4) {
    int r = e >> 8, c = e & 255;
    float4 v = *reinterpret_cast<const float4*>(src + (row0 + r) * 256 + c);
    bf16_t t4[4] = {(bf16_t)v.x, (bf16_t)v.y, (bf16_t)v.z, (bf16_t)v.w};
    int db = r * rowBytesLds + (((c << 1) + colOffBytes) ^ ((r & 7) << 4));
    *reinterpret_cast<uint2*>(reinterpret_cast<char*>(lds) + db) =
        *reinterpret_cast<const uint2*>(t4);
  }
}

// ---------------------------------------------------------------------------
// Weights f32 -> bf16 in ws. Offsets (elements): fc_gru_w 0, in_proj_w 65536,
// out_proj_w 262144, att_w 327680, gru_wih 458752, gru_whh 655360, fc2_w 851968.
// ---------------------------------------------------------------------------
__global__ __launch_bounds__(256) void cvt_weights(const float* __restrict__ w0,
                                                   const float* __restrict__ w1,
                                                   const float* __restrict__ w2,
                                                   const float* __restrict__ w3,
                                                   const float* __restrict__ w4,
                                                   const float* __restrict__ w5,
                                                   const float* __restrict__ w6,
                                                   bf16_t* __restrict__ dst) {
  long e = ((long)blockIdx.x * 256 + threadIdx.x) * 4;
  const float* src; long off;
  if (e < 65536)       { src = w0; off = 0; }
  else if (e < 262144) { src = w1; off = 65536; }
  else if (e < 327680) { src = w2; off = 262144; }
  else if (e < 458752) { src = w3; off = 327680; }
  else if (e < 655360) { src = w4; off = 458752; }
  else if (e < 851968) { src = w5; off = 655360; }
  else                 { src = w6; off = 851968; }
  float4 v = *reinterpret_cast<const float4*>(src + (e - off));
  bf16_t o[4] = {(bf16_t)v.x, (bf16_t)v.y, (bf16_t)v.z, (bf16_t)v.w};
  *reinterpret_cast<uint2*>(dst + e) = *reinterpret_cast<const uint2*>(o);
}

// ---------------------------------------------------------------------------
// MEGA kernel, 1024 threads (16 waves, 4 waves/SIMD). Block = one sample.
// r18 change: MFMA operand-SWAP on GEMM phases so the output fragment is
// row-major per lane (4 consecutive cols) -> epilogues become ds_write_b64 /
// float4 global stores instead of 16 scalar b16 writes (bank-conflict fix).
// V^T producer stays unswapped (its layout is already col4-contiguous).
// LDS: A_[0,32K) x->Hnew | B_[32,64K) IN->q->ctx->h | C_[64,96K) k->P->x_att
//      | D_[96,128K) V^T->x_ | SS[128K,+16.6K) scores f32 stride 65.
// ---------------------------------------------------------------------------
__global__ __launch_bounds__(1024) void mega_kernel(
    const float* __restrict__ inputs, const float* __restrict__ hidden,
    const int* __restrict__ drop, const bf16_t* __restrict__ Wb,
    const float* __restrict__ b0, const float* __restrict__ Bqkv,
    const float* __restrict__ Bo, const float* __restrict__ Batt,
    const float* __restrict__ bih, const float* __restrict__ bhh,
    const float* __restrict__ bt,
    float* __restrict__ Hout, float* __restrict__ outT,
    float* __restrict__ outD) {
  __shared__ __align__(16) char buf[147968];
  bf16_t* A_ = reinterpret_cast<bf16_t*>(buf);
  bf16_t* B_ = reinterpret_cast<bf16_t*>(buf + 32768);
  bf16_t* C_ = reinterpret_cast<bf16_t*>(buf + 65536);
  bf16_t* D_ = reinterpret_cast<bf16_t*>(buf + 98304);
  float*  SS = reinterpret_cast<float*>(buf + 131072);   // [64][65]
  const int tid = threadIdx.x, lane = tid & 63, wv = tid >> 6;  // wv 0..15
  const int rl = lane & 15, kof = (lane >> 4) << 3, ro4 = (lane >> 4) << 2;
  const int b = blockIdx.x;
  const long R0 = (long)b * 64;
  const int c0 = wv * 16;   // 16-col strip per wave

  // ph0: stage inputs -> B_
  stage_f32c(B_, inputs, R0, 512, 0, tid, 1024);
  __syncthreads();

  // ph1: x = relu(IN @ fc_gru_w^T + b0) -> A_  [swapped: lane = (row rl, cols ro4..+3)]
  {
    f32x4 acc[4] = {};
#pragma unroll 2
    for (int kk = 0; kk < 256; kk += 32) {
      bf16x8 a[4];
#pragma unroll
      for (int rt = 0; rt < 4; ++rt) a[rt] = lds_frag(B_, rt * 16 + rl, kk + kof, 512);
      bf16x8 bb = *reinterpret_cast<const bf16x8*>(Wb + (long)(c0 + rl) * 256 + kk + kof);
#pragma unroll
      for (int rt = 0; rt < 4; ++rt) acc[rt] = mfma16(bb, a[rt], acc[rt]);
    }
    float4 bv = *reinterpret_cast<const float4*>(b0 + c0 + ro4);
#pragma unroll
    for (int rt = 0; rt < 4; ++rt)
      lds_put4(A_, rt * 16 + rl, c0 + ro4, 512,
               fmaxf(acc[rt][0] + bv.x, 0.f), fmaxf(acc[rt][1] + bv.y, 0.f),
               fmaxf(acc[rt][2] + bv.z, 0.f), fmaxf(acc[rt][3] + bv.w, 0.f));
  }
  __syncthreads();

  // ph2a: q -> B_, k -> C_ [swapped]
  for (int which = 0; which < 2; ++which) {
    const bf16_t* Wp = Wb + 65536 + (long)which * 65536;
    f32x4 acc[4] = {};
#pragma unroll 2
    for (int kk = 0; kk < 256; kk += 32) {
      bf16x8 a[4];
#pragma unroll
      for (int rt = 0; rt < 4; ++rt) a[rt] = lds_frag(A_, rt * 16 + rl, kk + kof, 512);
      bf16x8 bb = *reinterpret_cast<const bf16x8*>(Wp + (long)(c0 + rl) * 256 + kk + kof);
#pragma unroll
      for (int rt = 0; rt < 4; ++rt) acc[rt] = mfma16(bb, a[rt], acc[rt]);
    }
    float4 bv = *reinterpret_cast<const float4*>(Bqkv + which * 256 + c0 + ro4);
    bf16_t* outp = which ? C_ : B_;
#pragma unroll
    for (int rt = 0; rt < 4; ++rt)
      lds_put4(outp, rt * 16 + rl, c0 + ro4, 512,
               acc[rt][0] + bv.x, acc[rt][1] + bv.y, acc[rt][2] + bv.z, acc[rt][3] + bv.w);
  }
  // ph2b: V^T -> D_ [UNswapped: lane = (col c0+rl fixed, rows ro4..+3) = V^T col4-contig]
  {
    const bf16_t* Wp = Wb + 65536 + 2L * 65536;
    f32x4 acc[4] = {};
#pragma unroll 2
    for (int kk = 0; kk < 256; kk += 32) {
      bf16x8 a[4];
#pragma unroll
      for (int rt = 0; rt < 4; ++rt) a[rt] = lds_frag(A_, rt * 16 + rl, kk + kof, 512);
      bf16x8 bb = *reinterpret_cast<const bf16x8*>(Wp + (long)(c0 + rl) * 256 + kk + kof);
#pragma unroll
      for (int rt = 0; rt < 4; ++rt) acc[rt] = mfma16(a[rt], bb, acc[rt]);
    }
    int c = c0 + rl;
    float bv = Bqkv[512 + c];
#pragma unroll
    for (int rt = 0; rt < 4; ++rt)
      lds_put4(D_, c, rt * 16 + ro4, 128,
               acc[rt][0] + bv, acc[rt][1] + bv, acc[rt][2] + bv, acc[rt][3] + bv);
  }
  __syncthreads();

  // ph3: scores = q k^T * scale, masked -> SS; also echo mask -> outD
  // [unswapped: col=lane&15 = key index; rows = query]
  {
    const int rt0 = (wv & 3) * 16, sc0 = (wv >> 2) * 16;
    f32x4 acc = {};
#pragma unroll 2
    for (int kk = 0; kk < 256; kk += 32) {
      bf16x8 a = lds_frag(B_, rt0 + rl, kk + kof, 512);
      bf16x8 bb = lds_frag(C_, sc0 + rl, kk + kof, 512);
      acc = mfma16(a, bb, acc);
    }
#pragma unroll
    for (int i = 0; i < 4; ++i) {
      int rr = rt0 + ro4 + i, cc = sc0 + rl;
      int dm = drop[(long)b * 4096 + rr * 64 + cc];
      float s = acc[i] * 0.0625f;
      if (dm) s = -1e9f;
      SS[rr * 65 + cc] = s;
      outD[(long)b * 4096 + rr * 64 + cc] = dm ? 1.f : 0.f;
    }
  }
  __syncthreads();

  // ph4: softmax -> P (bf16) over C_ (k dead)
#pragma unroll
  for (int j = 0; j < 4; ++j) {
    int rr = wv * 4 + j;
    float s = SS[rr * 65 + lane];
    float m = s;
#pragma unroll
    for (int off = 32; off >= 1; off >>= 1) m = fmaxf(m, __shfl_xor(m, off));
    float e = __expf(s - m);
    float sum = e;
#pragma unroll
    for (int off = 32; off >= 1; off >>= 1) sum += __shfl_xor(sum, off);
    lds_put(C_, rr, lane, 128, e / sum);
  }
  __syncthreads();

  // ph5: ctx = P @ V -> B_ (q dead) [swapped]
  {
    f32x4 acc[4] = {};
#pragma unroll
    for (int kk = 0; kk < 64; kk += 32) {
      bf16x8 a[4];
#pragma unroll
      for (int rt = 0; rt < 4; ++rt) a[rt] = lds_frag(C_, rt * 16 + rl, kk + kof, 128);
      bf16x8 bb = lds_frag(D_, c0 + rl, kk + kof, 128);
#pragma unroll
      for (int rt = 0; rt < 4; ++rt) acc[rt] = mfma16(bb, a[rt], acc[rt]);
    }
    __syncthreads();  // all P reads complete before overwrites
#pragma unroll
    for (int rt = 0; rt < 4; ++rt)
      lds_put4(B_, rt * 16 + rl, c0 + ro4, 512,
               acc[rt][0], acc[rt][1], acc[rt][2], acc[rt][3]);
  }
  __syncthreads();

  // ph6: x_att = ctx @ Wo^T + Bo -> C_ [swapped]
  {
    const bf16_t* Wo = Wb + 262144;
    f32x4 acc[4] = {};
#pragma unroll 2
    for (int kk = 0; kk < 256; kk += 32) {
      bf16x8 a[4];
#pragma unroll
      for (int rt = 0; rt < 4; ++rt) a[rt] = lds_frag(B_, rt * 16 + rl, kk + kof, 512);
      bf16x8 bb = *reinterpret_cast<const bf16x8*>(Wo + (long)(c0 + rl) * 256 + kk + kof);
#pragma unroll
      for (int rt = 0; rt < 4; ++rt) acc[rt] = mfma16(bb, a[rt], acc[rt]);
    }
    float4 bv = *reinterpret_cast<const float4*>(Bo + c0 + ro4);
#pragma unroll
    for (int rt = 0; rt < 4; ++rt)
      lds_put4(C_, rt * 16 + rl, c0 + ro4, 512,
               acc[rt][0] + bv.x, acc[rt][1] + bv.y, acc[rt][2] + bv.z, acc[rt][3] + bv.w);
  }
  __syncthreads();

  // ph7: stage hidden -> B_ (ctx dead); x_ = relu([x|x_att] @ att_w^T + Batt) -> D_ [swapped]
  stage_f32c(B_, hidden, R0, 512, 0, tid, 1024);
  {
    const bf16_t* Wa = Wb + 327680;
    f32x4 acc[4] = {};
#pragma unroll 2
    for (int kk = 0; kk < 512; kk += 32) {
      bf16x8 a[4];
#pragma unroll
      for (int rt = 0; rt < 4; ++rt)
        a[rt] = (kk < 256) ? lds_frag(A_, rt * 16 + rl, kk + kof, 512)
                           : lds_frag(C_, rt * 16 + rl, kk - 256 + kof, 512);
      bf16x8 bb = *reinterpret_cast<const bf16x8*>(Wa + (long)(c0 + rl) * 512 + kk + kof);
#pragma unroll
      for (int rt = 0; rt < 4; ++rt) acc[rt] = mfma16(bb, a[rt], acc[rt]);
    }
    float4 bv = *reinterpret_cast<const float4*>(Batt + c0 + ro4);
#pragma unroll
    for (int rt = 0; rt < 4; ++rt)
      lds_put4(D_, rt * 16 + rl, c0 + ro4, 512,
               fmaxf(acc[rt][0] + bv.x, 0.f), fmaxf(acc[rt][1] + bv.y, 0.f),
               fmaxf(acc[rt][2] + bv.z, 0.f), fmaxf(acc[rt][3] + bv.w, 0.f));
  }
  __syncthreads();

  // ph8: GRU (x_ in D_, h_in in B_) -> h to Hout (float4) + Hnew in A_ (b64) [swapped]
  {
    const bf16_t* Wih = Wb + 458752;
    const bf16_t* Whh = Wb + 655360;
    const int cg = c0;
    f32x4 aRZ[2][4] = {}, aIN[4] = {}, aHN[4] = {};
#pragma unroll 1
    for (int kk = 0; kk < 256; kk += 32) {
      bf16x8 ax[4], bI[3];
#pragma unroll
      for (int rt = 0; rt < 4; ++rt) ax[rt] = lds_frag(D_, rt * 16 + rl, kk + kof, 512);
#pragma unroll
      for (int g = 0; g < 3; ++g)
        bI[g] = *reinterpret_cast<const bf16x8*>(Wih + (long)(g * 256 + cg + rl) * 256 + kk + kof);
#pragma unroll
      for (int rt = 0; rt < 4; ++rt) {
        aRZ[0][rt] = mfma16(bI[0], ax[rt], aRZ[0][rt]);
        aRZ[1][rt] = mfma16(bI[1], ax[rt], aRZ[1][rt]);
        aIN[rt]    = mfma16(bI[2], ax[rt], aIN[rt]);
      }
    }
#pragma unroll 1
    for (int kk = 0; kk < 256; kk += 32) {
      bf16x8 ah_[4], bH[3];
#pragma unroll
      for (int rt = 0; rt < 4; ++rt) ah_[rt] = lds_frag(B_, rt * 16 + rl, kk + kof, 512);
#pragma unroll
      for (int g = 0; g < 3; ++g)
        bH[g] = *reinterpret_cast<const bf16x8*>(Whh + (long)(g * 256 + cg + rl) * 256 + kk + kof);
#pragma unroll
      for (int rt = 0; rt < 4; ++rt) {
        aRZ[0][rt] = mfma16(bH[0], ah_[rt], aRZ[0][rt]);
        aRZ[1][rt] = mfma16(bH[1], ah_[rt], aRZ[1][rt]);
        aHN[rt]    = mfma16(bH[2], ah_[rt], aHN[rt]);
      }
    }
    // lane: row rloc = rt*16+rl, cols cg+ro4..+3
    float4 bir = *reinterpret_cast<const float4*>(bih + cg + ro4);
    float4 bhr = *reinterpret_cast<const float4*>(bhh + cg + ro4);
    float4 biz = *reinterpret_cast<const float4*>(bih + 256 + cg + ro4);
    float4 bhz = *reinterpret_cast<const float4*>(bhh + 256 + cg + ro4);
    float4 bin_ = *reinterpret_cast<const float4*>(bih + 512 + cg + ro4);
    float4 bhn = *reinterpret_cast<const float4*>(bhh + 512 + cg + ro4);
    float brr[4] = {bir.x + bhr.x, bir.y + bhr.y, bir.z + bhr.z, bir.w + bhr.w};
    float bzz[4] = {biz.x + bhz.x, biz.y + bhz.y, biz.z + bhz.z, biz.w + bhz.w};
    float bnn[4] = {bin_.x, bin_.y, bin_.z, bin_.w};
    float bhn4[4] = {bhn.x, bhn.y, bhn.z, bhn.w};
#pragma unroll
    for (int rt = 0; rt < 4; ++rt) {
      int rloc = rt * 16 + rl;
      uint2 hvp = lds_get4(B_, rloc, cg + ro4, 512);
      const bf16_t* hv4 = reinterpret_cast<const bf16_t*>(&hvp);
      float4 hq;
      float hb[4];
#pragma unroll
      for (int i = 0; i < 4; ++i) {
        float rg = 1.f / (1.f + __expf(-(aRZ[0][rt][i] + brr[i])));
        float zg = 1.f / (1.f + __expf(-(aRZ[1][rt][i] + bzz[i])));
        float nx = aIN[rt][i] + bnn[i] + rg * (aHN[rt][i] + bhn4[i]);
        float ng = 1.f - 2.f / (__expf(2.f * nx) + 1.f);  // tanh, saturation-safe
        float h = (1.f - zg) * ng + zg * (float)hv4[i];
        hb[i] = h;
        (&hq.x)[i] = h;
      }
      *reinterpret_cast<float4*>(Hout + (R0 + rloc) * 256 + cg + ro4) = hq;
      lds_put4(A_, rloc, cg + ro4, 512, hb[0], hb[1], hb[2], hb[3]);
    }
  }
  __syncthreads();

  // ph9: tactic_q = Hnew @ fc2_w^T + bt (waves 0-3) [swapped]
  if (wv < 4) {
    const bf16_t* Wt = Wb + 851968;
    f32x4 acc = {};
#pragma unroll 2
    for (int kk = 0; kk < 256; kk += 32) {
      bf16x8 a = lds_frag(A_, wv * 16 + rl, kk + kof, 512);
      bf16x8 bb = *reinterpret_cast<const bf16x8*>(Wt + (long)rl * 256 + kk + kof);
      acc = mfma16(bb, a, acc);
    }
    float4 bv = *reinterpret_cast<const float4*>(bt + ro4);
    float4 oq;
    oq.x = acc[0] + bv.x; oq.y = acc[1] + bv.y;
    oq.z = acc[2] + bv.z; oq.w = acc[3] + bv.w;
    *reinterpret_cast<float4*>(outT + (R0 + wv * 16 + rl) * 16 + ro4) = oq;
  }
}

extern "C" void kernel_launch(void* const* d_in, const int* in_sizes, int n_in,
                              void* d_out, int out_size, void* d_ws, size_t ws_size,
                              hipStream_t stream) {
  (void)in_sizes; (void)n_in; (void)out_size; (void)ws_size;
  const float* inputs      = (const float*)d_in[0];
  const float* hidden      = (const float*)d_in[1];
  const int*   drp         = (const int*)d_in[2];   // bool pushed as int32
  // d_in[3] = t (unused)
  const float* fc_gru_w    = (const float*)d_in[4];
  const float* fc_gru_b    = (const float*)d_in[5];
  const float* in_proj_w   = (const float*)d_in[6];
  const float* in_proj_b   = (const float*)d_in[7];
  const float* out_proj_w  = (const float*)d_in[8];
  const float* out_proj_b  = (const float*)d_in[9];
  const float* att_w       = (const float*)d_in[10];
  const float* att_b       = (const float*)d_in[11];
  const float* gru_wih     = (const float*)d_in[12];
  const float* gru_whh     = (const float*)d_in[13];
  const float* gru_bih     = (const float*)d_in[14];
  const float* gru_bhh     = (const float*)d_in[15];
  const float* fc2_w       = (const float*)d_in[16];
  const float* fc2_b       = (const float*)d_in[17];

  float* out_t = (float*)d_out;          // [M,16]
  float* out_h = out_t + MTOT * 16;      // [M,256] f32 h
  float* out_d = out_h + MTOT * 256;     // [B*64*64] f32

  bf16_t* Wb = (bf16_t*)d_ws;            // bf16 weights (1.7 MB) — only ws use

  // 0) weights f32 -> bf16
  cvt_weights<<<836, 256, 0, stream>>>(fc_gru_w, in_proj_w, out_proj_w, att_w,
                                       gru_wih, gru_whh, fc2_w, Wb);
  // 1) whole per-sample chain fused (incl. drop echo); h -> out_h, q -> out_t
  mega_kernel<<<2048, 1024, 0, stream>>>(inputs, hidden, drp, Wb,
                                         fc_gru_b, in_proj_b, out_proj_b, att_b,
                                         gru_bih, gru_bhh, fc2_b,
                                         out_h, out_t, out_d);
}

// Round 19
// 388.770 us; speedup vs baseline: 4.7535x; 1.3808x over previous
//
#include <hip/hip_runtime.h>

typedef __bf16 bf16_t;
using bf16x8 = __bf16 __attribute__((ext_vector_type(8)));
using f32x4  = float __attribute__((ext_vector_type(4)));

// B=2048, N=64, D=256, H=256, T=16
static constexpr long MTOT = 131072;   // B*N

__device__ __forceinline__ f32x4 mfma16(bf16x8 a, bf16x8 b, f32x4 c) {
  return __builtin_amdgcn_mfma_f32_16x16x32_bf16(a, b, c, 0, 0, 0);
}

// Swizzled LDS tiles: element (row,k) at byte row*rowBytes + ((k*2) ^ ((row&7)<<4)).
__device__ __forceinline__ bf16x8 lds_frag(const bf16_t* base, int row, int k, int rowBytes) {
  int byte = row * rowBytes + ((k << 1) ^ ((row & 7) << 4));
  return *reinterpret_cast<const bf16x8*>(reinterpret_cast<const char*>(base) + byte);
}
__device__ __forceinline__ void lds_put(bf16_t* base, int row, int col, int rowBytes, float v) {
  int byte = row * rowBytes + ((col << 1) ^ ((row & 7) << 4));
  *reinterpret_cast<bf16_t*>(reinterpret_cast<char*>(base) + byte) = (bf16_t)v;
}
// Write 4 bf16 at (row, col4..col4+3); col4 multiple of 4 -> 8B contiguous.
__device__ __forceinline__ void lds_put4(bf16_t* base, int row, int col4, int rowBytes,
                                         float v0, float v1, float v2, float v3) {
  bf16_t t4[4] = {(bf16_t)v0, (bf16_t)v1, (bf16_t)v2, (bf16_t)v3};
  int byte = row * rowBytes + ((col4 << 1) ^ ((row & 7) << 4));
  *reinterpret_cast<uint2*>(reinterpret_cast<char*>(base) + byte) =
      *reinterpret_cast<const uint2*>(t4);
}
// Read 4 bf16 at (row, col4..col4+3).
__device__ __forceinline__ uint2 lds_get4(const bf16_t* base, int row, int col4, int rowBytes) {
  int byte = row * rowBytes + ((col4 << 1) ^ ((row & 7) << 4));
  return *reinterpret_cast<const uint2*>(reinterpret_cast<const char*>(base) + byte);
}

// Stage a [64 x 256] f32 tile -> single bf16 swizzled LDS.
__device__ __forceinline__ void stage_f32c(bf16_t* lds, const float* src, long row0,
                                           int rowBytesLds, int colOffBytes,
                                           int tid, int nthr) {
  for (int e = tid * 4; e < 64 * 256; e += nthr * 4) {
    int r = e >> 8, c = e & 255;
    float4 v = *reinterpret_cast<const float4*>(src + (row0 + r) * 256 + c);
    bf16_t t4[4] = {(bf16_t)v.x, (bf16_t)v.y, (bf16_t)v.z, (bf16_t)v.w};
    int db = r * rowBytesLds + (((c << 1) + colOffBytes) ^ ((r & 7) << 4));
    *reinterpret_cast<uint2*>(reinterpret_cast<char*>(lds) + db) =
        *reinterpret_cast<const uint2*>(t4);
  }
}

// ---------------------------------------------------------------------------
// Weights f32 -> bf16, packed fragment-major:
// packed[((s*(K/32)+t)*64 + l)*8 + j] = W[s*16 + (l&15)][t*32 + (l>>4)*8 + j]
// so a wave's 64 lanes load one contiguous 1KB chunk per (strip, kk) step.
// Segment offsets (elements) unchanged: fc_gru 0, in_proj 65536, out_proj
// 262144, att 327680, wih 458752, whh 655360, fc2 851968.
// Groups of 8 elements; totals: 8192,24576,8192,16384,24576,24576,512 =107008.
// ---------------------------------------------------------------------------
__global__ __launch_bounds__(256) void cvt_weights(const float* __restrict__ w0,
                                                   const float* __restrict__ w1,
                                                   const float* __restrict__ w2,
                                                   const float* __restrict__ w3,
                                                   const float* __restrict__ w4,
                                                   const float* __restrict__ w5,
                                                   const float* __restrict__ w6,
                                                   bf16_t* __restrict__ dst) {
  long g = (long)blockIdx.x * 256 + threadIdx.x;   // group id (8 elems each)
  const float* src; long dstOff; int K; long gl;
  if (g < 8192)        { src = w0; dstOff = 0;      K = 256; gl = g; }
  else if (g < 32768)  { src = w1; dstOff = 65536;  K = 256; gl = g - 8192; }
  else if (g < 40960)  { src = w2; dstOff = 262144; K = 256; gl = g - 32768; }
  else if (g < 57344)  { src = w3; dstOff = 327680; K = 512; gl = g - 40960; }
  else if (g < 81920)  { src = w4; dstOff = 458752; K = 256; gl = g - 57344; }
  else if (g < 106496) { src = w5; dstOff = 655360; K = 256; gl = g - 81920; }
  else                 { src = w6; dstOff = 851968; K = 256; gl = g - 106496; }
  int tPerS = (K >> 5) << 6;           // (K/32)*64
  int s = (int)(gl / tPerS);
  int rem = (int)(gl % tPerS);
  int t = rem >> 6, l = rem & 63;
  int r = s * 16 + (l & 15);
  int k = t * 32 + ((l >> 4) << 3);
  const float* sp = src + (long)r * K + k;
  float4 v0 = *reinterpret_cast<const float4*>(sp);
  float4 v1 = *reinterpret_cast<const float4*>(sp + 4);
  bf16_t o[8] = {(bf16_t)v0.x, (bf16_t)v0.y, (bf16_t)v0.z, (bf16_t)v0.w,
                 (bf16_t)v1.x, (bf16_t)v1.y, (bf16_t)v1.z, (bf16_t)v1.w};
  *reinterpret_cast<uint4*>(dst + dstOff + gl * 8) = *reinterpret_cast<const uint4*>(o);
}

// ---------------------------------------------------------------------------
// MEGA kernel, 1024 threads (16 waves, 4 waves/SIMD). Block = one sample.
// r19 change: packed weight layout -> every weight load is a wave-contiguous
// 1KB burst (was a 16-line 512B-strided gather). Values per lane identical.
// LDS: A_[0,32K) x->Hnew | B_[32,64K) IN->q->ctx->h | C_[64,96K) k->P->x_att
//      | D_[96,128K) V^T->x_ | SS[128K,+16.6K) scores f32 stride 65.
// ---------------------------------------------------------------------------
__global__ __launch_bounds__(1024) void mega_kernel(
    const float* __restrict__ inputs, const float* __restrict__ hidden,
    const int* __restrict__ drop, const bf16_t* __restrict__ Wb,
    const float* __restrict__ b0, const float* __restrict__ Bqkv,
    const float* __restrict__ Bo, const float* __restrict__ Batt,
    const float* __restrict__ bih, const float* __restrict__ bhh,
    const float* __restrict__ bt,
    float* __restrict__ Hout, float* __restrict__ outT,
    float* __restrict__ outD) {
  __shared__ __align__(16) char buf[147968];
  bf16_t* A_ = reinterpret_cast<bf16_t*>(buf);
  bf16_t* B_ = reinterpret_cast<bf16_t*>(buf + 32768);
  bf16_t* C_ = reinterpret_cast<bf16_t*>(buf + 65536);
  bf16_t* D_ = reinterpret_cast<bf16_t*>(buf + 98304);
  float*  SS = reinterpret_cast<float*>(buf + 131072);   // [64][65]
  const int tid = threadIdx.x, lane = tid & 63, wv = tid >> 6;  // wv 0..15
  const int rl = lane & 15, kof = (lane >> 4) << 3, ro4 = (lane >> 4) << 2;
  const int b = blockIdx.x;
  const long R0 = (long)b * 64;
  const int c0 = wv * 16;   // 16-col strip per wave

  // ph0: stage inputs -> B_
  stage_f32c(B_, inputs, R0, 512, 0, tid, 1024);
  __syncthreads();

  // ph1: x = relu(IN @ fc_gru_w^T + b0) -> A_  [swapped: lane = (row rl, cols ro4..+3)]
  {
    f32x4 acc[4] = {};
#pragma unroll 2
    for (int kk = 0; kk < 256; kk += 32) {
      bf16x8 a[4];
#pragma unroll
      for (int rt = 0; rt < 4; ++rt) a[rt] = lds_frag(B_, rt * 16 + rl, kk + kof, 512);
      bf16x8 bb = *reinterpret_cast<const bf16x8*>(
          Wb + ((long)(wv * 8 + (kk >> 5)) * 64 + lane) * 8);
#pragma unroll
      for (int rt = 0; rt < 4; ++rt) acc[rt] = mfma16(bb, a[rt], acc[rt]);
    }
    float4 bv = *reinterpret_cast<const float4*>(b0 + c0 + ro4);
#pragma unroll
    for (int rt = 0; rt < 4; ++rt)
      lds_put4(A_, rt * 16 + rl, c0 + ro4, 512,
               fmaxf(acc[rt][0] + bv.x, 0.f), fmaxf(acc[rt][1] + bv.y, 0.f),
               fmaxf(acc[rt][2] + bv.z, 0.f), fmaxf(acc[rt][3] + bv.w, 0.f));
  }
  __syncthreads();

  // ph2a: q -> B_, k -> C_ [swapped]
  for (int which = 0; which < 2; ++which) {
    const bf16_t* Wp = Wb + 65536;
    f32x4 acc[4] = {};
#pragma unroll 2
    for (int kk = 0; kk < 256; kk += 32) {
      bf16x8 a[4];
#pragma unroll
      for (int rt = 0; rt < 4; ++rt) a[rt] = lds_frag(A_, rt * 16 + rl, kk + kof, 512);
      bf16x8 bb = *reinterpret_cast<const bf16x8*>(
          Wp + ((long)((which * 16 + wv) * 8 + (kk >> 5)) * 64 + lane) * 8);
#pragma unroll
      for (int rt = 0; rt < 4; ++rt) acc[rt] = mfma16(bb, a[rt], acc[rt]);
    }
    float4 bv = *reinterpret_cast<const float4*>(Bqkv + which * 256 + c0 + ro4);
    bf16_t* outp = which ? C_ : B_;
#pragma unroll
    for (int rt = 0; rt < 4; ++rt)
      lds_put4(outp, rt * 16 + rl, c0 + ro4, 512,
               acc[rt][0] + bv.x, acc[rt][1] + bv.y, acc[rt][2] + bv.z, acc[rt][3] + bv.w);
  }
  // ph2b: V^T -> D_ [UNswapped: lane = (col c0+rl fixed, rows ro4..+3) = V^T col4-contig]
  {
    const bf16_t* Wp = Wb + 65536;
    f32x4 acc[4] = {};
#pragma unroll 2
    for (int kk = 0; kk < 256; kk += 32) {
      bf16x8 a[4];
#pragma unroll
      for (int rt = 0; rt < 4; ++rt) a[rt] = lds_frag(A_, rt * 16 + rl, kk + kof, 512);
      bf16x8 bb = *reinterpret_cast<const bf16x8*>(
          Wp + ((long)((2 * 16 + wv) * 8 + (kk >> 5)) * 64 + lane) * 8);
#pragma unroll
      for (int rt = 0; rt < 4; ++rt) acc[rt] = mfma16(a[rt], bb, acc[rt]);
    }
    int c = c0 + rl;
    float bv = Bqkv[512 + c];
#pragma unroll
    for (int rt = 0; rt < 4; ++rt)
      lds_put4(D_, c, rt * 16 + ro4, 128,
               acc[rt][0] + bv, acc[rt][1] + bv, acc[rt][2] + bv, acc[rt][3] + bv);
  }
  __syncthreads();

  // ph3: scores = q k^T * scale, masked -> SS; also echo mask -> outD
  {
    const int rt0 = (wv & 3) * 16, sc0 = (wv >> 2) * 16;
    f32x4 acc = {};
#pragma unroll 2
    for (int kk = 0; kk < 256; kk += 32) {
      bf16x8 a = lds_frag(B_, rt0 + rl, kk + kof, 512);
      bf16x8 bb = lds_frag(C_, sc0 + rl, kk + kof, 512);
      acc = mfma16(a, bb, acc);
    }
#pragma unroll
    for (int i = 0; i < 4; ++i) {
      int rr = rt0 + ro4 + i, cc = sc0 + rl;
      int dm = drop[(long)b * 4096 + rr * 64 + cc];
      float s = acc[i] * 0.0625f;
      if (dm) s = -1e9f;
      SS[rr * 65 + cc] = s;
      outD[(long)b * 4096 + rr * 64 + cc] = dm ? 1.f : 0.f;
    }
  }
  __syncthreads();

  // ph4: softmax -> P (bf16) over C_ (k dead)
#pragma unroll
  for (int j = 0; j < 4; ++j) {
    int rr = wv * 4 + j;
    float s = SS[rr * 65 + lane];
    float m = s;
#pragma unroll
    for (int off = 32; off >= 1; off >>= 1) m = fmaxf(m, __shfl_xor(m, off));
    float e = __expf(s - m);
    float sum = e;
#pragma unroll
    for (int off = 32; off >= 1; off >>= 1) sum += __shfl_xor(sum, off);
    lds_put(C_, rr, lane, 128, e / sum);
  }
  __syncthreads();

  // ph5: ctx = P @ V -> B_ (q dead) [swapped]
  {
    f32x4 acc[4] = {};
#pragma unroll
    for (int kk = 0; kk < 64; kk += 32) {
      bf16x8 a[4];
#pragma unroll
      for (int rt = 0; rt < 4; ++rt) a[rt] = lds_frag(C_, rt * 16 + rl, kk + kof, 128);
      bf16x8 bb = lds_frag(D_, c0 + rl, kk + kof, 128);
#pragma unroll
      for (int rt = 0; rt < 4; ++rt) acc[rt] = mfma16(bb, a[rt], acc[rt]);
    }
    __syncthreads();  // all P reads complete before overwrites
#pragma unroll
    for (int rt = 0; rt < 4; ++rt)
      lds_put4(B_, rt * 16 + rl, c0 + ro4, 512,
               acc[rt][0], acc[rt][1], acc[rt][2], acc[rt][3]);
  }
  __syncthreads();

  // ph6: x_att = ctx @ Wo^T + Bo -> C_ [swapped]
  {
    const bf16_t* Wo = Wb + 262144;
    f32x4 acc[4] = {};
#pragma unroll 2
    for (int kk = 0; kk < 256; kk += 32) {
      bf16x8 a[4];
#pragma unroll
      for (int rt = 0; rt < 4; ++rt) a[rt] = lds_frag(B_, rt * 16 + rl, kk + kof, 512);
      bf16x8 bb = *reinterpret_cast<const bf16x8*>(
          Wo + ((long)(wv * 8 + (kk >> 5)) * 64 + lane) * 8);
#pragma unroll
      for (int rt = 0; rt < 4; ++rt) acc[rt] = mfma16(bb, a[rt], acc[rt]);
    }
    float4 bv = *reinterpret_cast<const float4*>(Bo + c0 + ro4);
#pragma unroll
    for (int rt = 0; rt < 4; ++rt)
      lds_put4(C_, rt * 16 + rl, c0 + ro4, 512,
               acc[rt][0] + bv.x, acc[rt][1] + bv.y, acc[rt][2] + bv.z, acc[rt][3] + bv.w);
  }
  __syncthreads();

  // ph7: stage hidden -> B_ (ctx dead); x_ = relu([x|x_att] @ att_w^T + Batt) -> D_ [swapped]
  stage_f32c(B_, hidden, R0, 512, 0, tid, 1024);
  {
    const bf16_t* Wa = Wb + 327680;
    f32x4 acc[4] = {};
#pragma unroll 2
    for (int kk = 0; kk < 512; kk += 32) {
      bf16x8 a[4];
#pragma unroll
      for (int rt = 0; rt < 4; ++rt)
        a[rt] = (kk < 256) ? lds_frag(A_, rt * 16 + rl, kk + kof, 512)
                           : lds_frag(C_, rt * 16 + rl, kk - 256 + kof, 512);
      bf16x8 bb = *reinterpret_cast<const bf16x8*>(
          Wa + ((long)(wv * 16 + (kk >> 5)) * 64 + lane) * 8);
#pragma unroll
      for (int rt = 0; rt < 4; ++rt) acc[rt] = mfma16(bb, a[rt], acc[rt]);
    }
    float4 bv = *reinterpret_cast<const float4*>(Batt + c0 + ro4);
#pragma unroll
    for (int rt = 0; rt < 4; ++rt)
      lds_put4(D_, rt * 16 + rl, c0 + ro4, 512,
               fmaxf(acc[rt][0] + bv.x, 0.f), fmaxf(acc[rt][1] + bv.y, 0.f),
               fmaxf(acc[rt][2] + bv.z, 0.f), fmaxf(acc[rt][3] + bv.w, 0.f));
  }
  __syncthreads();

  // ph8: GRU (x_ in D_, h_in in B_) -> h to Hout (float4) + Hnew in A_ (b64) [swapped]
  {
    const bf16_t* Wih = Wb + 458752;
    const bf16_t* Whh = Wb + 655360;
    const int cg = c0;
    f32x4 aRZ[2][4] = {}, aIN[4] = {}, aHN[4] = {};
#pragma unroll 1
    for (int kk = 0; kk < 256; kk += 32) {
      bf16x8 ax[4], bI[3];
#pragma unroll
      for (int rt = 0; rt < 4; ++rt) ax[rt] = lds_frag(D_, rt * 16 + rl, kk + kof, 512);
#pragma unroll
      for (int g = 0; g < 3; ++g)
        bI[g] = *reinterpret_cast<const bf16x8*>(
            Wih + ((long)((g * 16 + wv) * 8 + (kk >> 5)) * 64 + lane) * 8);
#pragma unroll
      for (int rt = 0; rt < 4; ++rt) {
        aRZ[0][rt] = mfma16(bI[0], ax[rt], aRZ[0][rt]);
        aRZ[1][rt] = mfma16(bI[1], ax[rt], aRZ[1][rt]);
        aIN[rt]    = mfma16(bI[2], ax[rt], aIN[rt]);
      }
    }
#pragma unroll 1
    for (int kk = 0; kk < 256; kk += 32) {
      bf16x8 ah_[4], bH[3];
#pragma unroll
      for (int rt = 0; rt < 4; ++rt) ah_[rt] = lds_frag(B_, rt * 16 + rl, kk + kof, 512);
#pragma unroll
      for (int g = 0; g < 3; ++g)
        bH[g] = *reinterpret_cast<const bf16x8*>(
            Whh + ((long)((g * 16 + wv) * 8 + (kk >> 5)) * 64 + lane) * 8);
#pragma unroll
      for (int rt = 0; rt < 4; ++rt) {
        aRZ[0][rt] = mfma16(bH[0], ah_[rt], aRZ[0][rt]);
        aRZ[1][rt] = mfma16(bH[1], ah_[rt], aRZ[1][rt]);
        aHN[rt]    = mfma16(bH[2], ah_[rt], aHN[rt]);
      }
    }
    // lane: row rloc = rt*16+rl, cols cg+ro4..+3
    float4 bir = *reinterpret_cast<const float4*>(bih + cg + ro4);
    float4 bhr = *reinterpret_cast<const float4*>(bhh + cg + ro4);
    float4 biz = *reinterpret_cast<const float4*>(bih + 256 + cg + ro4);
    float4 bhz = *reinterpret_cast<const float4*>(bhh + 256 + cg + ro4);
    float4 bin_ = *reinterpret_cast<const float4*>(bih + 512 + cg + ro4);
    float4 bhn = *reinterpret_cast<const float4*>(bhh + 512 + cg + ro4);
    float brr[4] = {bir.x + bhr.x, bir.y + bhr.y, bir.z + bhr.z, bir.w + bhr.w};
    float bzz[4] = {biz.x + bhz.x, biz.y + bhz.y, biz.z + bhz.z, biz.w + bhz.w};
    float bnn[4] = {bin_.x, bin_.y, bin_.z, bin_.w};
    float bhn4[4] = {bhn.x, bhn.y, bhn.z, bhn.w};
#pragma unroll
    for (int rt = 0; rt < 4; ++rt) {
      int rloc = rt * 16 + rl;
      uint2 hvp = lds_get4(B_, rloc, cg + ro4, 512);
      const bf16_t* hv4 = reinterpret_cast<const bf16_t*>(&hvp);
      float4 hq;
      float hb[4];
#pragma unroll
      for (int i = 0; i < 4; ++i) {
        float rg = 1.f / (1.f + __expf(-(aRZ[0][rt][i] + brr[i])));
        float zg = 1.f / (1.f + __expf(-(aRZ[1][rt][i] + bzz[i])));
        float nx = aIN[rt][i] + bnn[i] + rg * (aHN[rt][i] + bhn4[i]);
        float ng = 1.f - 2.f / (__expf(2.f * nx) + 1.f);  // tanh, saturation-safe
        float h = (1.f - zg) * ng + zg * (float)hv4[i];
        hb[i] = h;
        (&hq.x)[i] = h;
      }
      *reinterpret_cast<float4*>(Hout + (R0 + rloc) * 256 + cg + ro4) = hq;
      lds_put4(A_, rloc, cg + ro4, 512, hb[0], hb[1], hb[2], hb[3]);
    }
  }
  __syncthreads();

  // ph9: tactic_q = Hnew @ fc2_w^T + bt (waves 0-3) [swapped]
  if (wv < 4) {
    const bf16_t* Wt = Wb + 851968;
    f32x4 acc = {};
#pragma unroll 2
    for (int kk = 0; kk < 256; kk += 32) {
      bf16x8 a = lds_frag(A_, wv * 16 + rl, kk + kof, 512);
      bf16x8 bb = *reinterpret_cast<const bf16x8*>(Wt + ((long)(kk >> 5) * 64 + lane) * 8);
      acc = mfma16(bb, a, acc);
    }
    float4 bv = *reinterpret_cast<const float4*>(bt + ro4);
    float4 oq;
    oq.x = acc[0] + bv.x; oq.y = acc[1] + bv.y;
    oq.z = acc[2] + bv.z; oq.w = acc[3] + bv.w;
    *reinterpret_cast<float4*>(outT + (R0 + wv * 16 + rl) * 16 + ro4) = oq;
  }
}

extern "C" void kernel_launch(void* const* d_in, const int* in_sizes, int n_in,
                              void* d_out, int out_size, void* d_ws, size_t ws_size,
                              hipStream_t stream) {
  (void)in_sizes; (void)n_in; (void)out_size; (void)ws_size;
  const float* inputs      = (const float*)d_in[0];
  const float* hidden      = (const float*)d_in[1];
  const int*   drp         = (const int*)d_in[2];   // bool pushed as int32
  // d_in[3] = t (unused)
  const float* fc_gru_w    = (const float*)d_in[4];
  const float* fc_gru_b    = (const float*)d_in[5];
  const float* in_proj_w   = (const float*)d_in[6];
  const float* in_proj_b   = (const float*)d_in[7];
  const float* out_proj_w  = (const float*)d_in[8];
  const float* out_proj_b  = (const float*)d_in[9];
  const float* att_w       = (const float*)d_in[10];
  const float* att_b       = (const float*)d_in[11];
  const float* gru_wih     = (const float*)d_in[12];
  const float* gru_whh     = (const float*)d_in[13];
  const float* gru_bih     = (const float*)d_in[14];
  const float* gru_bhh     = (const float*)d_in[15];
  const float* fc2_w       = (const float*)d_in[16];
  const float* fc2_b       = (const float*)d_in[17];

  float* out_t = (float*)d_out;          // [M,16]
  float* out_h = out_t + MTOT * 16;      // [M,256] f32 h
  float* out_d = out_h + MTOT * 256;     // [B*64*64] f32

  bf16_t* Wb = (bf16_t*)d_ws;            // packed bf16 weights (1.7 MB)

  // 0) weights f32 -> bf16 (fragment-major packing); 107008 groups / 256 = 418
  cvt_weights<<<418, 256, 0, stream>>>(fc_gru_w, in_proj_w, out_proj_w, att_w,
                                       gru_wih, gru_whh, fc2_w, Wb);
  // 1) whole per-sample chain fused (incl. drop echo); h -> out_h, q -> out_t
  mega_kernel<<<2048, 1024, 0, stream>>>(inputs, hidden, drp, Wb,
                                         fc_gru_b, in_proj_b, out_proj_b, att_b,
                                         gru_bih, gru_bhh, fc2_b,
                                         out_h, out_t, out_d);
}